// Round 2
// baseline (4844.598 us; speedup 1.0000x reference)
//
#include <hip/hip_runtime.h>

#define NBATCH 16
#define NPTS   4096
#define NSAMP  1024
#define NKNN   32
#define NROWS  (NBATCH*NSAMP*NKNN)   // 524288
#define BN_EPS 1e-5f

// ============================ FPS ============================
// One block per batch. dists + coords in registers (4 pts/thread).
// Exact f32 semantics: no FMA contraction, argmax ties -> lowest index.
// (Validated: Output 0 passed bitwise in round 1 — do not change arithmetic.)
__global__ __launch_bounds__(1024) void fps_kernel(const float* __restrict__ xyz,
                                                   float* __restrict__ newxyz)
{
    const int b = blockIdx.x;
    const int tid = threadIdx.x;
    const float* xb = xyz + (size_t)b * NPTS * 3;
    float px[4], py[4], pz[4], dmin[4];
    #pragma unroll
    for (int j = 0; j < 4; ++j) {
        const int p = tid + j * 1024;
        px[j] = xb[p*3+0]; py[j] = xb[p*3+1]; pz[j] = xb[p*3+2];
        dmin[j] = 1e10f;
    }
    __shared__ float red_v[16];
    __shared__ int   red_i[16];
    __shared__ float last3[3];
    if (tid == 0) {
        last3[0] = xb[0]; last3[1] = xb[1]; last3[2] = xb[2];
        float* o = newxyz + (size_t)b * NSAMP * 3;
        o[0] = xb[0]; o[1] = xb[1]; o[2] = xb[2];
    }
    __syncthreads();
    for (int t = 1; t < NSAMP; ++t) {
        const float lx = last3[0], ly = last3[1], lz = last3[2];
        float bv = -1.0f; int bi = 0;
        #pragma unroll
        for (int j = 0; j < 4; ++j) {
            const float dx = __fsub_rn(px[j], lx);
            const float dy = __fsub_rn(py[j], ly);
            const float dz = __fsub_rn(pz[j], lz);
            const float d = __fadd_rn(__fadd_rn(__fmul_rn(dx,dx), __fmul_rn(dy,dy)), __fmul_rn(dz,dz));
            const float nd = fminf(dmin[j], d);
            dmin[j] = nd;
            const int gi = tid + j * 1024;
            if (nd > bv || (nd == bv && gi < bi)) { bv = nd; bi = gi; }
        }
        #pragma unroll
        for (int m = 1; m < 64; m <<= 1) {
            const float ov = __shfl_xor(bv, m);
            const int   oi = __shfl_xor(bi, m);
            if (ov > bv || (ov == bv && oi < bi)) { bv = ov; bi = oi; }
        }
        if ((tid & 63) == 0) { red_v[tid >> 6] = bv; red_i[tid >> 6] = bi; }
        __syncthreads();
        bv = red_v[0]; bi = red_i[0];
        #pragma unroll
        for (int w = 1; w < 16; ++w) {
            const float ov = red_v[w]; const int oi = red_i[w];
            if (ov > bv || (ov == bv && oi < bi)) { bv = ov; bi = oi; }
        }
        if (tid == (bi & 1023)) {
            const int j = bi >> 10;
            last3[0] = px[j]; last3[1] = py[j]; last3[2] = pz[j];
            float* o = newxyz + ((size_t)b * NSAMP + t) * 3;
            o[0] = px[j]; o[1] = py[j]; o[2] = pz[j];
        }
        __syncthreads();
    }
}

// ============================ kNN ============================
// One block (256 thr) per centroid. Distance = (qq - 2*dot) + xx with the dot
// computed as an FMA chain (acc = fma(q_c, x_c, acc), ascending c) to match
// the reference's einsum lowering (Eigen sgemm). qq/xx stay separate-rounded
// (elementwise reduce path, no contraction — the FPS-validated style).
__global__ __launch_bounds__(256) void knn_kernel(const float* __restrict__ xyz,
                                                  const float* __restrict__ newxyz,
                                                  int* __restrict__ idx_out)
{
    const int bs = blockIdx.x;
    const int b = bs >> 10;
    const int tid = threadIdx.x;
    __shared__ unsigned keys[NPTS];
    __shared__ int hist[256];
    __shared__ float qsh[3];
    __shared__ int ctrl[4];   // 0:prefix 1:rem 2:nless 3:ntie
    __shared__ int ties[128];
    if (tid < 3) qsh[tid] = newxyz[bs*3 + tid];
    if (tid == 0) { ctrl[0] = 0; ctrl[1] = NKNN; }
    __syncthreads();
    const float q0 = qsh[0], q1 = qsh[1], q2 = qsh[2];
    const float qq = __fadd_rn(__fadd_rn(__fmul_rn(q0,q0), __fmul_rn(q1,q1)), __fmul_rn(q2,q2));
    const float* xb = xyz + (size_t)b * NPTS * 3;
    for (int n = tid; n < NPTS; n += 256) {
        const float x0 = xb[n*3+0], x1 = xb[n*3+1], x2 = xb[n*3+2];
        const float xx = __fadd_rn(__fadd_rn(__fmul_rn(x0,x0), __fmul_rn(x1,x1)), __fmul_rn(x2,x2));
        float dt = __fmul_rn(q0, x0);
        dt = __fmaf_rn(q1, x1, dt);
        dt = __fmaf_rn(q2, x2, dt);
        const float dd = __fadd_rn(__fsub_rn(qq, __fmul_rn(2.0f, dt)), xx);
        unsigned ub = __float_as_uint(dd);
        ub = (ub & 0x80000000u) ? ~ub : (ub | 0x80000000u);
        keys[n] = ub;
    }
    // radix select (MSB byte -> LSB byte)
    for (int p = 3; p >= 0; --p) {
        __syncthreads();
        hist[tid] = 0;
        __syncthreads();
        const unsigned pre = (unsigned)ctrl[0];
        const int shift = p * 8;
        const unsigned himask = (p == 3) ? 0u : (0xFFFFFFFFu << ((p + 1) * 8));
        for (int n = tid; n < NPTS; n += 256) {
            const unsigned k = keys[n];
            if ((k & himask) == pre) atomicAdd(&hist[(k >> shift) & 255], 1);
        }
        __syncthreads();
        if (tid == 0) {
            int r = ctrl[1]; unsigned pf = (unsigned)ctrl[0];
            for (int bin = 0; bin < 256; ++bin) {
                const int cnt = hist[bin];
                if (r > cnt) r -= cnt;
                else { pf |= ((unsigned)bin) << shift; break; }
            }
            ctrl[0] = (int)pf; ctrl[1] = r;
        }
    }
    __syncthreads();
    const unsigned T = (unsigned)ctrl[0];
    if (tid == 0) { ctrl[2] = 0; ctrl[3] = 0; }
    __syncthreads();
    int* out = idx_out + (size_t)bs * NKNN;
    for (int n = tid; n < NPTS; n += 256) {
        const unsigned k = keys[n];
        if (k < T) {
            const int pos = atomicAdd(&ctrl[2], 1);
            if (pos < NKNN) out[pos] = n;
        } else if (k == T) {
            const int pos = atomicAdd(&ctrl[3], 1);
            if (pos < 128) ties[pos] = n;
        }
    }
    __syncthreads();
    if (tid == 0) {
        const int nless = ctrl[2] < NKNN ? ctrl[2] : NKNN;
        const int need = NKNN - nless;
        const int ntie = ctrl[3] < 128 ? ctrl[3] : 128;
        int last = -1;
        for (int j = 0; j < need; ++j) {
            int best = 0x7fffffff;
            for (int i = 0; i < ntie; ++i) {
                const int v = ties[i];
                if (v > last && v < best) best = v;
            }
            out[nless + j] = (best == 0x7fffffff) ? 0 : best;
            last = best;
        }
    }
}

// ============================ stats helpers ============================
__global__ void zero_stats_kernel(double* st)
{
    const int i = blockIdx.x * 256 + threadIdx.x;
    if (i < 512) st[i] = 0.0;
}

// Recompute MLP chain up to layer L; accumulate per-channel sum/sumsq of
// the PRE-BN activation of layer L. bnp: [layer][scale|shift][64] floats.
template<int L>
__global__ __launch_bounds__(256) void lstats_kernel(
    const float* __restrict__ xyz, const float* __restrict__ newxyz,
    const int* __restrict__ idxws,
    const float* __restrict__ w0, const float* __restrict__ b0,
    const float* __restrict__ w1, const float* __restrict__ b1,
    const float* __restrict__ w2, const float* __restrict__ b2,
    const float* __restrict__ bnp, double* __restrict__ stats)
{
    __shared__ float w1s[64*64];
    __shared__ float w2s[64*64];
    __shared__ float w0s[192];
    __shared__ float gxs[4][3];
    __shared__ float hb1[4][64];
    __shared__ float hb2[4][64];
    __shared__ double rs[256];
    __shared__ double rs2[256];
    const int tid = threadIdx.x;
    const int c = tid & 63;
    const int rq = tid >> 6;
    if (tid < 192) w0s[tid] = w0[tid];
    if (L >= 1) for (int i = tid; i < 4096; i += 256) w1s[i] = w1[i];
    if (L >= 2) for (int i = tid; i < 4096; i += 256) w2s[i] = w2[i];
    const float b0c = b0[c];
    float b1c = 0.f, b2c = 0.f, sc0 = 0.f, sh0 = 0.f, sc1 = 0.f, sh1 = 0.f;
    if (L >= 1) { b1c = b1[c]; sc0 = bnp[c]; sh0 = bnp[64+c]; }
    if (L >= 2) { b2c = b2[c]; sc1 = bnp[128+c]; sh1 = bnp[192+c]; }
    __syncthreads();
    double s = 0.0, s2 = 0.0;
    const int tiles = NROWS / 4;
    for (int tile = blockIdx.x; tile < tiles; tile += gridDim.x) {
        const int row = tile * 4 + rq;
        if (c < 3) {
            const int bs = row >> 5;
            const int bb = row >> 15;
            const int id = idxws[row];
            gxs[rq][c] = xyz[((size_t)bb * NPTS + id) * 3 + c] - newxyz[bs*3 + c];
        }
        __syncthreads();
        const float t0 = gxs[rq][0]*w0s[c] + gxs[rq][1]*w0s[64+c] + gxs[rq][2]*w0s[128+c] + b0c;
        if (L == 0) {
            s += t0; s2 += (double)t0 * (double)t0;
        } else {
            hb1[rq][c] = fmaxf(sc0*t0 + sh0, 0.0f);
            __syncthreads();
            float t1 = b1c;
            #pragma unroll
            for (int j = 0; j < 64; ++j) t1 += hb1[rq][j] * w1s[j*64 + c];
            if (L == 1) {
                s += t1; s2 += (double)t1 * (double)t1;
            } else {
                hb2[rq][c] = fmaxf(sc1*t1 + sh1, 0.0f);
                __syncthreads();
                float t2 = b2c;
                #pragma unroll
                for (int j = 0; j < 64; ++j) t2 += hb2[rq][j] * w2s[j*64 + c];
                s += t2; s2 += (double)t2 * (double)t2;
            }
        }
        __syncthreads();
    }
    rs[tid] = s; rs2[tid] = s2;
    __syncthreads();
    if (tid < 64) {
        const double a  = rs[c]  + rs[64+c]  + rs[128+c]  + rs[192+c];
        const double a2 = rs2[c] + rs2[64+c] + rs2[128+c] + rs2[192+c];
        atomicAdd(&stats[c], a);
        atomicAdd(&stats[64 + c], a2);
    }
}

__global__ void bn_finalize_kernel(const double* __restrict__ st,
                                   const float* __restrict__ g,
                                   const float* __restrict__ be,
                                   float* __restrict__ outp, float n)
{
    const int c = threadIdx.x;  // 64
    const double m = st[c] / (double)n;
    const double var = st[64 + c] / (double)n - m * m;
    const float scale = g[c] * rsqrtf((float)var + BN_EPS);
    outp[c] = scale;
    outp[64 + c] = be[c] - (float)m * scale;
}

// ============================ final fused conv ============================
// Block = 512 thr, 8 centroids. Phase A: recompute weightnet -> wt[8][32][64].
// Phase B: per d: gather features, nf_d = gf^T*wt, y += nf_d * wf_tile.
__global__ __launch_bounds__(512) void final_conv_kernel(
    const float* __restrict__ xyz, const float* __restrict__ newxyz,
    const int* __restrict__ idxws, const float* __restrict__ feat,
    const float* __restrict__ w0, const float* __restrict__ b0,
    const float* __restrict__ w1, const float* __restrict__ b1,
    const float* __restrict__ w2, const float* __restrict__ b2,
    const float* __restrict__ bnp, const float* __restrict__ wf,
    const float* __restrict__ bf, float* __restrict__ y)
{
    __shared__ float wt[8][32][64];    // 64 KB
    __shared__ float w1s[64*64];       // 16 KB
    __shared__ float w2s[64*64];       // 16 KB
    __shared__ float wfs[64*64];       // 16 KB
    __shared__ float hb1[8][64];
    __shared__ float hb2[8][64];
    __shared__ float nfs[8][64];
    __shared__ float gfd[8][32];
    __shared__ int   idxs[8][32];
    __shared__ float qs[8][3];
    __shared__ float gxs[8][3];
    __shared__ float w0s[192];
    const int tid = threadIdx.x;
    const int c = tid & 63;
    const int rq = tid >> 6;          // 0..7
    const int g = blockIdx.x;
    const int bs0 = g * 8;
    const int b = bs0 >> 10;
    if (tid < 256) idxs[tid >> 5][tid & 31] = idxws[(size_t)bs0 * NKNN + tid];
    if (tid < 24)  qs[tid / 3][tid % 3] = newxyz[(bs0 + tid/3)*3 + (tid % 3)];
    if (tid < 192) w0s[tid] = w0[tid];
    for (int i = tid; i < 4096; i += 512) { w1s[i] = w1[i]; w2s[i] = w2[i]; }
    const float b0c = b0[c], b1c = b1[c], b2c = b2[c];
    const float sc0 = bnp[c],     sh0 = bnp[64+c];
    const float sc1 = bnp[128+c], sh1 = bnp[192+c];
    const float sc2 = bnp[256+c], sh2 = bnp[320+c];
    __syncthreads();
    // -------- Phase A: weights --------
    for (int rt = 0; rt < 32; ++rt) {
        const int rowg = rt * 8 + rq;
        const int ci = rowg >> 5, k = rowg & 31;
        if (c < 3) {
            const int id = idxs[ci][k];
            gxs[rq][c] = xyz[((size_t)b * NPTS + id) * 3 + c] - qs[ci][c];
        }
        __syncthreads();
        const float t0 = gxs[rq][0]*w0s[c] + gxs[rq][1]*w0s[64+c] + gxs[rq][2]*w0s[128+c] + b0c;
        hb1[rq][c] = fmaxf(sc0*t0 + sh0, 0.f);
        __syncthreads();
        float t1 = b1c;
        #pragma unroll
        for (int j = 0; j < 64; ++j) t1 += hb1[rq][j] * w1s[j*64 + c];
        hb2[rq][c] = fmaxf(sc1*t1 + sh1, 0.f);
        __syncthreads();
        float t2 = b2c;
        #pragma unroll
        for (int j = 0; j < 64; ++j) t2 += hb2[rq][j] * w2s[j*64 + c];
        wt[ci][k][c] = fmaxf(sc2*t2 + sh2, 0.f);
        __syncthreads();
    }
    // -------- Phase B: nf + final gemm --------
    float yacc = bf[c];
    for (int d = 0; d < 64; ++d) {
        for (int i = tid; i < 4096; i += 512) wfs[i] = wf[(size_t)d * 4096 + i];
        if (tid < 256) {
            const int ci = tid >> 5, k = tid & 31;
            gfd[ci][k] = feat[((size_t)(b * 64 + d)) * NPTS + idxs[ci][k]];
        }
        __syncthreads();
        float v = 0.f;
        #pragma unroll
        for (int k2 = 0; k2 < 32; ++k2) v += gfd[rq][k2] * wt[rq][k2][c];
        nfs[rq][c] = v;
        __syncthreads();
        #pragma unroll
        for (int w = 0; w < 64; ++w) yacc += nfs[rq][w] * wfs[w*64 + c];
        __syncthreads();
    }
    y[(size_t)(bs0 + rq) * 64 + c] = yacc;
}

__global__ __launch_bounds__(256) void ystats_kernel(const float* __restrict__ y,
                                                     double* __restrict__ st)
{
    const int tid = threadIdx.x;
    const int c = tid & 63;
    double s = 0.0, s2 = 0.0;
    for (int i = blockIdx.x * 256 + tid; i < NBATCH*NSAMP*64; i += gridDim.x * 256) {
        const float v = y[i];
        s += v; s2 += (double)v * (double)v;
    }
    __shared__ double rs[256], rs2[256];
    rs[tid] = s; rs2[tid] = s2;
    __syncthreads();
    if (tid < 64) {
        const double a  = rs[c]  + rs[64+c]  + rs[128+c]  + rs[192+c];
        const double a2 = rs2[c] + rs2[64+c] + rs2[128+c] + rs2[192+c];
        atomicAdd(&st[c], a);
        atomicAdd(&st[64 + c], a2);
    }
}

__global__ void writeout_kernel(const float* __restrict__ y,
                                const float* __restrict__ bnp3,
                                float* __restrict__ outp)
{
    const int i = blockIdx.x * 256 + threadIdx.x;
    if (i >= NBATCH * 64 * NSAMP) return;
    const int s = i & 1023;
    const int o = (i >> 10) & 63;
    const int bb = i >> 16;
    const float v = y[((size_t)(bb << 10) + s) * 64 + o];
    outp[i] = fmaxf(bnp3[o] * v + bnp3[64 + o], 0.f);
}

// ============================ launch ============================
extern "C" void kernel_launch(void* const* d_in, const int* in_sizes, int n_in,
                              void* d_out, int out_size, void* d_ws, size_t ws_size,
                              hipStream_t stream)
{
    (void)in_sizes; (void)n_in; (void)out_size; (void)ws_size;
    const float* xyz  = (const float*)d_in[0];
    const float* feat = (const float*)d_in[1];
    const float* w0   = (const float*)d_in[2];
    const float* b0   = (const float*)d_in[3];
    const float* g0   = (const float*)d_in[4];
    const float* be0  = (const float*)d_in[5];
    const float* w1   = (const float*)d_in[6];
    const float* b1   = (const float*)d_in[7];
    const float* g1   = (const float*)d_in[8];
    const float* be1  = (const float*)d_in[9];
    const float* w2   = (const float*)d_in[10];
    const float* b2   = (const float*)d_in[11];
    const float* g2   = (const float*)d_in[12];
    const float* be2  = (const float*)d_in[13];
    const float* wf   = (const float*)d_in[14];
    const float* bf   = (const float*)d_in[15];
    const float* gf   = (const float*)d_in[16];
    const float* bef  = (const float*)d_in[17];

    float* out = (float*)d_out;
    float* newxyz = out;                       // (B, S, 3)
    float* outmain = out + NBATCH * NSAMP * 3; // (B, 64, S)

    char* ws = (char*)d_ws;
    int*    idxws = (int*)ws;                                   // 2 MB
    float*  ybuf  = (float*)(ws + 2097152);                     // 4 MB
    double* stats = (double*)(ws + 2097152 + 4194304);          // 4 KB (4 layers x 2 x 64)
    float*  bnp   = (float*)(ws + 2097152 + 4194304 + 4096);    // 2 KB (4 layers x 2 x 64)

    zero_stats_kernel<<<2, 256, 0, stream>>>(stats);
    fps_kernel<<<NBATCH, 1024, 0, stream>>>(xyz, newxyz);
    knn_kernel<<<NBATCH * NSAMP, 256, 0, stream>>>(xyz, newxyz, idxws);

    lstats_kernel<0><<<2048, 256, 0, stream>>>(xyz, newxyz, idxws, w0, b0, w1, b1, w2, b2, bnp, stats);
    bn_finalize_kernel<<<1, 64, 0, stream>>>(stats, g0, be0, bnp, (float)NROWS);
    lstats_kernel<1><<<2048, 256, 0, stream>>>(xyz, newxyz, idxws, w0, b0, w1, b1, w2, b2, bnp, stats + 128);
    bn_finalize_kernel<<<1, 64, 0, stream>>>(stats + 128, g1, be1, bnp + 128, (float)NROWS);
    lstats_kernel<2><<<2048, 256, 0, stream>>>(xyz, newxyz, idxws, w0, b0, w1, b1, w2, b2, bnp, stats + 256);
    bn_finalize_kernel<<<1, 64, 0, stream>>>(stats + 256, g2, be2, bnp + 256, (float)NROWS);

    final_conv_kernel<<<NBATCH * NSAMP / 8, 512, 0, stream>>>(
        xyz, newxyz, idxws, feat, w0, b0, w1, b1, w2, b2, bnp, wf, bf, ybuf);

    ystats_kernel<<<256, 256, 0, stream>>>(ybuf, stats + 384);
    bn_finalize_kernel<<<1, 64, 0, stream>>>(stats + 384, gf, bef, bnp + 384, (float)(NBATCH * NSAMP));
    writeout_kernel<<<4096, 256, 0, stream>>>(ybuf, bnp + 384, outmain);
}

// Round 3
// 4420.590 us; speedup vs baseline: 1.0959x; 1.0959x over previous
//
#include <hip/hip_runtime.h>

#define NBATCH 16
#define NPTS   4096
#define NSAMP  1024
#define NKNN   32
#define NROWS  (NBATCH*NSAMP*NKNN)   // 524288
#define BN_EPS 1e-5f

// ============================ FPS ============================
// One block (256 thr) per batch. 16 pts/thread in registers; xyz staged in
// LDS for winner-coordinate broadcast. ONE barrier per iteration via
// parity-double-buffered reduction slots. Exact f32 semantics: no FMA
// contraction, argmax ties -> lowest index (validated bitwise in rounds 1-2).
__global__ __launch_bounds__(256) void fps_kernel(const float* __restrict__ xyz,
                                                  float* __restrict__ newxyz)
{
    const int b = blockIdx.x;
    const int tid = threadIdx.x;
    const float* xb = xyz + (size_t)b * NPTS * 3;
    __shared__ float xs[NPTS];
    __shared__ float ys[NPTS];
    __shared__ float zs[NPTS];
    __shared__ float red_v[2][4];
    __shared__ int   red_i[2][4];
    float px[16], py[16], pz[16], dmin[16];
    #pragma unroll
    for (int j = 0; j < 16; ++j) {
        const int p = tid + j * 256;
        const float x = xb[p*3+0], y = xb[p*3+1], z = xb[p*3+2];
        px[j] = x; py[j] = y; pz[j] = z;
        xs[p] = x; ys[p] = y; zs[p] = z;
        dmin[j] = 1e10f;
    }
    if (tid == 0) {
        float* o = newxyz + (size_t)b * NSAMP * 3;
        o[0] = xb[0]; o[1] = xb[1]; o[2] = xb[2];
    }
    __syncthreads();
    float lx = xs[0], ly = ys[0], lz = zs[0];
    for (int t = 1; t < NSAMP; ++t) {
        float bv = -1.0f; int bi = 0;
        #pragma unroll
        for (int j = 0; j < 16; ++j) {
            const float dx = __fsub_rn(px[j], lx);
            const float dy = __fsub_rn(py[j], ly);
            const float dz = __fsub_rn(pz[j], lz);
            const float d = __fadd_rn(__fadd_rn(__fmul_rn(dx,dx), __fmul_rn(dy,dy)), __fmul_rn(dz,dz));
            const float nd = fminf(dmin[j], d);
            dmin[j] = nd;
            const int gi = tid + j * 256;
            if (nd > bv || (nd == bv && gi < bi)) { bv = nd; bi = gi; }
        }
        #pragma unroll
        for (int m = 1; m < 64; m <<= 1) {
            const float ov = __shfl_xor(bv, m);
            const int   oi = __shfl_xor(bi, m);
            if (ov > bv || (ov == bv && oi < bi)) { bv = ov; bi = oi; }
        }
        const int par = t & 1;
        if ((tid & 63) == 0) { red_v[par][tid >> 6] = bv; red_i[par][tid >> 6] = bi; }
        __syncthreads();
        bv = red_v[par][0]; bi = red_i[par][0];
        #pragma unroll
        for (int w = 1; w < 4; ++w) {
            const float ov = red_v[par][w]; const int oi = red_i[par][w];
            if (ov > bv || (ov == bv && oi < bi)) { bv = ov; bi = oi; }
        }
        lx = xs[bi]; ly = ys[bi]; lz = zs[bi];
        if (tid == 0) {
            float* o = newxyz + ((size_t)b * NSAMP + t) * 3;
            o[0] = lx; o[1] = ly; o[2] = lz;
        }
    }
}

// ============================ kNN ============================
// One block (256 thr) per centroid. Distance = (qq - 2*dot) + xx with the dot
// as an FMA chain (matches reference einsum lowering — validated round 2).
__global__ __launch_bounds__(256) void knn_kernel(const float* __restrict__ xyz,
                                                  const float* __restrict__ newxyz,
                                                  int* __restrict__ idx_out)
{
    const int bs = blockIdx.x;
    const int b = bs >> 10;
    const int tid = threadIdx.x;
    __shared__ unsigned keys[NPTS];
    __shared__ int hist[256];
    __shared__ float qsh[3];
    __shared__ int ctrl[4];   // 0:prefix 1:rem 2:nless 3:ntie
    __shared__ int ties[128];
    if (tid < 3) qsh[tid] = newxyz[bs*3 + tid];
    if (tid == 0) { ctrl[0] = 0; ctrl[1] = NKNN; }
    __syncthreads();
    const float q0 = qsh[0], q1 = qsh[1], q2 = qsh[2];
    const float qq = __fadd_rn(__fadd_rn(__fmul_rn(q0,q0), __fmul_rn(q1,q1)), __fmul_rn(q2,q2));
    const float* xb = xyz + (size_t)b * NPTS * 3;
    for (int n = tid; n < NPTS; n += 256) {
        const float x0 = xb[n*3+0], x1 = xb[n*3+1], x2 = xb[n*3+2];
        const float xx = __fadd_rn(__fadd_rn(__fmul_rn(x0,x0), __fmul_rn(x1,x1)), __fmul_rn(x2,x2));
        float dt = __fmul_rn(q0, x0);
        dt = __fmaf_rn(q1, x1, dt);
        dt = __fmaf_rn(q2, x2, dt);
        const float dd = __fadd_rn(__fsub_rn(qq, __fmul_rn(2.0f, dt)), xx);
        unsigned ub = __float_as_uint(dd);
        ub = (ub & 0x80000000u) ? ~ub : (ub | 0x80000000u);
        keys[n] = ub;
    }
    for (int p = 3; p >= 0; --p) {
        __syncthreads();
        hist[tid] = 0;
        __syncthreads();
        const unsigned pre = (unsigned)ctrl[0];
        const int shift = p * 8;
        const unsigned himask = (p == 3) ? 0u : (0xFFFFFFFFu << ((p + 1) * 8));
        for (int n = tid; n < NPTS; n += 256) {
            const unsigned k = keys[n];
            if ((k & himask) == pre) atomicAdd(&hist[(k >> shift) & 255], 1);
        }
        __syncthreads();
        if (tid == 0) {
            int r = ctrl[1]; unsigned pf = (unsigned)ctrl[0];
            for (int bin = 0; bin < 256; ++bin) {
                const int cnt = hist[bin];
                if (r > cnt) r -= cnt;
                else { pf |= ((unsigned)bin) << shift; break; }
            }
            ctrl[0] = (int)pf; ctrl[1] = r;
        }
    }
    __syncthreads();
    const unsigned T = (unsigned)ctrl[0];
    if (tid == 0) { ctrl[2] = 0; ctrl[3] = 0; }
    __syncthreads();
    int* out = idx_out + (size_t)bs * NKNN;
    for (int n = tid; n < NPTS; n += 256) {
        const unsigned k = keys[n];
        if (k < T) {
            const int pos = atomicAdd(&ctrl[2], 1);
            if (pos < NKNN) out[pos] = n;
        } else if (k == T) {
            const int pos = atomicAdd(&ctrl[3], 1);
            if (pos < 128) ties[pos] = n;
        }
    }
    __syncthreads();
    if (tid == 0) {
        const int nless = ctrl[2] < NKNN ? ctrl[2] : NKNN;
        const int need = NKNN - nless;
        const int ntie = ctrl[3] < 128 ? ctrl[3] : 128;
        int last = -1;
        for (int j = 0; j < need; ++j) {
            int best = 0x7fffffff;
            for (int i = 0; i < ntie; ++i) {
                const int v = ties[i];
                if (v > last && v < best) best = v;
            }
            out[nless + j] = (best == 0x7fffffff) ? 0 : best;
            last = best;
        }
    }
}

// ============================ stats helpers ============================
__global__ void zero_stats_kernel(double* st)
{
    const int i = blockIdx.x * 256 + threadIdx.x;
    if (i < 512) st[i] = 0.0;
}

template<int L>
__global__ __launch_bounds__(256) void lstats_kernel(
    const float* __restrict__ xyz, const float* __restrict__ newxyz,
    const int* __restrict__ idxws,
    const float* __restrict__ w0, const float* __restrict__ b0,
    const float* __restrict__ w1, const float* __restrict__ b1,
    const float* __restrict__ w2, const float* __restrict__ b2,
    const float* __restrict__ bnp, double* __restrict__ stats)
{
    __shared__ float w1s[64*64];
    __shared__ float w2s[64*64];
    __shared__ float w0s[192];
    __shared__ float gxs[4][3];
    __shared__ float hb1[4][64];
    __shared__ float hb2[4][64];
    __shared__ double rs[256];
    __shared__ double rs2[256];
    const int tid = threadIdx.x;
    const int c = tid & 63;
    const int rq = tid >> 6;
    if (tid < 192) w0s[tid] = w0[tid];
    if (L >= 1) for (int i = tid; i < 4096; i += 256) w1s[i] = w1[i];
    if (L >= 2) for (int i = tid; i < 4096; i += 256) w2s[i] = w2[i];
    const float b0c = b0[c];
    float b1c = 0.f, b2c = 0.f, sc0 = 0.f, sh0 = 0.f, sc1 = 0.f, sh1 = 0.f;
    if (L >= 1) { b1c = b1[c]; sc0 = bnp[c]; sh0 = bnp[64+c]; }
    if (L >= 2) { b2c = b2[c]; sc1 = bnp[128+c]; sh1 = bnp[192+c]; }
    __syncthreads();
    double s = 0.0, s2 = 0.0;
    const int tiles = NROWS / 4;
    for (int tile = blockIdx.x; tile < tiles; tile += gridDim.x) {
        const int row = tile * 4 + rq;
        if (c < 3) {
            const int bs = row >> 5;
            const int bb = row >> 15;
            const int id = idxws[row];
            gxs[rq][c] = xyz[((size_t)bb * NPTS + id) * 3 + c] - newxyz[bs*3 + c];
        }
        __syncthreads();
        const float t0 = gxs[rq][0]*w0s[c] + gxs[rq][1]*w0s[64+c] + gxs[rq][2]*w0s[128+c] + b0c;
        if (L == 0) {
            s += t0; s2 += (double)t0 * (double)t0;
        } else {
            hb1[rq][c] = fmaxf(sc0*t0 + sh0, 0.0f);
            __syncthreads();
            float t1 = b1c;
            #pragma unroll
            for (int j = 0; j < 64; ++j) t1 += hb1[rq][j] * w1s[j*64 + c];
            if (L == 1) {
                s += t1; s2 += (double)t1 * (double)t1;
            } else {
                hb2[rq][c] = fmaxf(sc1*t1 + sh1, 0.0f);
                __syncthreads();
                float t2 = b2c;
                #pragma unroll
                for (int j = 0; j < 64; ++j) t2 += hb2[rq][j] * w2s[j*64 + c];
                s += t2; s2 += (double)t2 * (double)t2;
            }
        }
        __syncthreads();
    }
    rs[tid] = s; rs2[tid] = s2;
    __syncthreads();
    if (tid < 64) {
        const double a  = rs[c]  + rs[64+c]  + rs[128+c]  + rs[192+c];
        const double a2 = rs2[c] + rs2[64+c] + rs2[128+c] + rs2[192+c];
        atomicAdd(&stats[c], a);
        atomicAdd(&stats[64 + c], a2);
    }
}

__global__ void bn_finalize_kernel(const double* __restrict__ st,
                                   const float* __restrict__ g,
                                   const float* __restrict__ be,
                                   float* __restrict__ outp, float n)
{
    const int c = threadIdx.x;  // 64
    const double m = st[c] / (double)n;
    const double var = st[64 + c] / (double)n - m * m;
    const float scale = g[c] * rsqrtf((float)var + BN_EPS);
    outp[c] = scale;
    outp[64 + c] = be[c] - (float)m * scale;
}

// ============================ final fused conv ============================
// Block = 256 thr, 4 centroids. LDS union: phase-A w1s/w2s aliased with
// phase-B double-buffered wfs/gfd/nfs. Phase B: 1 barrier per d-iteration.
// ~73 KB LDS -> 2 blocks/CU.
__global__ __launch_bounds__(256) void final_conv_kernel(
    const float* __restrict__ xyz, const float* __restrict__ newxyz,
    const int* __restrict__ idxws, const float* __restrict__ feat,
    const float* __restrict__ w0, const float* __restrict__ b0,
    const float* __restrict__ w1, const float* __restrict__ b1,
    const float* __restrict__ w2, const float* __restrict__ b2,
    const float* __restrict__ bnp, const float* __restrict__ wf,
    const float* __restrict__ bf, float* __restrict__ y)
{
    __shared__ float wt[4][32][64];    // 32 KB persistent
    __shared__ float uni[8960];        // 35 KB union region
    __shared__ float hb1[4][64];
    __shared__ float hb2[4][64];
    __shared__ int   idxs[4][32];
    __shared__ float qs[4][3];
    __shared__ float gxs[4][3];
    __shared__ float w0s[192];
    float* w1s = uni;                                   // phase A: [4096]
    float* w2s = uni + 4096;                            // phase A: [4096]
    float (*wfs)[4096]   = (float (*)[4096])uni;        // phase B: [2][4096]
    float (*gfd)[4][32]  = (float (*)[4][32])(uni + 8192);   // [2][4][32]
    float (*nfs)[4][64]  = (float (*)[4][64])(uni + 8448);   // [2][4][64]
    const int tid = threadIdx.x;
    const int c = tid & 63;
    const int rq = tid >> 6;          // 0..3
    const int bs0 = blockIdx.x * 4;
    const int b = bs0 >> 10;
    if (tid < 128) idxs[tid >> 5][tid & 31] = idxws[(size_t)bs0 * NKNN + tid];
    if (tid < 12)  qs[tid / 3][tid % 3] = newxyz[(bs0 + tid/3)*3 + (tid % 3)];
    if (tid < 192) w0s[tid] = w0[tid];
    for (int i = tid; i < 4096; i += 256) { w1s[i] = w1[i]; w2s[i] = w2[i]; }
    const float b0c = b0[c], b1c = b1[c], b2c = b2[c];
    const float sc0 = bnp[c],     sh0 = bnp[64+c];
    const float sc1 = bnp[128+c], sh1 = bnp[192+c];
    const float sc2 = bnp[256+c], sh2 = bnp[320+c];
    __syncthreads();
    // -------- Phase A: weightnet -> wt[4][32][64] --------
    for (int rt = 0; rt < 32; ++rt) {
        const int rowg = rt * 4 + rq;
        const int ci = rowg >> 5, k = rowg & 31;
        if (c < 3) {
            const int id = idxs[ci][k];
            gxs[rq][c] = xyz[((size_t)b * NPTS + id) * 3 + c] - qs[ci][c];
        }
        __syncthreads();
        const float t0 = gxs[rq][0]*w0s[c] + gxs[rq][1]*w0s[64+c] + gxs[rq][2]*w0s[128+c] + b0c;
        hb1[rq][c] = fmaxf(sc0*t0 + sh0, 0.f);
        __syncthreads();
        float t1 = b1c;
        #pragma unroll
        for (int j = 0; j < 64; ++j) t1 += hb1[rq][j] * w1s[j*64 + c];
        hb2[rq][c] = fmaxf(sc1*t1 + sh1, 0.f);
        __syncthreads();
        float t2 = b2c;
        #pragma unroll
        for (int j = 0; j < 64; ++j) t2 += hb2[rq][j] * w2s[j*64 + c];
        wt[ci][k][c] = fmaxf(sc2*t2 + sh2, 0.f);
        __syncthreads();
    }
    // -------- Phase B: nf + final gemm (double-buffered, 1 barrier/iter) ----
    float yacc = bf[c];
    for (int i = tid; i < 4096; i += 256) wfs[0][i] = wf[i];
    if (tid < 128) {
        const int ci = tid >> 5, k = tid & 31;
        gfd[0][ci][k] = feat[(size_t)(b * 64 + 0) * NPTS + idxs[ci][k]];
    }
    __syncthreads();
    for (int d = 0; d < 64; ++d) {
        const int p = d & 1, q = p ^ 1;
        if (d < 63) {
            for (int i = tid; i < 4096; i += 256) wfs[q][i] = wf[(size_t)(d+1) * 4096 + i];
            if (tid < 128) {
                const int ci = tid >> 5, k = tid & 31;
                gfd[q][ci][k] = feat[(size_t)(b * 64 + d + 1) * NPTS + idxs[ci][k]];
            }
        }
        float v = 0.f;
        #pragma unroll
        for (int k2 = 0; k2 < 32; ++k2) v += gfd[p][rq][k2] * wt[rq][k2][c];
        nfs[p][rq][c] = v;
        __syncthreads();
        #pragma unroll
        for (int w = 0; w < 64; ++w) yacc += nfs[p][rq][w] * wfs[p][w*64 + c];
    }
    y[(size_t)(bs0 + rq) * 64 + c] = yacc;
}

__global__ __launch_bounds__(256) void ystats_kernel(const float* __restrict__ y,
                                                     double* __restrict__ st)
{
    const int tid = threadIdx.x;
    const int c = tid & 63;
    double s = 0.0, s2 = 0.0;
    for (int i = blockIdx.x * 256 + tid; i < NBATCH*NSAMP*64; i += gridDim.x * 256) {
        const float v = y[i];
        s += v; s2 += (double)v * (double)v;
    }
    __shared__ double rs[256], rs2[256];
    rs[tid] = s; rs2[tid] = s2;
    __syncthreads();
    if (tid < 64) {
        const double a  = rs[c]  + rs[64+c]  + rs[128+c]  + rs[192+c];
        const double a2 = rs2[c] + rs2[64+c] + rs2[128+c] + rs2[192+c];
        atomicAdd(&st[c], a);
        atomicAdd(&st[64 + c], a2);
    }
}

__global__ void writeout_kernel(const float* __restrict__ y,
                                const float* __restrict__ bnp3,
                                float* __restrict__ outp)
{
    const int i = blockIdx.x * 256 + threadIdx.x;
    if (i >= NBATCH * 64 * NSAMP) return;
    const int s = i & 1023;
    const int o = (i >> 10) & 63;
    const int bb = i >> 16;
    const float v = y[((size_t)(bb << 10) + s) * 64 + o];
    outp[i] = fmaxf(bnp3[o] * v + bnp3[64 + o], 0.f);
}

// ============================ launch ============================
extern "C" void kernel_launch(void* const* d_in, const int* in_sizes, int n_in,
                              void* d_out, int out_size, void* d_ws, size_t ws_size,
                              hipStream_t stream)
{
    (void)in_sizes; (void)n_in; (void)out_size; (void)ws_size;
    const float* xyz  = (const float*)d_in[0];
    const float* feat = (const float*)d_in[1];
    const float* w0   = (const float*)d_in[2];
    const float* b0   = (const float*)d_in[3];
    const float* g0   = (const float*)d_in[4];
    const float* be0  = (const float*)d_in[5];
    const float* w1   = (const float*)d_in[6];
    const float* b1   = (const float*)d_in[7];
    const float* g1   = (const float*)d_in[8];
    const float* be1  = (const float*)d_in[9];
    const float* w2   = (const float*)d_in[10];
    const float* b2   = (const float*)d_in[11];
    const float* g2   = (const float*)d_in[12];
    const float* be2  = (const float*)d_in[13];
    const float* wf   = (const float*)d_in[14];
    const float* bf   = (const float*)d_in[15];
    const float* gf   = (const float*)d_in[16];
    const float* bef  = (const float*)d_in[17];

    float* out = (float*)d_out;
    float* newxyz = out;                       // (B, S, 3)
    float* outmain = out + NBATCH * NSAMP * 3; // (B, 64, S)

    char* ws = (char*)d_ws;
    int*    idxws = (int*)ws;                                   // 2 MB
    float*  ybuf  = (float*)(ws + 2097152);                     // 4 MB
    double* stats = (double*)(ws + 2097152 + 4194304);          // 4 KB
    float*  bnp   = (float*)(ws + 2097152 + 4194304 + 4096);    // 2 KB

    zero_stats_kernel<<<2, 256, 0, stream>>>(stats);
    fps_kernel<<<NBATCH, 256, 0, stream>>>(xyz, newxyz);
    knn_kernel<<<NBATCH * NSAMP, 256, 0, stream>>>(xyz, newxyz, idxws);

    lstats_kernel<0><<<2048, 256, 0, stream>>>(xyz, newxyz, idxws, w0, b0, w1, b1, w2, b2, bnp, stats);
    bn_finalize_kernel<<<1, 64, 0, stream>>>(stats, g0, be0, bnp, (float)NROWS);
    lstats_kernel<1><<<2048, 256, 0, stream>>>(xyz, newxyz, idxws, w0, b0, w1, b1, w2, b2, bnp, stats + 128);
    bn_finalize_kernel<<<1, 64, 0, stream>>>(stats + 128, g1, be1, bnp + 128, (float)NROWS);
    lstats_kernel<2><<<2048, 256, 0, stream>>>(xyz, newxyz, idxws, w0, b0, w1, b1, w2, b2, bnp, stats + 256);
    bn_finalize_kernel<<<1, 64, 0, stream>>>(stats + 256, g2, be2, bnp + 256, (float)NROWS);

    final_conv_kernel<<<NBATCH * NSAMP / 4, 256, 0, stream>>>(
        xyz, newxyz, idxws, feat, w0, b0, w1, b1, w2, b2, bnp, wf, bf, ybuf);

    ystats_kernel<<<256, 256, 0, stream>>>(ybuf, stats + 384);
    bn_finalize_kernel<<<1, 64, 0, stream>>>(stats + 384, gf, bef, bnp + 384, (float)(NBATCH * NSAMP));
    writeout_kernel<<<4096, 256, 0, stream>>>(ybuf, bnp + 384, outmain);
}

// Round 4
// 3597.408 us; speedup vs baseline: 1.3467x; 1.2288x over previous
//
#include <hip/hip_runtime.h>

#define NBATCH 16
#define NPTS   4096
#define NSAMP  1024
#define NKNN   32
#define NROWS  (NBATCH*NSAMP*NKNN)   // 524288
#define BN_EPS 1e-5f

__device__ __forceinline__ unsigned pack_bf16pair(float a, float b) {
    unsigned ua = __float_as_uint(a); ua += 0x7FFFu + ((ua >> 16) & 1u);
    unsigned ub = __float_as_uint(b); ub += 0x7FFFu + ((ub >> 16) & 1u);
    return (ua >> 16) | (ub & 0xFFFF0000u);
}
__device__ __forceinline__ float bfp_lo(unsigned u) { return __uint_as_float(u << 16); }
__device__ __forceinline__ float bfp_hi(unsigned u) { return __uint_as_float(u & 0xFFFF0000u); }

// ============================ FPS ============================
// (validated bitwise rounds 1-3 — arithmetic untouched)
__global__ __launch_bounds__(256) void fps_kernel(const float* __restrict__ xyz,
                                                  float* __restrict__ newxyz)
{
    const int b = blockIdx.x;
    const int tid = threadIdx.x;
    const float* xb = xyz + (size_t)b * NPTS * 3;
    __shared__ float xs[NPTS];
    __shared__ float ys[NPTS];
    __shared__ float zs[NPTS];
    __shared__ float red_v[2][4];
    __shared__ int   red_i[2][4];
    float px[16], py[16], pz[16], dmin[16];
    #pragma unroll
    for (int j = 0; j < 16; ++j) {
        const int p = tid + j * 256;
        const float x = xb[p*3+0], y = xb[p*3+1], z = xb[p*3+2];
        px[j] = x; py[j] = y; pz[j] = z;
        xs[p] = x; ys[p] = y; zs[p] = z;
        dmin[j] = 1e10f;
    }
    if (tid == 0) {
        float* o = newxyz + (size_t)b * NSAMP * 3;
        o[0] = xb[0]; o[1] = xb[1]; o[2] = xb[2];
    }
    __syncthreads();
    float lx = xs[0], ly = ys[0], lz = zs[0];
    for (int t = 1; t < NSAMP; ++t) {
        float bv = -1.0f; int bi = 0;
        #pragma unroll
        for (int j = 0; j < 16; ++j) {
            const float dx = __fsub_rn(px[j], lx);
            const float dy = __fsub_rn(py[j], ly);
            const float dz = __fsub_rn(pz[j], lz);
            const float d = __fadd_rn(__fadd_rn(__fmul_rn(dx,dx), __fmul_rn(dy,dy)), __fmul_rn(dz,dz));
            const float nd = fminf(dmin[j], d);
            dmin[j] = nd;
            const int gi = tid + j * 256;
            if (nd > bv || (nd == bv && gi < bi)) { bv = nd; bi = gi; }
        }
        #pragma unroll
        for (int m = 1; m < 64; m <<= 1) {
            const float ov = __shfl_xor(bv, m);
            const int   oi = __shfl_xor(bi, m);
            if (ov > bv || (ov == bv && oi < bi)) { bv = ov; bi = oi; }
        }
        const int par = t & 1;
        if ((tid & 63) == 0) { red_v[par][tid >> 6] = bv; red_i[par][tid >> 6] = bi; }
        __syncthreads();
        bv = red_v[par][0]; bi = red_i[par][0];
        #pragma unroll
        for (int w = 1; w < 4; ++w) {
            const float ov = red_v[par][w]; const int oi = red_i[par][w];
            if (ov > bv || (ov == bv && oi < bi)) { bv = ov; bi = oi; }
        }
        lx = xs[bi]; ly = ys[bi]; lz = zs[bi];
        if (tid == 0) {
            float* o = newxyz + ((size_t)b * NSAMP + t) * 3;
            o[0] = lx; o[1] = ly; o[2] = lz;
        }
    }
}

// ============================ kNN ============================
// (validated rounds 2-3 — FMA-chain dot, radix select, tie->lowest index)
__global__ __launch_bounds__(256) void knn_kernel(const float* __restrict__ xyz,
                                                  const float* __restrict__ newxyz,
                                                  int* __restrict__ idx_out)
{
    const int bs = blockIdx.x;
    const int b = bs >> 10;
    const int tid = threadIdx.x;
    __shared__ unsigned keys[NPTS];
    __shared__ int hist[256];
    __shared__ float qsh[3];
    __shared__ int ctrl[4];
    __shared__ int ties[128];
    if (tid < 3) qsh[tid] = newxyz[bs*3 + tid];
    if (tid == 0) { ctrl[0] = 0; ctrl[1] = NKNN; }
    __syncthreads();
    const float q0 = qsh[0], q1 = qsh[1], q2 = qsh[2];
    const float qq = __fadd_rn(__fadd_rn(__fmul_rn(q0,q0), __fmul_rn(q1,q1)), __fmul_rn(q2,q2));
    const float* xb = xyz + (size_t)b * NPTS * 3;
    for (int n = tid; n < NPTS; n += 256) {
        const float x0 = xb[n*3+0], x1 = xb[n*3+1], x2 = xb[n*3+2];
        const float xx = __fadd_rn(__fadd_rn(__fmul_rn(x0,x0), __fmul_rn(x1,x1)), __fmul_rn(x2,x2));
        float dt = __fmul_rn(q0, x0);
        dt = __fmaf_rn(q1, x1, dt);
        dt = __fmaf_rn(q2, x2, dt);
        const float dd = __fadd_rn(__fsub_rn(qq, __fmul_rn(2.0f, dt)), xx);
        unsigned ub = __float_as_uint(dd);
        ub = (ub & 0x80000000u) ? ~ub : (ub | 0x80000000u);
        keys[n] = ub;
    }
    for (int p = 3; p >= 0; --p) {
        __syncthreads();
        hist[tid] = 0;
        __syncthreads();
        const unsigned pre = (unsigned)ctrl[0];
        const int shift = p * 8;
        const unsigned himask = (p == 3) ? 0u : (0xFFFFFFFFu << ((p + 1) * 8));
        for (int n = tid; n < NPTS; n += 256) {
            const unsigned k = keys[n];
            if ((k & himask) == pre) atomicAdd(&hist[(k >> shift) & 255], 1);
        }
        __syncthreads();
        if (tid == 0) {
            int r = ctrl[1]; unsigned pf = (unsigned)ctrl[0];
            for (int bin = 0; bin < 256; ++bin) {
                const int cnt = hist[bin];
                if (r > cnt) r -= cnt;
                else { pf |= ((unsigned)bin) << shift; break; }
            }
            ctrl[0] = (int)pf; ctrl[1] = r;
        }
    }
    __syncthreads();
    const unsigned T = (unsigned)ctrl[0];
    if (tid == 0) { ctrl[2] = 0; ctrl[3] = 0; }
    __syncthreads();
    int* out = idx_out + (size_t)bs * NKNN;
    for (int n = tid; n < NPTS; n += 256) {
        const unsigned k = keys[n];
        if (k < T) {
            const int pos = atomicAdd(&ctrl[2], 1);
            if (pos < NKNN) out[pos] = n;
        } else if (k == T) {
            const int pos = atomicAdd(&ctrl[3], 1);
            if (pos < 128) ties[pos] = n;
        }
    }
    __syncthreads();
    if (tid == 0) {
        const int nless = ctrl[2] < NKNN ? ctrl[2] : NKNN;
        const int need = NKNN - nless;
        const int ntie = ctrl[3] < 128 ? ctrl[3] : 128;
        int last = -1;
        for (int j = 0; j < need; ++j) {
            int best = 0x7fffffff;
            for (int i = 0; i < ntie; ++i) {
                const int v = ties[i];
                if (v > last && v < best) best = v;
            }
            out[nless + j] = (best == 0x7fffffff) ? 0 : best;
            last = best;
        }
    }
}

// ============================ stats helpers ============================
__global__ void zero_stats_kernel(double* st)
{
    const int i = blockIdx.x * 256 + threadIdx.x;
    if (i < 512) st[i] = 0.0;
}

// BN0 stats via moments: t0 is affine in gx, so only Sgx (3) + S gx gx^T (6).
__global__ __launch_bounds__(256) void gxmoments_kernel(
    const float* __restrict__ xyz, const float* __restrict__ newxyz,
    const int* __restrict__ idxws, double* __restrict__ stats)
{
    const int tid = threadIdx.x;
    double m[9];
    #pragma unroll
    for (int i = 0; i < 9; ++i) m[i] = 0.0;
    for (int row = blockIdx.x * 256 + tid; row < NROWS; row += gridDim.x * 256) {
        const int bs = row >> 5;
        const int bb = row >> 15;
        const int id = idxws[row];
        const float* xp = xyz + ((size_t)bb * NPTS + id) * 3;
        const float* qp = newxyz + bs * 3;
        const float gx = xp[0] - qp[0];
        const float gy = xp[1] - qp[1];
        const float gz = xp[2] - qp[2];
        const double dx = gx, dy = gy, dz = gz;
        m[0] += dx; m[1] += dy; m[2] += dz;
        m[3] += dx*dx; m[4] += dx*dy; m[5] += dx*dz;
        m[6] += dy*dy; m[7] += dy*dz; m[8] += dz*dz;
    }
    #pragma unroll
    for (int i = 0; i < 9; ++i) {
        #pragma unroll
        for (int s = 1; s < 64; s <<= 1) m[i] += __shfl_xor(m[i], s);
    }
    __shared__ double part[4][9];
    if ((tid & 63) == 0) {
        #pragma unroll
        for (int i = 0; i < 9; ++i) part[tid >> 6][i] = m[i];
    }
    __syncthreads();
    if (tid < 9) atomicAdd(&stats[tid], part[0][tid] + part[1][tid] + part[2][tid] + part[3][tid]);
}

__global__ void bn0_moments_finalize_kernel(const double* __restrict__ st,
    const float* __restrict__ w0, const float* __restrict__ b0,
    const float* __restrict__ g0, const float* __restrict__ be0,
    float* __restrict__ outp)
{
    const int c = threadIdx.x;  // 64
    const double N = (double)NROWS;
    const double w0c = w0[c], w1c = w0[64 + c], w2c = w0[128 + c];
    const double b = b0[c];
    const double dotS = st[0]*w0c + st[1]*w1c + st[2]*w2c;
    const double qf = w0c*w0c*st[3] + w1c*w1c*st[6] + w2c*w2c*st[8]
                    + 2.0*(w0c*w1c*st[4] + w0c*w2c*st[5] + w1c*w2c*st[7]);
    const double mean = dotS / N + b;
    const double ex2 = (qf + 2.0*b*dotS) / N + b*b;
    const double var = ex2 - mean*mean;
    const float scale = g0[c] * rsqrtf((float)var + BN_EPS);
    outp[c] = scale;
    outp[64 + c] = be0[c] - (float)mean * scale;
}

// Recompute MLP chain to layer L (1 or 2); per-channel sum/sumsq of pre-BN act.
// 8 rows/tile, 2 rows/thread sharing weight reads; h via uniform float4.
template<int L>
__global__ __launch_bounds__(256) void lstats_kernel(
    const float* __restrict__ xyz, const float* __restrict__ newxyz,
    const int* __restrict__ idxws,
    const float* __restrict__ w0, const float* __restrict__ b0,
    const float* __restrict__ w1, const float* __restrict__ b1,
    const float* __restrict__ w2, const float* __restrict__ b2,
    const float* __restrict__ bnp, double* __restrict__ stats)
{
    __shared__ __align__(16) float w1s[4096];
    __shared__ __align__(16) float w2s[4096];
    __shared__ float w0s[192];
    __shared__ float gxs[8][3];
    __shared__ __align__(16) float hb1[8][64];
    __shared__ __align__(16) float hb2[8][64];
    __shared__ double rs[256], rs2[256];
    const int tid = threadIdx.x;
    const int c = tid & 63;
    const int rq = tid >> 6;
    const int s0v = rq * 2, s1v = rq * 2 + 1;
    if (tid < 192) w0s[tid] = w0[tid];
    for (int i = tid; i < 4096; i += 256) w1s[i] = w1[i];
    if (L >= 2) for (int i = tid; i < 4096; i += 256) w2s[i] = w2[i];
    const float b0c = b0[c];
    const float b1c = b1[c], sc0 = bnp[c], sh0 = bnp[64+c];
    float b2c = 0.f, sc1 = 0.f, sh1 = 0.f;
    if (L >= 2) { b2c = b2[c]; sc1 = bnp[128+c]; sh1 = bnp[192+c]; }
    __syncthreads();
    double s = 0.0, s2 = 0.0;
    const int ntiles = NROWS / 8;
    for (int tile = blockIdx.x; tile < ntiles; tile += gridDim.x) {
        if (tid < 24) {
            const int slot = tid / 3, cc = tid % 3;
            const int row = tile * 8 + slot;
            const int bs = row >> 5;
            const int bb = row >> 15;
            const int id = idxws[row];
            gxs[slot][cc] = xyz[((size_t)bb * NPTS + id) * 3 + cc] - newxyz[bs*3 + cc];
        }
        __syncthreads();
        {
            const float t00 = gxs[s0v][0]*w0s[c] + gxs[s0v][1]*w0s[64+c] + gxs[s0v][2]*w0s[128+c] + b0c;
            const float t01 = gxs[s1v][0]*w0s[c] + gxs[s1v][1]*w0s[64+c] + gxs[s1v][2]*w0s[128+c] + b0c;
            hb1[s0v][c] = fmaxf(sc0*t00 + sh0, 0.f);
            hb1[s1v][c] = fmaxf(sc0*t01 + sh0, 0.f);
        }
        __syncthreads();
        float t10 = b1c, t11 = b1c;
        {
            const float4* h0p = (const float4*)&hb1[s0v][0];
            const float4* h1p = (const float4*)&hb1[s1v][0];
            #pragma unroll
            for (int j4 = 0; j4 < 16; ++j4) {
                const float4 h0 = h0p[j4], h1 = h1p[j4];
                const float* wr = &w1s[j4*256 + c];
                const float wv0 = wr[0], wv1 = wr[64], wv2 = wr[128], wv3 = wr[192];
                t10 += h0.x*wv0 + h0.y*wv1 + h0.z*wv2 + h0.w*wv3;
                t11 += h1.x*wv0 + h1.y*wv1 + h1.z*wv2 + h1.w*wv3;
            }
        }
        if (L == 1) {
            s  += (double)t10 + (double)t11;
            s2 += (double)t10*(double)t10 + (double)t11*(double)t11;
            __syncthreads();
        } else {
            hb2[s0v][c] = fmaxf(sc1*t10 + sh1, 0.f);
            hb2[s1v][c] = fmaxf(sc1*t11 + sh1, 0.f);
            __syncthreads();
            float t20 = b2c, t21 = b2c;
            const float4* h0p = (const float4*)&hb2[s0v][0];
            const float4* h1p = (const float4*)&hb2[s1v][0];
            #pragma unroll
            for (int j4 = 0; j4 < 16; ++j4) {
                const float4 h0 = h0p[j4], h1 = h1p[j4];
                const float* wr = &w2s[j4*256 + c];
                const float wv0 = wr[0], wv1 = wr[64], wv2 = wr[128], wv3 = wr[192];
                t20 += h0.x*wv0 + h0.y*wv1 + h0.z*wv2 + h0.w*wv3;
                t21 += h1.x*wv0 + h1.y*wv1 + h1.z*wv2 + h1.w*wv3;
            }
            s  += (double)t20 + (double)t21;
            s2 += (double)t20*(double)t20 + (double)t21*(double)t21;
            __syncthreads();
        }
    }
    rs[tid] = s; rs2[tid] = s2;
    __syncthreads();
    if (tid < 64) {
        const double a  = rs[c]  + rs[64+c]  + rs[128+c]  + rs[192+c];
        const double a2 = rs2[c] + rs2[64+c] + rs2[128+c] + rs2[192+c];
        atomicAdd(&stats[c], a);
        atomicAdd(&stats[64 + c], a2);
    }
}

__global__ void bn_finalize_kernel(const double* __restrict__ st,
                                   const float* __restrict__ g,
                                   const float* __restrict__ be,
                                   float* __restrict__ outp, float n)
{
    const int c = threadIdx.x;  // 64
    const double m = st[c] / (double)n;
    const double var = st[64 + c] / (double)n - m * m;
    const float scale = g[c] * rsqrtf((float)var + BN_EPS);
    outp[c] = scale;
    outp[64 + c] = be[c] - (float)m * scale;
}

// ============================ final fused conv ============================
// 256 thr, 8 centroids/block. Phase A: weightnet -> bf16-pair-packed wt (32KB).
// Phase B: paired centroids per thread share all wfs reads; staged loads split
// issue-early/write-late across the two barriers per d (race-free by design).
__global__ __launch_bounds__(256) void final_conv_kernel(
    const float* __restrict__ xyz, const float* __restrict__ newxyz,
    const int* __restrict__ idxws, const float* __restrict__ feat,
    const float* __restrict__ w0, const float* __restrict__ b0,
    const float* __restrict__ w1, const float* __restrict__ b1,
    const float* __restrict__ w2, const float* __restrict__ b2,
    const float* __restrict__ bnp, const float* __restrict__ wf,
    const float* __restrict__ bf, float* __restrict__ y)
{
    __shared__ unsigned wtp[8][16][64];            // 32 KB packed bf16 pairs (k, k+1)
    __shared__ __align__(16) float uni[2][4096];   // 32 KB: A: w1s/w2s; B: wfs dbuf
    __shared__ __align__(16) float gfd[2][8][32];  // 2 KB dbuf
    __shared__ __align__(16) float nfs[8][64];     // 2 KB
    __shared__ __align__(16) float hb1[8][64];
    __shared__ __align__(16) float hb2[8][64];
    __shared__ int   idxs[8][32];
    __shared__ float qs[8][3];
    __shared__ float gxs[8][3];
    __shared__ float w0s[192];
    const int tid = threadIdx.x;
    const int c = tid & 63;
    const int rq = tid >> 6;          // 0..3
    const int eA = rq, eB = rq + 4;
    const int bs0 = blockIdx.x * 8;
    const int b = bs0 >> 10;
    idxs[tid >> 5][tid & 31] = idxws[(size_t)bs0 * NKNN + tid];
    if (tid < 24)  qs[tid / 3][tid % 3] = newxyz[(bs0 + tid/3)*3 + (tid % 3)];
    if (tid < 192) w0s[tid] = w0[tid];
    for (int i = tid; i < 4096; i += 256) { uni[0][i] = w1[i]; uni[1][i] = w2[i]; }
    const float b0c = b0[c], b1c = b1[c], b2c = b2[c];
    const float sc0 = bnp[c],     sh0 = bnp[64+c];
    const float sc1 = bnp[128+c], sh1 = bnp[192+c];
    const float sc2 = bnp[256+c], sh2 = bnp[320+c];
    __syncthreads();
    // -------- Phase A: weightnet (2 rows/thread) --------
    const int s0v = rq * 2, s1v = s0v + 1;
    for (int it = 0; it < 32; ++it) {
        if (tid < 24) {
            const int slot = tid / 3, cc = tid % 3;
            const int row = it * 8 + slot;
            const int e = row >> 5, k = row & 31;
            gxs[slot][cc] = xyz[((size_t)b * NPTS + idxs[e][k]) * 3 + cc] - qs[e][cc];
        }
        __syncthreads();
        {
            const float t00 = gxs[s0v][0]*w0s[c] + gxs[s0v][1]*w0s[64+c] + gxs[s0v][2]*w0s[128+c] + b0c;
            const float t01 = gxs[s1v][0]*w0s[c] + gxs[s1v][1]*w0s[64+c] + gxs[s1v][2]*w0s[128+c] + b0c;
            hb1[s0v][c] = fmaxf(sc0*t00 + sh0, 0.f);
            hb1[s1v][c] = fmaxf(sc0*t01 + sh0, 0.f);
        }
        __syncthreads();
        float t10 = b1c, t11 = b1c;
        {
            const float4* h0p = (const float4*)&hb1[s0v][0];
            const float4* h1p = (const float4*)&hb1[s1v][0];
            #pragma unroll
            for (int j4 = 0; j4 < 16; ++j4) {
                const float4 h0 = h0p[j4], h1 = h1p[j4];
                const float* wr = &uni[0][j4*256 + c];
                const float wv0 = wr[0], wv1 = wr[64], wv2 = wr[128], wv3 = wr[192];
                t10 += h0.x*wv0 + h0.y*wv1 + h0.z*wv2 + h0.w*wv3;
                t11 += h1.x*wv0 + h1.y*wv1 + h1.z*wv2 + h1.w*wv3;
            }
        }
        hb2[s0v][c] = fmaxf(sc1*t10 + sh1, 0.f);
        hb2[s1v][c] = fmaxf(sc1*t11 + sh1, 0.f);
        __syncthreads();
        float t20 = b2c, t21 = b2c;
        {
            const float4* h0p = (const float4*)&hb2[s0v][0];
            const float4* h1p = (const float4*)&hb2[s1v][0];
            #pragma unroll
            for (int j4 = 0; j4 < 16; ++j4) {
                const float4 h0 = h0p[j4], h1 = h1p[j4];
                const float* wr = &uni[1][j4*256 + c];
                const float wv0 = wr[0], wv1 = wr[64], wv2 = wr[128], wv3 = wr[192];
                t20 += h0.x*wv0 + h0.y*wv1 + h0.z*wv2 + h0.w*wv3;
                t21 += h1.x*wv0 + h1.y*wv1 + h1.z*wv2 + h1.w*wv3;
            }
        }
        {
            const int r0 = it * 8 + s0v;
            const int e0 = r0 >> 5, k0 = r0 & 31;
            wtp[e0][k0 >> 1][c] = pack_bf16pair(fmaxf(sc2*t20 + sh2, 0.f),
                                                fmaxf(sc2*t21 + sh2, 0.f));
        }
        __syncthreads();
    }
    // -------- Phase B: nf + final gemm --------
    {   // prologue: stage d=0
        const float4* src = (const float4*)wf;
        #pragma unroll
        for (int i = 0; i < 4; ++i) ((float4*)&uni[0][0])[tid + i*256] = src[tid + i*256];
        gfd[0][tid >> 5][tid & 31] = feat[(size_t)(b * 64 + 0) * NPTS + idxs[tid >> 5][tid & 31]];
    }
    __syncthreads();
    float yA = bf[c], yB = bf[c];
    for (int d = 0; d < 64; ++d) {
        const int p = d & 1, q = p ^ 1;
        float4 wfr0, wfr1, wfr2, wfr3; float gfr;
        if (d < 63) {   // issue next-tile loads early (write after barrier)
            const float4* src = (const float4*)(wf + (size_t)(d + 1) * 4096);
            wfr0 = src[tid]; wfr1 = src[tid + 256]; wfr2 = src[tid + 512]; wfr3 = src[tid + 768];
            gfr = feat[(size_t)(b * 64 + d + 1) * NPTS + idxs[tid >> 5][tid & 31]];
        }
        // nf for 2 centroids
        float nfA = 0.f, nfB = 0.f;
        {
            const float4* gA = (const float4*)&gfd[p][eA][0];
            const float4* gB = (const float4*)&gfd[p][eB][0];
            #pragma unroll
            for (int k8 = 0; k8 < 8; ++k8) {
                const float4 fa = gA[k8], fb = gB[k8];
                const unsigned uA0 = wtp[eA][k8*2][c],   uA1 = wtp[eA][k8*2+1][c];
                const unsigned uB0 = wtp[eB][k8*2][c],   uB1 = wtp[eB][k8*2+1][c];
                nfA += fa.x*bfp_lo(uA0) + fa.y*bfp_hi(uA0) + fa.z*bfp_lo(uA1) + fa.w*bfp_hi(uA1);
                nfB += fb.x*bfp_lo(uB0) + fb.y*bfp_hi(uB0) + fb.z*bfp_lo(uB1) + fb.w*bfp_hi(uB1);
            }
        }
        nfs[eA][c] = nfA; nfs[eB][c] = nfB;
        __syncthreads();
        if (d < 63) {   // write-late staging into q buffers
            float4* dst = (float4*)&uni[q][0];
            dst[tid] = wfr0; dst[tid + 256] = wfr1; dst[tid + 512] = wfr2; dst[tid + 768] = wfr3;
            gfd[q][tid >> 5][tid & 31] = gfr;
        }
        // yacc: shared wfs reads for both centroids
        {
            const float4* nA = (const float4*)&nfs[eA][0];
            const float4* nB = (const float4*)&nfs[eB][0];
            #pragma unroll
            for (int w4 = 0; w4 < 16; ++w4) {
                const float4 a4 = nA[w4], b4 = nB[w4];
                const float* wr = &uni[p][w4*256 + c];
                const float wv0 = wr[0], wv1 = wr[64], wv2 = wr[128], wv3 = wr[192];
                yA += a4.x*wv0 + a4.y*wv1 + a4.z*wv2 + a4.w*wv3;
                yB += b4.x*wv0 + b4.y*wv1 + b4.z*wv2 + b4.w*wv3;
            }
        }
        __syncthreads();
    }
    y[(size_t)(bs0 + eA) * 64 + c] = yA;
    y[(size_t)(bs0 + eB) * 64 + c] = yB;
}

__global__ __launch_bounds__(256) void ystats_kernel(const float* __restrict__ y,
                                                     double* __restrict__ st)
{
    const int tid = threadIdx.x;
    const int c = tid & 63;
    double s = 0.0, s2 = 0.0;
    for (int i = blockIdx.x * 256 + tid; i < NBATCH*NSAMP*64; i += gridDim.x * 256) {
        const float v = y[i];
        s += v; s2 += (double)v * (double)v;
    }
    __shared__ double rs[256], rs2[256];
    rs[tid] = s; rs2[tid] = s2;
    __syncthreads();
    if (tid < 64) {
        const double a  = rs[c]  + rs[64+c]  + rs[128+c]  + rs[192+c];
        const double a2 = rs2[c] + rs2[64+c] + rs2[128+c] + rs2[192+c];
        atomicAdd(&st[c], a);
        atomicAdd(&st[64 + c], a2);
    }
}

__global__ void writeout_kernel(const float* __restrict__ y,
                                const float* __restrict__ bnp3,
                                float* __restrict__ outp)
{
    const int i = blockIdx.x * 256 + threadIdx.x;
    if (i >= NBATCH * 64 * NSAMP) return;
    const int s = i & 1023;
    const int o = (i >> 10) & 63;
    const int bb = i >> 16;
    const float v = y[((size_t)(bb << 10) + s) * 64 + o];
    outp[i] = fmaxf(bnp3[o] * v + bnp3[64 + o], 0.f);
}

// ============================ launch ============================
extern "C" void kernel_launch(void* const* d_in, const int* in_sizes, int n_in,
                              void* d_out, int out_size, void* d_ws, size_t ws_size,
                              hipStream_t stream)
{
    (void)in_sizes; (void)n_in; (void)out_size; (void)ws_size;
    const float* xyz  = (const float*)d_in[0];
    const float* feat = (const float*)d_in[1];
    const float* w0   = (const float*)d_in[2];
    const float* b0   = (const float*)d_in[3];
    const float* g0   = (const float*)d_in[4];
    const float* be0  = (const float*)d_in[5];
    const float* w1   = (const float*)d_in[6];
    const float* b1   = (const float*)d_in[7];
    const float* g1   = (const float*)d_in[8];
    const float* be1  = (const float*)d_in[9];
    const float* w2   = (const float*)d_in[10];
    const float* b2   = (const float*)d_in[11];
    const float* g2   = (const float*)d_in[12];
    const float* be2  = (const float*)d_in[13];
    const float* wf   = (const float*)d_in[14];
    const float* bf   = (const float*)d_in[15];
    const float* gf   = (const float*)d_in[16];
    const float* bef  = (const float*)d_in[17];

    float* out = (float*)d_out;
    float* newxyz = out;                       // (B, S, 3)
    float* outmain = out + NBATCH * NSAMP * 3; // (B, 64, S)

    char* ws = (char*)d_ws;
    int*    idxws = (int*)ws;                                   // 2 MB
    float*  ybuf  = (float*)(ws + 2097152);                     // 4 MB
    double* stats = (double*)(ws + 2097152 + 4194304);          // 4 KB
    float*  bnp   = (float*)(ws + 2097152 + 4194304 + 4096);    // 2 KB

    zero_stats_kernel<<<2, 256, 0, stream>>>(stats);
    fps_kernel<<<NBATCH, 256, 0, stream>>>(xyz, newxyz);
    knn_kernel<<<NBATCH * NSAMP, 256, 0, stream>>>(xyz, newxyz, idxws);

    gxmoments_kernel<<<512, 256, 0, stream>>>(xyz, newxyz, idxws, stats);
    bn0_moments_finalize_kernel<<<1, 64, 0, stream>>>(stats, w0, b0, g0, be0, bnp);
    lstats_kernel<1><<<1024, 256, 0, stream>>>(xyz, newxyz, idxws, w0, b0, w1, b1, w2, b2, bnp, stats + 128);
    bn_finalize_kernel<<<1, 64, 0, stream>>>(stats + 128, g1, be1, bnp + 128, (float)NROWS);
    lstats_kernel<2><<<1024, 256, 0, stream>>>(xyz, newxyz, idxws, w0, b0, w1, b1, w2, b2, bnp, stats + 256);
    bn_finalize_kernel<<<1, 64, 0, stream>>>(stats + 256, g2, be2, bnp + 256, (float)NROWS);

    final_conv_kernel<<<NBATCH * NSAMP / 8, 256, 0, stream>>>(
        xyz, newxyz, idxws, feat, w0, b0, w1, b1, w2, b2, bnp, wf, bf, ybuf);

    ystats_kernel<<<256, 256, 0, stream>>>(ybuf, stats + 384);
    bn_finalize_kernel<<<1, 64, 0, stream>>>(stats + 384, gf, bef, bnp + 384, (float)(NBATCH * NSAMP));
    writeout_kernel<<<4096, 256, 0, stream>>>(ybuf, bnp + 384, outmain);
}

// Round 5
// 2639.714 us; speedup vs baseline: 1.8353x; 1.3628x over previous
//
#include <hip/hip_runtime.h>

#define NBATCH 16
#define NPTS   4096
#define NSAMP  1024
#define NKNN   32
#define NROWS  (NBATCH*NSAMP*NKNN)   // 524288
#define BN_EPS 1e-5f

__device__ __forceinline__ unsigned pack_bf16pair(float a, float b) {
    unsigned ua = __float_as_uint(a); ua += 0x7FFFu + ((ua >> 16) & 1u);
    unsigned ub = __float_as_uint(b); ub += 0x7FFFu + ((ub >> 16) & 1u);
    return (ua >> 16) | (ub & 0xFFFF0000u);
}
__device__ __forceinline__ float bfp_lo(unsigned u) { return __uint_as_float(u << 16); }
__device__ __forceinline__ float bfp_hi(unsigned u) { return __uint_as_float(u & 0xFFFF0000u); }

// ============================ FPS v3 ============================
// 256 thr/block, 1 block/batch. Contiguous layout: thread t owns points
// [16t, 16t+16). Value-only shfl_xor max reduce; index recovered via
// ballot+ffs+readlane (tie -> lowest lane = lowest index under contiguous
// layout; per-lane descending scan -> lowest j; cross-wave ascending strict
// '>' -> lowest wave). Distance arithmetic bit-identical to rounds 1-4.
__global__ __launch_bounds__(256) void fps_kernel(const float* __restrict__ xyz,
                                                  float* __restrict__ newxyz)
{
    const int b = blockIdx.x;
    const int tid = threadIdx.x;
    const int wv = tid >> 6;
    const float* xb = xyz + (size_t)b * NPTS * 3;
    __shared__ float xs[NPTS];
    __shared__ float ys[NPTS];
    __shared__ float zs[NPTS];
    __shared__ __align__(16) float red_v[2][4];
    __shared__ __align__(16) int   red_i[2][4];
    float px[16], py[16], pz[16], dmin[16];
    {
        float arr[48];
        const float4* s4 = (const float4*)(xb + (size_t)tid * 48);
        #pragma unroll
        for (int i = 0; i < 12; ++i) *(float4*)&arr[i*4] = s4[i];
        #pragma unroll
        for (int j = 0; j < 16; ++j) {
            px[j] = arr[3*j]; py[j] = arr[3*j+1]; pz[j] = arr[3*j+2];
            const int p = tid * 16 + j;
            xs[p] = px[j]; ys[p] = py[j]; zs[p] = pz[j];
            dmin[j] = 1e10f;
        }
    }
    if (tid == 0) {
        float* o = newxyz + (size_t)b * NSAMP * 3;
        o[0] = xb[0]; o[1] = xb[1]; o[2] = xb[2];
    }
    __syncthreads();
    float lx = xs[0], ly = ys[0], lz = zs[0];
    for (int t = 1; t < NSAMP; ++t) {
        // ---- update dmin, track lane max (value only) ----
        float bv = -1.0f;
        #pragma unroll
        for (int j = 0; j < 16; ++j) {
            const float dx = __fsub_rn(px[j], lx);
            const float dy = __fsub_rn(py[j], ly);
            const float dz = __fsub_rn(pz[j], lz);
            const float d = __fadd_rn(__fadd_rn(__fmul_rn(dx,dx), __fmul_rn(dy,dy)), __fmul_rn(dz,dz));
            const float nd = fminf(dmin[j], d);
            dmin[j] = nd;
            bv = fmaxf(bv, nd);
        }
        // lowest j achieving bv (independent of shuffle chain -> overlaps it)
        int lj = 0;
        #pragma unroll
        for (int j = 15; j >= 0; --j) if (dmin[j] == bv) lj = j;
        const int bi_lane = tid * 16 + lj;
        // ---- value-only wave max ----
        float mv = bv;
        #pragma unroll
        for (int m = 1; m < 64; m <<= 1) mv = fmaxf(mv, __shfl_xor(mv, m));
        // winner lane = lowest lane with bv == mv
        const unsigned long long mask = __ballot(bv == mv);
        const int winner = __ffsll(mask) - 1;
        const int bi_w = __builtin_amdgcn_readlane(bi_lane, winner);
        const int par = t & 1;
        if ((tid & 63) == 0) { red_v[par][wv] = mv; red_i[par][wv] = bi_w; }
        __syncthreads();
        // ---- cross-wave (4 slots, vector reads, ascending strict '>') ----
        const float4 rv = *(const float4*)&red_v[par][0];
        const int4   ri = *(const int4*)&red_i[par][0];
        float fv = rv.x; int bi = ri.x;
        if (rv.y > fv) { fv = rv.y; bi = ri.y; }
        if (rv.z > fv) { fv = rv.z; bi = ri.z; }
        if (rv.w > fv) { fv = rv.w; bi = ri.w; }
        lx = xs[bi]; ly = ys[bi]; lz = zs[bi];
        if (tid == 0) {
            float* o = newxyz + ((size_t)b * NSAMP + t) * 3;
            o[0] = lx; o[1] = ly; o[2] = lz;
        }
    }
}

// ============================ kNN ============================
// (validated rounds 2-4 — FMA-chain dot, radix select, tie->lowest index)
__global__ __launch_bounds__(256) void knn_kernel(const float* __restrict__ xyz,
                                                  const float* __restrict__ newxyz,
                                                  int* __restrict__ idx_out)
{
    const int bs = blockIdx.x;
    const int b = bs >> 10;
    const int tid = threadIdx.x;
    __shared__ unsigned keys[NPTS];
    __shared__ int hist[256];
    __shared__ float qsh[3];
    __shared__ int ctrl[4];
    __shared__ int ties[128];
    if (tid < 3) qsh[tid] = newxyz[bs*3 + tid];
    if (tid == 0) { ctrl[0] = 0; ctrl[1] = NKNN; }
    __syncthreads();
    const float q0 = qsh[0], q1 = qsh[1], q2 = qsh[2];
    const float qq = __fadd_rn(__fadd_rn(__fmul_rn(q0,q0), __fmul_rn(q1,q1)), __fmul_rn(q2,q2));
    const float* xb = xyz + (size_t)b * NPTS * 3;
    for (int n = tid; n < NPTS; n += 256) {
        const float x0 = xb[n*3+0], x1 = xb[n*3+1], x2 = xb[n*3+2];
        const float xx = __fadd_rn(__fadd_rn(__fmul_rn(x0,x0), __fmul_rn(x1,x1)), __fmul_rn(x2,x2));
        float dt = __fmul_rn(q0, x0);
        dt = __fmaf_rn(q1, x1, dt);
        dt = __fmaf_rn(q2, x2, dt);
        const float dd = __fadd_rn(__fsub_rn(qq, __fmul_rn(2.0f, dt)), xx);
        unsigned ub = __float_as_uint(dd);
        ub = (ub & 0x80000000u) ? ~ub : (ub | 0x80000000u);
        keys[n] = ub;
    }
    for (int p = 3; p >= 0; --p) {
        __syncthreads();
        hist[tid] = 0;
        __syncthreads();
        const unsigned pre = (unsigned)ctrl[0];
        const int shift = p * 8;
        const unsigned himask = (p == 3) ? 0u : (0xFFFFFFFFu << ((p + 1) * 8));
        for (int n = tid; n < NPTS; n += 256) {
            const unsigned k = keys[n];
            if ((k & himask) == pre) atomicAdd(&hist[(k >> shift) & 255], 1);
        }
        __syncthreads();
        if (tid == 0) {
            int r = ctrl[1]; unsigned pf = (unsigned)ctrl[0];
            for (int bin = 0; bin < 256; ++bin) {
                const int cnt = hist[bin];
                if (r > cnt) r -= cnt;
                else { pf |= ((unsigned)bin) << shift; break; }
            }
            ctrl[0] = (int)pf; ctrl[1] = r;
        }
    }
    __syncthreads();
    const unsigned T = (unsigned)ctrl[0];
    if (tid == 0) { ctrl[2] = 0; ctrl[3] = 0; }
    __syncthreads();
    int* out = idx_out + (size_t)bs * NKNN;
    for (int n = tid; n < NPTS; n += 256) {
        const unsigned k = keys[n];
        if (k < T) {
            const int pos = atomicAdd(&ctrl[2], 1);
            if (pos < NKNN) out[pos] = n;
        } else if (k == T) {
            const int pos = atomicAdd(&ctrl[3], 1);
            if (pos < 128) ties[pos] = n;
        }
    }
    __syncthreads();
    if (tid == 0) {
        const int nless = ctrl[2] < NKNN ? ctrl[2] : NKNN;
        const int need = NKNN - nless;
        const int ntie = ctrl[3] < 128 ? ctrl[3] : 128;
        int last = -1;
        for (int j = 0; j < need; ++j) {
            int best = 0x7fffffff;
            for (int i = 0; i < ntie; ++i) {
                const int v = ties[i];
                if (v > last && v < best) best = v;
            }
            out[nless + j] = (best == 0x7fffffff) ? 0 : best;
            last = best;
        }
    }
}

// ============================ stats helpers ============================
__global__ void zero_stats_kernel(double* st)
{
    const int i = blockIdx.x * 256 + threadIdx.x;
    if (i < 512) st[i] = 0.0;
}

// BN0 stats via moments: t0 is affine in gx, so only Sgx (3) + S gx gx^T (6).
__global__ __launch_bounds__(256) void gxmoments_kernel(
    const float* __restrict__ xyz, const float* __restrict__ newxyz,
    const int* __restrict__ idxws, double* __restrict__ stats)
{
    const int tid = threadIdx.x;
    double m[9];
    #pragma unroll
    for (int i = 0; i < 9; ++i) m[i] = 0.0;
    for (int row = blockIdx.x * 256 + tid; row < NROWS; row += gridDim.x * 256) {
        const int bs = row >> 5;
        const int bb = row >> 15;
        const int id = idxws[row];
        const float* xp = xyz + ((size_t)bb * NPTS + id) * 3;
        const float* qp = newxyz + bs * 3;
        const float gx = xp[0] - qp[0];
        const float gy = xp[1] - qp[1];
        const float gz = xp[2] - qp[2];
        const double dx = gx, dy = gy, dz = gz;
        m[0] += dx; m[1] += dy; m[2] += dz;
        m[3] += dx*dx; m[4] += dx*dy; m[5] += dx*dz;
        m[6] += dy*dy; m[7] += dy*dz; m[8] += dz*dz;
    }
    #pragma unroll
    for (int i = 0; i < 9; ++i) {
        #pragma unroll
        for (int s = 1; s < 64; s <<= 1) m[i] += __shfl_xor(m[i], s);
    }
    __shared__ double part[4][9];
    if ((tid & 63) == 0) {
        #pragma unroll
        for (int i = 0; i < 9; ++i) part[tid >> 6][i] = m[i];
    }
    __syncthreads();
    if (tid < 9) atomicAdd(&stats[tid], part[0][tid] + part[1][tid] + part[2][tid] + part[3][tid]);
}

__global__ void bn0_moments_finalize_kernel(const double* __restrict__ st,
    const float* __restrict__ w0, const float* __restrict__ b0,
    const float* __restrict__ g0, const float* __restrict__ be0,
    float* __restrict__ outp)
{
    const int c = threadIdx.x;  // 64
    const double N = (double)NROWS;
    const double w0c = w0[c], w1c = w0[64 + c], w2c = w0[128 + c];
    const double b = b0[c];
    const double dotS = st[0]*w0c + st[1]*w1c + st[2]*w2c;
    const double qf = w0c*w0c*st[3] + w1c*w1c*st[6] + w2c*w2c*st[8]
                    + 2.0*(w0c*w1c*st[4] + w0c*w2c*st[5] + w1c*w2c*st[7]);
    const double mean = dotS / N + b;
    const double ex2 = (qf + 2.0*b*dotS) / N + b*b;
    const double var = ex2 - mean*mean;
    const float scale = g0[c] * rsqrtf((float)var + BN_EPS);
    outp[c] = scale;
    outp[64 + c] = be0[c] - (float)mean * scale;
}

// Recompute MLP chain to layer L (1 or 2); per-channel sum/sumsq of pre-BN act.
template<int L>
__global__ __launch_bounds__(256) void lstats_kernel(
    const float* __restrict__ xyz, const float* __restrict__ newxyz,
    const int* __restrict__ idxws,
    const float* __restrict__ w0, const float* __restrict__ b0,
    const float* __restrict__ w1, const float* __restrict__ b1,
    const float* __restrict__ w2, const float* __restrict__ b2,
    const float* __restrict__ bnp, double* __restrict__ stats)
{
    __shared__ __align__(16) float w1s[4096];
    __shared__ __align__(16) float w2s[4096];
    __shared__ float w0s[192];
    __shared__ float gxs[8][3];
    __shared__ __align__(16) float hb1[8][64];
    __shared__ __align__(16) float hb2[8][64];
    __shared__ double rs[256], rs2[256];
    const int tid = threadIdx.x;
    const int c = tid & 63;
    const int rq = tid >> 6;
    const int s0v = rq * 2, s1v = rq * 2 + 1;
    if (tid < 192) w0s[tid] = w0[tid];
    for (int i = tid; i < 4096; i += 256) w1s[i] = w1[i];
    if (L >= 2) for (int i = tid; i < 4096; i += 256) w2s[i] = w2[i];
    const float b0c = b0[c];
    const float b1c = b1[c], sc0 = bnp[c], sh0 = bnp[64+c];
    float b2c = 0.f, sc1 = 0.f, sh1 = 0.f;
    if (L >= 2) { b2c = b2[c]; sc1 = bnp[128+c]; sh1 = bnp[192+c]; }
    __syncthreads();
    double s = 0.0, s2 = 0.0;
    const int ntiles = NROWS / 8;
    for (int tile = blockIdx.x; tile < ntiles; tile += gridDim.x) {
        if (tid < 24) {
            const int slot = tid / 3, cc = tid % 3;
            const int row = tile * 8 + slot;
            const int bs = row >> 5;
            const int bb = row >> 15;
            const int id = idxws[row];
            gxs[slot][cc] = xyz[((size_t)bb * NPTS + id) * 3 + cc] - newxyz[bs*3 + cc];
        }
        __syncthreads();
        {
            const float t00 = gxs[s0v][0]*w0s[c] + gxs[s0v][1]*w0s[64+c] + gxs[s0v][2]*w0s[128+c] + b0c;
            const float t01 = gxs[s1v][0]*w0s[c] + gxs[s1v][1]*w0s[64+c] + gxs[s1v][2]*w0s[128+c] + b0c;
            hb1[s0v][c] = fmaxf(sc0*t00 + sh0, 0.f);
            hb1[s1v][c] = fmaxf(sc0*t01 + sh0, 0.f);
        }
        __syncthreads();
        float t10 = b1c, t11 = b1c;
        {
            const float4* h0p = (const float4*)&hb1[s0v][0];
            const float4* h1p = (const float4*)&hb1[s1v][0];
            #pragma unroll
            for (int j4 = 0; j4 < 16; ++j4) {
                const float4 h0 = h0p[j4], h1 = h1p[j4];
                const float* wr = &w1s[j4*256 + c];
                const float wv0 = wr[0], wv1 = wr[64], wv2 = wr[128], wv3 = wr[192];
                t10 += h0.x*wv0 + h0.y*wv1 + h0.z*wv2 + h0.w*wv3;
                t11 += h1.x*wv0 + h1.y*wv1 + h1.z*wv2 + h1.w*wv3;
            }
        }
        if (L == 1) {
            s  += (double)t10 + (double)t11;
            s2 += (double)t10*(double)t10 + (double)t11*(double)t11;
            __syncthreads();
        } else {
            hb2[s0v][c] = fmaxf(sc1*t10 + sh1, 0.f);
            hb2[s1v][c] = fmaxf(sc1*t11 + sh1, 0.f);
            __syncthreads();
            float t20 = b2c, t21 = b2c;
            const float4* h0p = (const float4*)&hb2[s0v][0];
            const float4* h1p = (const float4*)&hb2[s1v][0];
            #pragma unroll
            for (int j4 = 0; j4 < 16; ++j4) {
                const float4 h0 = h0p[j4], h1 = h1p[j4];
                const float* wr = &w2s[j4*256 + c];
                const float wv0 = wr[0], wv1 = wr[64], wv2 = wr[128], wv3 = wr[192];
                t20 += h0.x*wv0 + h0.y*wv1 + h0.z*wv2 + h0.w*wv3;
                t21 += h1.x*wv0 + h1.y*wv1 + h1.z*wv2 + h1.w*wv3;
            }
            s  += (double)t20 + (double)t21;
            s2 += (double)t20*(double)t20 + (double)t21*(double)t21;
            __syncthreads();
        }
    }
    rs[tid] = s; rs2[tid] = s2;
    __syncthreads();
    if (tid < 64) {
        const double a  = rs[c]  + rs[64+c]  + rs[128+c]  + rs[192+c];
        const double a2 = rs2[c] + rs2[64+c] + rs2[128+c] + rs2[192+c];
        atomicAdd(&stats[c], a);
        atomicAdd(&stats[64 + c], a2);
    }
}

__global__ void bn_finalize_kernel(const double* __restrict__ st,
                                   const float* __restrict__ g,
                                   const float* __restrict__ be,
                                   float* __restrict__ outp, float n)
{
    const int c = threadIdx.x;  // 64
    const double m = st[c] / (double)n;
    const double var = st[64 + c] / (double)n - m * m;
    const float scale = g[c] * rsqrtf((float)var + BN_EPS);
    outp[c] = scale;
    outp[64 + c] = be[c] - (float)m * scale;
}

// ============================ final fused conv ============================
__global__ __launch_bounds__(256) void final_conv_kernel(
    const float* __restrict__ xyz, const float* __restrict__ newxyz,
    const int* __restrict__ idxws, const float* __restrict__ feat,
    const float* __restrict__ w0, const float* __restrict__ b0,
    const float* __restrict__ w1, const float* __restrict__ b1,
    const float* __restrict__ w2, const float* __restrict__ b2,
    const float* __restrict__ bnp, const float* __restrict__ wf,
    const float* __restrict__ bf, float* __restrict__ y)
{
    __shared__ unsigned wtp[8][16][64];            // 32 KB packed bf16 pairs (k, k+1)
    __shared__ __align__(16) float uni[2][4096];   // 32 KB: A: w1s/w2s; B: wfs dbuf
    __shared__ __align__(16) float gfd[2][8][32];  // 2 KB dbuf
    __shared__ __align__(16) float nfs[8][64];     // 2 KB
    __shared__ __align__(16) float hb1[8][64];
    __shared__ __align__(16) float hb2[8][64];
    __shared__ int   idxs[8][32];
    __shared__ float qs[8][3];
    __shared__ float gxs[8][3];
    __shared__ float w0s[192];
    const int tid = threadIdx.x;
    const int c = tid & 63;
    const int rq = tid >> 6;          // 0..3
    const int eA = rq, eB = rq + 4;
    const int bs0 = blockIdx.x * 8;
    const int b = bs0 >> 10;
    idxs[tid >> 5][tid & 31] = idxws[(size_t)bs0 * NKNN + tid];
    if (tid < 24)  qs[tid / 3][tid % 3] = newxyz[(bs0 + tid/3)*3 + (tid % 3)];
    if (tid < 192) w0s[tid] = w0[tid];
    for (int i = tid; i < 4096; i += 256) { uni[0][i] = w1[i]; uni[1][i] = w2[i]; }
    const float b0c = b0[c], b1c = b1[c], b2c = b2[c];
    const float sc0 = bnp[c],     sh0 = bnp[64+c];
    const float sc1 = bnp[128+c], sh1 = bnp[192+c];
    const float sc2 = bnp[256+c], sh2 = bnp[320+c];
    __syncthreads();
    // -------- Phase A: weightnet (2 rows/thread) --------
    const int s0v = rq * 2, s1v = s0v + 1;
    for (int it = 0; it < 32; ++it) {
        if (tid < 24) {
            const int slot = tid / 3, cc = tid % 3;
            const int row = it * 8 + slot;
            const int e = row >> 5, k = row & 31;
            gxs[slot][cc] = xyz[((size_t)b * NPTS + idxs[e][k]) * 3 + cc] - qs[e][cc];
        }
        __syncthreads();
        {
            const float t00 = gxs[s0v][0]*w0s[c] + gxs[s0v][1]*w0s[64+c] + gxs[s0v][2]*w0s[128+c] + b0c;
            const float t01 = gxs[s1v][0]*w0s[c] + gxs[s1v][1]*w0s[64+c] + gxs[s1v][2]*w0s[128+c] + b0c;
            hb1[s0v][c] = fmaxf(sc0*t00 + sh0, 0.f);
            hb1[s1v][c] = fmaxf(sc0*t01 + sh0, 0.f);
        }
        __syncthreads();
        float t10 = b1c, t11 = b1c;
        {
            const float4* h0p = (const float4*)&hb1[s0v][0];
            const float4* h1p = (const float4*)&hb1[s1v][0];
            #pragma unroll
            for (int j4 = 0; j4 < 16; ++j4) {
                const float4 h0 = h0p[j4], h1 = h1p[j4];
                const float* wr = &uni[0][j4*256 + c];
                const float wv0 = wr[0], wv1 = wr[64], wv2 = wr[128], wv3 = wr[192];
                t10 += h0.x*wv0 + h0.y*wv1 + h0.z*wv2 + h0.w*wv3;
                t11 += h1.x*wv0 + h1.y*wv1 + h1.z*wv2 + h1.w*wv3;
            }
        }
        hb2[s0v][c] = fmaxf(sc1*t10 + sh1, 0.f);
        hb2[s1v][c] = fmaxf(sc1*t11 + sh1, 0.f);
        __syncthreads();
        float t20 = b2c, t21 = b2c;
        {
            const float4* h0p = (const float4*)&hb2[s0v][0];
            const float4* h1p = (const float4*)&hb2[s1v][0];
            #pragma unroll
            for (int j4 = 0; j4 < 16; ++j4) {
                const float4 h0 = h0p[j4], h1 = h1p[j4];
                const float* wr = &uni[1][j4*256 + c];
                const float wv0 = wr[0], wv1 = wr[64], wv2 = wr[128], wv3 = wr[192];
                t20 += h0.x*wv0 + h0.y*wv1 + h0.z*wv2 + h0.w*wv3;
                t21 += h1.x*wv0 + h1.y*wv1 + h1.z*wv2 + h1.w*wv3;
            }
        }
        {
            const int r0 = it * 8 + s0v;
            const int e0 = r0 >> 5, k0 = r0 & 31;
            wtp[e0][k0 >> 1][c] = pack_bf16pair(fmaxf(sc2*t20 + sh2, 0.f),
                                                fmaxf(sc2*t21 + sh2, 0.f));
        }
        __syncthreads();
    }
    // -------- Phase B: nf + final gemm --------
    {
        const float4* src = (const float4*)wf;
        #pragma unroll
        for (int i = 0; i < 4; ++i) ((float4*)&uni[0][0])[tid + i*256] = src[tid + i*256];
        gfd[0][tid >> 5][tid & 31] = feat[(size_t)(b * 64 + 0) * NPTS + idxs[tid >> 5][tid & 31]];
    }
    __syncthreads();
    float yA = bf[c], yB = bf[c];
    for (int d = 0; d < 64; ++d) {
        const int p = d & 1, q = p ^ 1;
        float4 wfr0, wfr1, wfr2, wfr3; float gfr;
        if (d < 63) {
            const float4* src = (const float4*)(wf + (size_t)(d + 1) * 4096);
            wfr0 = src[tid]; wfr1 = src[tid + 256]; wfr2 = src[tid + 512]; wfr3 = src[tid + 768];
            gfr = feat[(size_t)(b * 64 + d + 1) * NPTS + idxs[tid >> 5][tid & 31]];
        }
        float nfA = 0.f, nfB = 0.f;
        {
            const float4* gA = (const float4*)&gfd[p][eA][0];
            const float4* gB = (const float4*)&gfd[p][eB][0];
            #pragma unroll
            for (int k8 = 0; k8 < 8; ++k8) {
                const float4 fa = gA[k8], fb = gB[k8];
                const unsigned uA0 = wtp[eA][k8*2][c],   uA1 = wtp[eA][k8*2+1][c];
                const unsigned uB0 = wtp[eB][k8*2][c],   uB1 = wtp[eB][k8*2+1][c];
                nfA += fa.x*bfp_lo(uA0) + fa.y*bfp_hi(uA0) + fa.z*bfp_lo(uA1) + fa.w*bfp_hi(uA1);
                nfB += fb.x*bfp_lo(uB0) + fb.y*bfp_hi(uB0) + fb.z*bfp_lo(uB1) + fb.w*bfp_hi(uB1);
            }
        }
        nfs[eA][c] = nfA; nfs[eB][c] = nfB;
        __syncthreads();
        if (d < 63) {
            float4* dst = (float4*)&uni[q][0];
            dst[tid] = wfr0; dst[tid + 256] = wfr1; dst[tid + 512] = wfr2; dst[tid + 768] = wfr3;
            gfd[q][tid >> 5][tid & 31] = gfr;
        }
        {
            const float4* nA = (const float4*)&nfs[eA][0];
            const float4* nB = (const float4*)&nfs[eB][0];
            #pragma unroll
            for (int w4 = 0; w4 < 16; ++w4) {
                const float4 a4 = nA[w4], b4 = nB[w4];
                const float* wr = &uni[p][w4*256 + c];
                const float wv0 = wr[0], wv1 = wr[64], wv2 = wr[128], wv3 = wr[192];
                yA += a4.x*wv0 + a4.y*wv1 + a4.z*wv2 + a4.w*wv3;
                yB += b4.x*wv0 + b4.y*wv1 + b4.z*wv2 + b4.w*wv3;
            }
        }
        __syncthreads();
    }
    y[(size_t)(bs0 + eA) * 64 + c] = yA;
    y[(size_t)(bs0 + eB) * 64 + c] = yB;
}

__global__ __launch_bounds__(256) void ystats_kernel(const float* __restrict__ y,
                                                     double* __restrict__ st)
{
    const int tid = threadIdx.x;
    const int c = tid & 63;
    double s = 0.0, s2 = 0.0;
    for (int i = blockIdx.x * 256 + tid; i < NBATCH*NSAMP*64; i += gridDim.x * 256) {
        const float v = y[i];
        s += v; s2 += (double)v * (double)v;
    }
    __shared__ double rs[256], rs2[256];
    rs[tid] = s; rs2[tid] = s2;
    __syncthreads();
    if (tid < 64) {
        const double a  = rs[c]  + rs[64+c]  + rs[128+c]  + rs[192+c];
        const double a2 = rs2[c] + rs2[64+c] + rs2[128+c] + rs2[192+c];
        atomicAdd(&st[c], a);
        atomicAdd(&st[64 + c], a2);
    }
}

__global__ void writeout_kernel(const float* __restrict__ y,
                                const float* __restrict__ bnp3,
                                float* __restrict__ outp)
{
    const int i = blockIdx.x * 256 + threadIdx.x;
    if (i >= NBATCH * 64 * NSAMP) return;
    const int s = i & 1023;
    const int o = (i >> 10) & 63;
    const int bb = i >> 16;
    const float v = y[((size_t)(bb << 10) + s) * 64 + o];
    outp[i] = fmaxf(bnp3[o] * v + bnp3[64 + o], 0.f);
}

// ============================ launch ============================
extern "C" void kernel_launch(void* const* d_in, const int* in_sizes, int n_in,
                              void* d_out, int out_size, void* d_ws, size_t ws_size,
                              hipStream_t stream)
{
    (void)in_sizes; (void)n_in; (void)out_size; (void)ws_size;
    const float* xyz  = (const float*)d_in[0];
    const float* feat = (const float*)d_in[1];
    const float* w0   = (const float*)d_in[2];
    const float* b0   = (const float*)d_in[3];
    const float* g0   = (const float*)d_in[4];
    const float* be0  = (const float*)d_in[5];
    const float* w1   = (const float*)d_in[6];
    const float* b1   = (const float*)d_in[7];
    const float* g1   = (const float*)d_in[8];
    const float* be1  = (const float*)d_in[9];
    const float* w2   = (const float*)d_in[10];
    const float* b2   = (const float*)d_in[11];
    const float* g2   = (const float*)d_in[12];
    const float* be2  = (const float*)d_in[13];
    const float* wf   = (const float*)d_in[14];
    const float* bf   = (const float*)d_in[15];
    const float* gf   = (const float*)d_in[16];
    const float* bef  = (const float*)d_in[17];

    float* out = (float*)d_out;
    float* newxyz = out;                       // (B, S, 3)
    float* outmain = out + NBATCH * NSAMP * 3; // (B, 64, S)

    char* ws = (char*)d_ws;
    int*    idxws = (int*)ws;                                   // 2 MB
    float*  ybuf  = (float*)(ws + 2097152);                     // 4 MB
    double* stats = (double*)(ws + 2097152 + 4194304);          // 4 KB
    float*  bnp   = (float*)(ws + 2097152 + 4194304 + 4096);    // 2 KB

    zero_stats_kernel<<<2, 256, 0, stream>>>(stats);
    fps_kernel<<<NBATCH, 256, 0, stream>>>(xyz, newxyz);
    knn_kernel<<<NBATCH * NSAMP, 256, 0, stream>>>(xyz, newxyz, idxws);

    gxmoments_kernel<<<512, 256, 0, stream>>>(xyz, newxyz, idxws, stats);
    bn0_moments_finalize_kernel<<<1, 64, 0, stream>>>(stats, w0, b0, g0, be0, bnp);
    lstats_kernel<1><<<1024, 256, 0, stream>>>(xyz, newxyz, idxws, w0, b0, w1, b1, w2, b2, bnp, stats + 128);
    bn_finalize_kernel<<<1, 64, 0, stream>>>(stats + 128, g1, be1, bnp + 128, (float)NROWS);
    lstats_kernel<2><<<1024, 256, 0, stream>>>(xyz, newxyz, idxws, w0, b0, w1, b1, w2, b2, bnp, stats + 256);
    bn_finalize_kernel<<<1, 64, 0, stream>>>(stats + 256, g2, be2, bnp + 256, (float)NROWS);

    final_conv_kernel<<<NBATCH * NSAMP / 8, 256, 0, stream>>>(
        xyz, newxyz, idxws, feat, w0, b0, w1, b1, w2, b2, bnp, wf, bf, ybuf);

    ystats_kernel<<<256, 256, 0, stream>>>(ybuf, stats + 384);
    bn_finalize_kernel<<<1, 64, 0, stream>>>(stats + 384, gf, bef, bnp + 384, (float)(NBATCH * NSAMP));
    writeout_kernel<<<4096, 256, 0, stream>>>(ybuf, bnp + 384, outmain);
}

// Round 6
// 2136.998 us; speedup vs baseline: 2.2670x; 1.2352x over previous
//
#include <hip/hip_runtime.h>

#define NBATCH 16
#define NPTS   4096
#define NSAMP  1024
#define NKNN   32
#define NROWS  (NBATCH*NSAMP*NKNN)   // 524288
#define BN_EPS 1e-5f

typedef __attribute__((ext_vector_type(4))) float f32x4;
typedef __attribute__((ext_vector_type(8))) short bf16x8;
union frag_u { unsigned u[4]; bf16x8 h; uint4 u4; };

__device__ __forceinline__ unsigned pack_bf16pair(float a, float b) {
    unsigned ua = __float_as_uint(a); ua += 0x7FFFu + ((ua >> 16) & 1u);
    unsigned ub = __float_as_uint(b); ub += 0x7FFFu + ((ub >> 16) & 1u);
    return (ua >> 16) | (ub & 0xFFFF0000u);
}

// ============================ FPS v3 ============================
// (validated rounds 1-5 — arithmetic untouched)
__global__ __launch_bounds__(256) void fps_kernel(const float* __restrict__ xyz,
                                                  float* __restrict__ newxyz)
{
    const int b = blockIdx.x;
    const int tid = threadIdx.x;
    const int wv = tid >> 6;
    const float* xb = xyz + (size_t)b * NPTS * 3;
    __shared__ float xs[NPTS];
    __shared__ float ys[NPTS];
    __shared__ float zs[NPTS];
    __shared__ __align__(16) float red_v[2][4];
    __shared__ __align__(16) int   red_i[2][4];
    float px[16], py[16], pz[16], dmin[16];
    {
        float arr[48];
        const float4* s4 = (const float4*)(xb + (size_t)tid * 48);
        #pragma unroll
        for (int i = 0; i < 12; ++i) *(float4*)&arr[i*4] = s4[i];
        #pragma unroll
        for (int j = 0; j < 16; ++j) {
            px[j] = arr[3*j]; py[j] = arr[3*j+1]; pz[j] = arr[3*j+2];
            const int p = tid * 16 + j;
            xs[p] = px[j]; ys[p] = py[j]; zs[p] = pz[j];
            dmin[j] = 1e10f;
        }
    }
    if (tid == 0) {
        float* o = newxyz + (size_t)b * NSAMP * 3;
        o[0] = xb[0]; o[1] = xb[1]; o[2] = xb[2];
    }
    __syncthreads();
    float lx = xs[0], ly = ys[0], lz = zs[0];
    for (int t = 1; t < NSAMP; ++t) {
        float bv = -1.0f;
        #pragma unroll
        for (int j = 0; j < 16; ++j) {
            const float dx = __fsub_rn(px[j], lx);
            const float dy = __fsub_rn(py[j], ly);
            const float dz = __fsub_rn(pz[j], lz);
            const float d = __fadd_rn(__fadd_rn(__fmul_rn(dx,dx), __fmul_rn(dy,dy)), __fmul_rn(dz,dz));
            const float nd = fminf(dmin[j], d);
            dmin[j] = nd;
            bv = fmaxf(bv, nd);
        }
        int lj = 0;
        #pragma unroll
        for (int j = 15; j >= 0; --j) if (dmin[j] == bv) lj = j;
        const int bi_lane = tid * 16 + lj;
        float mv = bv;
        #pragma unroll
        for (int m = 1; m < 64; m <<= 1) mv = fmaxf(mv, __shfl_xor(mv, m));
        const unsigned long long mask = __ballot(bv == mv);
        const int winner = __ffsll(mask) - 1;
        const int bi_w = __builtin_amdgcn_readlane(bi_lane, winner);
        const int par = t & 1;
        if ((tid & 63) == 0) { red_v[par][wv] = mv; red_i[par][wv] = bi_w; }
        __syncthreads();
        const float4 rv = *(const float4*)&red_v[par][0];
        const int4   ri = *(const int4*)&red_i[par][0];
        float fv = rv.x; int bi = ri.x;
        if (rv.y > fv) { fv = rv.y; bi = ri.y; }
        if (rv.z > fv) { fv = rv.z; bi = ri.z; }
        if (rv.w > fv) { fv = rv.w; bi = ri.w; }
        lx = xs[bi]; ly = ys[bi]; lz = zs[bi];
        if (tid == 0) {
            float* o = newxyz + ((size_t)b * NSAMP + t) * 3;
            o[0] = lx; o[1] = ly; o[2] = lz;
        }
    }
}

// ============================ kNN ============================
// (validated rounds 2-5)
__global__ __launch_bounds__(256) void knn_kernel(const float* __restrict__ xyz,
                                                  const float* __restrict__ newxyz,
                                                  int* __restrict__ idx_out)
{
    const int bs = blockIdx.x;
    const int b = bs >> 10;
    const int tid = threadIdx.x;
    __shared__ unsigned keys[NPTS];
    __shared__ int hist[256];
    __shared__ float qsh[3];
    __shared__ int ctrl[4];
    __shared__ int ties[128];
    if (tid < 3) qsh[tid] = newxyz[bs*3 + tid];
    if (tid == 0) { ctrl[0] = 0; ctrl[1] = NKNN; }
    __syncthreads();
    const float q0 = qsh[0], q1 = qsh[1], q2 = qsh[2];
    const float qq = __fadd_rn(__fadd_rn(__fmul_rn(q0,q0), __fmul_rn(q1,q1)), __fmul_rn(q2,q2));
    const float* xb = xyz + (size_t)b * NPTS * 3;
    for (int n = tid; n < NPTS; n += 256) {
        const float x0 = xb[n*3+0], x1 = xb[n*3+1], x2 = xb[n*3+2];
        const float xx = __fadd_rn(__fadd_rn(__fmul_rn(x0,x0), __fmul_rn(x1,x1)), __fmul_rn(x2,x2));
        float dt = __fmul_rn(q0, x0);
        dt = __fmaf_rn(q1, x1, dt);
        dt = __fmaf_rn(q2, x2, dt);
        const float dd = __fadd_rn(__fsub_rn(qq, __fmul_rn(2.0f, dt)), xx);
        unsigned ub = __float_as_uint(dd);
        ub = (ub & 0x80000000u) ? ~ub : (ub | 0x80000000u);
        keys[n] = ub;
    }
    for (int p = 3; p >= 0; --p) {
        __syncthreads();
        hist[tid] = 0;
        __syncthreads();
        const unsigned pre = (unsigned)ctrl[0];
        const int shift = p * 8;
        const unsigned himask = (p == 3) ? 0u : (0xFFFFFFFFu << ((p + 1) * 8));
        for (int n = tid; n < NPTS; n += 256) {
            const unsigned k = keys[n];
            if ((k & himask) == pre) atomicAdd(&hist[(k >> shift) & 255], 1);
        }
        __syncthreads();
        if (tid == 0) {
            int r = ctrl[1]; unsigned pf = (unsigned)ctrl[0];
            for (int bin = 0; bin < 256; ++bin) {
                const int cnt = hist[bin];
                if (r > cnt) r -= cnt;
                else { pf |= ((unsigned)bin) << shift; break; }
            }
            ctrl[0] = (int)pf; ctrl[1] = r;
        }
    }
    __syncthreads();
    const unsigned T = (unsigned)ctrl[0];
    if (tid == 0) { ctrl[2] = 0; ctrl[3] = 0; }
    __syncthreads();
    int* out = idx_out + (size_t)bs * NKNN;
    for (int n = tid; n < NPTS; n += 256) {
        const unsigned k = keys[n];
        if (k < T) {
            const int pos = atomicAdd(&ctrl[2], 1);
            if (pos < NKNN) out[pos] = n;
        } else if (k == T) {
            const int pos = atomicAdd(&ctrl[3], 1);
            if (pos < 128) ties[pos] = n;
        }
    }
    __syncthreads();
    if (tid == 0) {
        const int nless = ctrl[2] < NKNN ? ctrl[2] : NKNN;
        const int need = NKNN - nless;
        const int ntie = ctrl[3] < 128 ? ctrl[3] : 128;
        int last = -1;
        for (int j = 0; j < need; ++j) {
            int best = 0x7fffffff;
            for (int i = 0; i < ntie; ++i) {
                const int v = ties[i];
                if (v > last && v < best) best = v;
            }
            out[nless + j] = (best == 0x7fffffff) ? 0 : best;
            last = best;
        }
    }
}

// ============================ stats helpers ============================
__global__ void zero_stats_kernel(double* st)
{
    const int i = blockIdx.x * 256 + threadIdx.x;
    if (i < 512) st[i] = 0.0;
}

__global__ __launch_bounds__(256) void gxmoments_kernel(
    const float* __restrict__ xyz, const float* __restrict__ newxyz,
    const int* __restrict__ idxws, double* __restrict__ stats)
{
    const int tid = threadIdx.x;
    double m[9];
    #pragma unroll
    for (int i = 0; i < 9; ++i) m[i] = 0.0;
    for (int row = blockIdx.x * 256 + tid; row < NROWS; row += gridDim.x * 256) {
        const int bs = row >> 5;
        const int bb = row >> 15;
        const int id = idxws[row];
        const float* xp = xyz + ((size_t)bb * NPTS + id) * 3;
        const float* qp = newxyz + bs * 3;
        const float gx = xp[0] - qp[0];
        const float gy = xp[1] - qp[1];
        const float gz = xp[2] - qp[2];
        const double dx = gx, dy = gy, dz = gz;
        m[0] += dx; m[1] += dy; m[2] += dz;
        m[3] += dx*dx; m[4] += dx*dy; m[5] += dx*dz;
        m[6] += dy*dy; m[7] += dy*dz; m[8] += dz*dz;
    }
    #pragma unroll
    for (int i = 0; i < 9; ++i) {
        #pragma unroll
        for (int s = 1; s < 64; s <<= 1) m[i] += __shfl_xor(m[i], s);
    }
    __shared__ double part[4][9];
    if ((tid & 63) == 0) {
        #pragma unroll
        for (int i = 0; i < 9; ++i) part[tid >> 6][i] = m[i];
    }
    __syncthreads();
    if (tid < 9) atomicAdd(&stats[tid], part[0][tid] + part[1][tid] + part[2][tid] + part[3][tid]);
}

__global__ void bn0_moments_finalize_kernel(const double* __restrict__ st,
    const float* __restrict__ w0, const float* __restrict__ b0,
    const float* __restrict__ g0, const float* __restrict__ be0,
    float* __restrict__ outp)
{
    const int c = threadIdx.x;  // 64
    const double N = (double)NROWS;
    const double w0c = w0[c], w1c = w0[64 + c], w2c = w0[128 + c];
    const double b = b0[c];
    const double dotS = st[0]*w0c + st[1]*w1c + st[2]*w2c;
    const double qf = w0c*w0c*st[3] + w1c*w1c*st[6] + w2c*w2c*st[8]
                    + 2.0*(w0c*w1c*st[4] + w0c*w2c*st[5] + w1c*w2c*st[7]);
    const double mean = dotS / N + b;
    const double ex2 = (qf + 2.0*b*dotS) / N + b*b;
    const double var = ex2 - mean*mean;
    const float scale = g0[c] * rsqrtf((float)var + BN_EPS);
    outp[c] = scale;
    outp[64 + c] = be0[c] - (float)mean * scale;
}

template<int L>
__global__ __launch_bounds__(256) void lstats_kernel(
    const float* __restrict__ xyz, const float* __restrict__ newxyz,
    const int* __restrict__ idxws,
    const float* __restrict__ w0, const float* __restrict__ b0,
    const float* __restrict__ w1, const float* __restrict__ b1,
    const float* __restrict__ w2, const float* __restrict__ b2,
    const float* __restrict__ bnp, double* __restrict__ stats)
{
    __shared__ __align__(16) float w1s[4096];
    __shared__ __align__(16) float w2s[4096];
    __shared__ float w0s[192];
    __shared__ float gxs[8][3];
    __shared__ __align__(16) float hb1[8][64];
    __shared__ __align__(16) float hb2[8][64];
    __shared__ double rs[256], rs2[256];
    const int tid = threadIdx.x;
    const int c = tid & 63;
    const int rq = tid >> 6;
    const int s0v = rq * 2, s1v = rq * 2 + 1;
    if (tid < 192) w0s[tid] = w0[tid];
    for (int i = tid; i < 4096; i += 256) w1s[i] = w1[i];
    if (L >= 2) for (int i = tid; i < 4096; i += 256) w2s[i] = w2[i];
    const float b0c = b0[c];
    const float b1c = b1[c], sc0 = bnp[c], sh0 = bnp[64+c];
    float b2c = 0.f, sc1 = 0.f, sh1 = 0.f;
    if (L >= 2) { b2c = b2[c]; sc1 = bnp[128+c]; sh1 = bnp[192+c]; }
    __syncthreads();
    double s = 0.0, s2 = 0.0;
    const int ntiles = NROWS / 8;
    for (int tile = blockIdx.x; tile < ntiles; tile += gridDim.x) {
        if (tid < 24) {
            const int slot = tid / 3, cc = tid % 3;
            const int row = tile * 8 + slot;
            const int bs = row >> 5;
            const int bb = row >> 15;
            const int id = idxws[row];
            gxs[slot][cc] = xyz[((size_t)bb * NPTS + id) * 3 + cc] - newxyz[bs*3 + cc];
        }
        __syncthreads();
        {
            const float t00 = gxs[s0v][0]*w0s[c] + gxs[s0v][1]*w0s[64+c] + gxs[s0v][2]*w0s[128+c] + b0c;
            const float t01 = gxs[s1v][0]*w0s[c] + gxs[s1v][1]*w0s[64+c] + gxs[s1v][2]*w0s[128+c] + b0c;
            hb1[s0v][c] = fmaxf(sc0*t00 + sh0, 0.f);
            hb1[s1v][c] = fmaxf(sc0*t01 + sh0, 0.f);
        }
        __syncthreads();
        float t10 = b1c, t11 = b1c;
        {
            const float4* h0p = (const float4*)&hb1[s0v][0];
            const float4* h1p = (const float4*)&hb1[s1v][0];
            #pragma unroll
            for (int j4 = 0; j4 < 16; ++j4) {
                const float4 h0 = h0p[j4], h1 = h1p[j4];
                const float* wr = &w1s[j4*256 + c];
                const float wv0 = wr[0], wv1 = wr[64], wv2 = wr[128], wv3 = wr[192];
                t10 += h0.x*wv0 + h0.y*wv1 + h0.z*wv2 + h0.w*wv3;
                t11 += h1.x*wv0 + h1.y*wv1 + h1.z*wv2 + h1.w*wv3;
            }
        }
        if (L == 1) {
            s  += (double)t10 + (double)t11;
            s2 += (double)t10*(double)t10 + (double)t11*(double)t11;
            __syncthreads();
        } else {
            hb2[s0v][c] = fmaxf(sc1*t10 + sh1, 0.f);
            hb2[s1v][c] = fmaxf(sc1*t11 + sh1, 0.f);
            __syncthreads();
            float t20 = b2c, t21 = b2c;
            const float4* h0p = (const float4*)&hb2[s0v][0];
            const float4* h1p = (const float4*)&hb2[s1v][0];
            #pragma unroll
            for (int j4 = 0; j4 < 16; ++j4) {
                const float4 h0 = h0p[j4], h1 = h1p[j4];
                const float* wr = &w2s[j4*256 + c];
                const float wv0 = wr[0], wv1 = wr[64], wv2 = wr[128], wv3 = wr[192];
                t20 += h0.x*wv0 + h0.y*wv1 + h0.z*wv2 + h0.w*wv3;
                t21 += h1.x*wv0 + h1.y*wv1 + h1.z*wv2 + h1.w*wv3;
            }
            s  += (double)t20 + (double)t21;
            s2 += (double)t20*(double)t20 + (double)t21*(double)t21;
            __syncthreads();
        }
    }
    rs[tid] = s; rs2[tid] = s2;
    __syncthreads();
    if (tid < 64) {
        const double a  = rs[c]  + rs[64+c]  + rs[128+c]  + rs[192+c];
        const double a2 = rs2[c] + rs2[64+c] + rs2[128+c] + rs2[192+c];
        atomicAdd(&stats[c], a);
        atomicAdd(&stats[64 + c], a2);
    }
}

__global__ void bn_finalize_kernel(const double* __restrict__ st,
                                   const float* __restrict__ g,
                                   const float* __restrict__ be,
                                   float* __restrict__ outp, float n)
{
    const int c = threadIdx.x;  // 64
    const double m = st[c] / (double)n;
    const double var = st[64 + c] / (double)n - m * m;
    const float scale = g[c] * rsqrtf((float)var + BN_EPS);
    outp[c] = scale;
    outp[64 + c] = be[c] - (float)m * scale;
}

// ============================ wf pre-pack ============================
// wf (4096x64 f32) -> B-fragment-ordered bf16 pairs: wfb[ktile128][otile4][lane64][4]
// B-frag: lane l holds col o = ot*16 + (l&15), k = kt*32 + (l>>4)*8 + j.
__global__ void wfpack_kernel(const float* __restrict__ wf, unsigned* __restrict__ wfb)
{
    const int blk = blockIdx.x;           // 512 = kt*4 + ot
    const int kt = blk >> 2, ot = blk & 3;
    const int l = threadIdx.x;            // 64
    const int o = ot*16 + (l & 15);
    const int kb = kt*32 + (l >> 4)*8;
    unsigned out[4];
    #pragma unroll
    for (int r = 0; r < 4; ++r) {
        const float a = wf[(size_t)(kb + 2*r) * 64 + o];
        const float b = wf[(size_t)(kb + 2*r + 1) * 64 + o];
        out[r] = pack_bf16pair(a, b);
    }
    *(uint4*)&wfb[((size_t)blk * 64 + l) * 4] = *(const uint4*)out;
}

// ============================ final fused conv ============================
// 256 thr, 8 centroids/block. Phase A (VALU, unchanged): weightnet ->
// wtp[e][kp][c] bf16 k-pairs. Phase B (MFMA 16x16x32 bf16):
//  nf^T: D[m=w][n=d] = wt^T(A) x gf(B-gathered-from-feat); pack D -> ya (LDS,
//  XOR-swizzled, aliases Phase-A weight region); y: D[m=s][n=o] accumulated
//  over 128 ktiles, A from ya, B from pre-packed wfb (coalesced dwordx4).
__global__ __launch_bounds__(256) void final_conv_kernel(
    const float* __restrict__ xyz, const float* __restrict__ newxyz,
    const int* __restrict__ idxws, const float* __restrict__ feat,
    const float* __restrict__ w0, const float* __restrict__ b0,
    const float* __restrict__ w1, const float* __restrict__ b1,
    const float* __restrict__ w2, const float* __restrict__ b2,
    const float* __restrict__ bnp, const unsigned* __restrict__ wfb,
    const float* __restrict__ bf, float* __restrict__ y)
{
    __shared__ unsigned wtp[8][16][64];            // 32 KB packed bf16 pairs (k,k+1)
    __shared__ __align__(16) float uni[2][4096];   // 32 KB: A: w1s/w2s; B: ya
    __shared__ __align__(16) float hb1[8][64];
    __shared__ __align__(16) float hb2[8][64];
    __shared__ int   idxs[8][32];
    __shared__ float qs[8][3];
    __shared__ float gxs[8][3];
    __shared__ float w0s[192];
    const int tid = threadIdx.x;
    const int c = tid & 63;
    const int rq = tid >> 6;          // 0..3 (wave id)
    const int bs0 = blockIdx.x * 8;
    const int b = bs0 >> 10;
    idxs[tid >> 5][tid & 31] = idxws[(size_t)bs0 * NKNN + tid];
    if (tid < 24)  qs[tid / 3][tid % 3] = newxyz[(bs0 + tid/3)*3 + (tid % 3)];
    if (tid < 192) w0s[tid] = w0[tid];
    for (int i = tid; i < 4096; i += 256) { uni[0][i] = w1[i]; uni[1][i] = w2[i]; }
    const float b0c = b0[c], b1c = b1[c], b2c = b2[c];
    const float sc0 = bnp[c],     sh0 = bnp[64+c];
    const float sc1 = bnp[128+c], sh1 = bnp[192+c];
    const float sc2 = bnp[256+c], sh2 = bnp[320+c];
    __syncthreads();
    // -------- Phase A: weightnet (VALU, 2 rows/thread) --------
    const int s0v = rq * 2, s1v = s0v + 1;
    for (int it = 0; it < 32; ++it) {
        if (tid < 24) {
            const int slot = tid / 3, cc = tid % 3;
            const int row = it * 8 + slot;
            const int e = row >> 5, k = row & 31;
            gxs[slot][cc] = xyz[((size_t)b * NPTS + idxs[e][k]) * 3 + cc] - qs[e][cc];
        }
        __syncthreads();
        {
            const float t00 = gxs[s0v][0]*w0s[c] + gxs[s0v][1]*w0s[64+c] + gxs[s0v][2]*w0s[128+c] + b0c;
            const float t01 = gxs[s1v][0]*w0s[c] + gxs[s1v][1]*w0s[64+c] + gxs[s1v][2]*w0s[128+c] + b0c;
            hb1[s0v][c] = fmaxf(sc0*t00 + sh0, 0.f);
            hb1[s1v][c] = fmaxf(sc0*t01 + sh0, 0.f);
        }
        __syncthreads();
        float t10 = b1c, t11 = b1c;
        {
            const float4* h0p = (const float4*)&hb1[s0v][0];
            const float4* h1p = (const float4*)&hb1[s1v][0];
            #pragma unroll
            for (int j4 = 0; j4 < 16; ++j4) {
                const float4 h0 = h0p[j4], h1 = h1p[j4];
                const float* wr = &uni[0][j4*256 + c];
                const float wv0 = wr[0], wv1 = wr[64], wv2 = wr[128], wv3 = wr[192];
                t10 += h0.x*wv0 + h0.y*wv1 + h0.z*wv2 + h0.w*wv3;
                t11 += h1.x*wv0 + h1.y*wv1 + h1.z*wv2 + h1.w*wv3;
            }
        }
        hb2[s0v][c] = fmaxf(sc1*t10 + sh1, 0.f);
        hb2[s1v][c] = fmaxf(sc1*t11 + sh1, 0.f);
        __syncthreads();
        float t20 = b2c, t21 = b2c;
        {
            const float4* h0p = (const float4*)&hb2[s0v][0];
            const float4* h1p = (const float4*)&hb2[s1v][0];
            #pragma unroll
            for (int j4 = 0; j4 < 16; ++j4) {
                const float4 h0 = h0p[j4], h1 = h1p[j4];
                const float* wr = &uni[1][j4*256 + c];
                const float wv0 = wr[0], wv1 = wr[64], wv2 = wr[128], wv3 = wr[192];
                t20 += h0.x*wv0 + h0.y*wv1 + h0.z*wv2 + h0.w*wv3;
                t21 += h1.x*wv0 + h1.y*wv1 + h1.z*wv2 + h1.w*wv3;
            }
        }
        {
            const int r0 = it * 8 + s0v;
            const int e0 = r0 >> 5, k0 = r0 & 31;
            wtp[e0][k0 >> 1][c] = pack_bf16pair(fmaxf(sc2*t20 + sh2, 0.f),
                                                fmaxf(sc2*t21 + sh2, 0.f));
        }
        __syncthreads();
    }
    // -------- Phase B: MFMA --------
    const int lane = tid & 63;
    const int wid  = rq;              // wave owns y-otile = wid
    const int lg   = lane >> 4;       // lane group 0..3
    const int lm   = lane & 15;
    unsigned* yaf = (unsigned*)uni;   // ya[8][1024], swizzled
    // preload nf A-frags (wt): A[m=w][k], lane row w=wt*16+lm, k=lg*8+j
    frag_u afr[2][4];
    #pragma unroll
    for (int es = 0; es < 2; ++es)
        #pragma unroll
        for (int w4 = 0; w4 < 4; ++w4)
            #pragma unroll
            for (int r = 0; r < 4; ++r)
                afr[es][w4].u[r] = wtp[wid*2 + es][lg*4 + r][w4*16 + lm];
    f32x4 yacc = {0.f, 0.f, 0.f, 0.f};
    for (int dhalf = 0; dhalf < 2; ++dhalf) {
        // ---- nf^T MFMAs: gather gf B-frags straight from feat ----
        #pragma unroll
        for (int es = 0; es < 2; ++es) {
            const int e = wid*2 + es;
            #pragma unroll
            for (int dt = 0; dt < 2; ++dt) {
                const int d = dhalf*32 + dt*16 + lm;
                const float* fb = feat + (size_t)(b*64 + d) * NPTS;
                frag_u B;
                #pragma unroll
                for (int r = 0; r < 4; ++r) {
                    const int k0 = lg*8 + 2*r;
                    B.u[r] = pack_bf16pair(fb[idxs[e][k0]], fb[idxs[e][k0+1]]);
                }
                #pragma unroll
                for (int w4 = 0; w4 < 4; ++w4) {
                    f32x4 dnf = {0.f, 0.f, 0.f, 0.f};
                    dnf = __builtin_amdgcn_mfma_f32_16x16x32_bf16(afr[es][w4].h, B.h, dnf, 0, 0, 0);
                    const unsigned p0 = pack_bf16pair(dnf[0], dnf[1]);
                    const unsigned p1 = pack_bf16pair(dnf[2], dnf[3]);
                    const int dloc = dt*16 + lm;
                    const int kp0 = dloc*32 + w4*8 + lg*2;
                    const int sw = kp0 ^ ((lm & 3) << 3) ^ ((e & 7) << 2);
                    *(uint2*)&yaf[e*1024 + sw] = make_uint2(p0, p1);
                }
            }
        }
        __syncthreads();
        // ---- y partial: 64 ktiles of this half, wave owns otile=wid ----
        for (int kt = 0; kt < 64; ++kt) {
            frag_u A, Bf;
            const int kpb = (kt*16 + lg*4) ^ (((kt >> 1) & 3) << 3) ^ ((lm & 7) << 2);
            A.u4 = *(const uint4*)&yaf[(lm & 7)*1024 + kpb];
            Bf.u4 = *(const uint4*)&wfb[(((size_t)(dhalf*64 + kt)*4 + wid)*64 + lane)*4];
            yacc = __builtin_amdgcn_mfma_f32_16x16x32_bf16(A.h, Bf.h, yacc, 0, 0, 0);
        }
        __syncthreads();
    }
    // ---- store: D row s = lg*4+r (valid <8), col o = wid*16+lm ----
    if (lg < 2) {
        const float bfo = bf[wid*16 + lm];
        #pragma unroll
        for (int r = 0; r < 4; ++r)
            y[(size_t)(bs0 + lg*4 + r) * 64 + wid*16 + lm] = yacc[r] + bfo;
    }
}

__global__ __launch_bounds__(256) void ystats_kernel(const float* __restrict__ y,
                                                     double* __restrict__ st)
{
    const int tid = threadIdx.x;
    const int c = tid & 63;
    double s = 0.0, s2 = 0.0;
    for (int i = blockIdx.x * 256 + tid; i < NBATCH*NSAMP*64; i += gridDim.x * 256) {
        const float v = y[i];
        s += v; s2 += (double)v * (double)v;
    }
    __shared__ double rs[256], rs2[256];
    rs[tid] = s; rs2[tid] = s2;
    __syncthreads();
    if (tid < 64) {
        const double a  = rs[c]  + rs[64+c]  + rs[128+c]  + rs[192+c];
        const double a2 = rs2[c] + rs2[64+c] + rs2[128+c] + rs2[192+c];
        atomicAdd(&st[c], a);
        atomicAdd(&st[64 + c], a2);
    }
}

__global__ void writeout_kernel(const float* __restrict__ y,
                                const float* __restrict__ bnp3,
                                float* __restrict__ outp)
{
    const int i = blockIdx.x * 256 + threadIdx.x;
    if (i >= NBATCH * 64 * NSAMP) return;
    const int s = i & 1023;
    const int o = (i >> 10) & 63;
    const int bb = i >> 16;
    const float v = y[((size_t)(bb << 10) + s) * 64 + o];
    outp[i] = fmaxf(bnp3[o] * v + bnp3[64 + o], 0.f);
}

// ============================ launch ============================
extern "C" void kernel_launch(void* const* d_in, const int* in_sizes, int n_in,
                              void* d_out, int out_size, void* d_ws, size_t ws_size,
                              hipStream_t stream)
{
    (void)in_sizes; (void)n_in; (void)out_size; (void)ws_size;
    const float* xyz  = (const float*)d_in[0];
    const float* feat = (const float*)d_in[1];
    const float* w0   = (const float*)d_in[2];
    const float* b0   = (const float*)d_in[3];
    const float* g0   = (const float*)d_in[4];
    const float* be0  = (const float*)d_in[5];
    const float* w1   = (const float*)d_in[6];
    const float* b1   = (const float*)d_in[7];
    const float* g1   = (const float*)d_in[8];
    const float* be1  = (const float*)d_in[9];
    const float* w2   = (const float*)d_in[10];
    const float* b2   = (const float*)d_in[11];
    const float* g2   = (const float*)d_in[12];
    const float* be2  = (const float*)d_in[13];
    const float* wf   = (const float*)d_in[14];
    const float* bf   = (const float*)d_in[15];
    const float* gf   = (const float*)d_in[16];
    const float* bef  = (const float*)d_in[17];

    float* out = (float*)d_out;
    float* newxyz = out;                       // (B, S, 3)
    float* outmain = out + NBATCH * NSAMP * 3; // (B, 64, S)

    char* ws = (char*)d_ws;
    int*      idxws = (int*)ws;                                   // 2 MB
    float*    ybuf  = (float*)(ws + 2097152);                     // 4 MB
    double*   stats = (double*)(ws + 2097152 + 4194304);          // 4 KB
    float*    bnp   = (float*)(ws + 2097152 + 4194304 + 4096);    // 2 KB
    unsigned* wfb   = (unsigned*)(ws + 2097152 + 4194304 + 4096 + 2048); // 512 KB

    zero_stats_kernel<<<2, 256, 0, stream>>>(stats);
    wfpack_kernel<<<512, 64, 0, stream>>>(wf, wfb);
    fps_kernel<<<NBATCH, 256, 0, stream>>>(xyz, newxyz);
    knn_kernel<<<NBATCH * NSAMP, 256, 0, stream>>>(xyz, newxyz, idxws);

    gxmoments_kernel<<<512, 256, 0, stream>>>(xyz, newxyz, idxws, stats);
    bn0_moments_finalize_kernel<<<1, 64, 0, stream>>>(stats, w0, b0, g0, be0, bnp);
    lstats_kernel<1><<<1024, 256, 0, stream>>>(xyz, newxyz, idxws, w0, b0, w1, b1, w2, b2, bnp, stats + 128);
    bn_finalize_kernel<<<1, 64, 0, stream>>>(stats + 128, g1, be1, bnp + 128, (float)NROWS);
    lstats_kernel<2><<<1024, 256, 0, stream>>>(xyz, newxyz, idxws, w0, b0, w1, b1, w2, b2, bnp, stats + 256);
    bn_finalize_kernel<<<1, 64, 0, stream>>>(stats + 256, g2, be2, bnp + 256, (float)NROWS);

    final_conv_kernel<<<NBATCH * NSAMP / 8, 256, 0, stream>>>(
        xyz, newxyz, idxws, feat, w0, b0, w1, b1, w2, b2, bnp, wfb, bf, ybuf);

    ystats_kernel<<<256, 256, 0, stream>>>(ybuf, stats + 384);
    bn_finalize_kernel<<<1, 64, 0, stream>>>(stats + 384, gf, bef, bnp + 384, (float)(NBATCH * NSAMP));
    writeout_kernel<<<4096, 256, 0, stream>>>(ybuf, bnp + 384, outmain);
}

// Round 7
// 1672.929 us; speedup vs baseline: 2.8959x; 1.2774x over previous
//
#include <hip/hip_runtime.h>

#define NBATCH 16
#define NPTS   4096
#define NSAMP  1024
#define NKNN   32
#define NROWS  (NBATCH*NSAMP*NKNN)   // 524288
#define BN_EPS 1e-5f
#define H1PAD  66

typedef __attribute__((ext_vector_type(4))) float f32x4;
typedef __attribute__((ext_vector_type(8))) short bf16x8;
union frag_u { unsigned u[4]; bf16x8 h; uint4 u4; };

__device__ __forceinline__ unsigned pack_bf16pair(float a, float b) {
    unsigned ua = __float_as_uint(a); ua += 0x7FFFu + ((ua >> 16) & 1u);
    unsigned ub = __float_as_uint(b); ub += 0x7FFFu + ((ub >> 16) & 1u);
    return (ua >> 16) | (ub & 0xFFFF0000u);
}

// ============================ FPS v3 ============================
// (validated rounds 1-6 — arithmetic untouched)
__global__ __launch_bounds__(256) void fps_kernel(const float* __restrict__ xyz,
                                                  float* __restrict__ newxyz)
{
    const int b = blockIdx.x;
    const int tid = threadIdx.x;
    const int wv = tid >> 6;
    const float* xb = xyz + (size_t)b * NPTS * 3;
    __shared__ float xs[NPTS];
    __shared__ float ys[NPTS];
    __shared__ float zs[NPTS];
    __shared__ __align__(16) float red_v[2][4];
    __shared__ __align__(16) int   red_i[2][4];
    float px[16], py[16], pz[16], dmin[16];
    {
        float arr[48];
        const float4* s4 = (const float4*)(xb + (size_t)tid * 48);
        #pragma unroll
        for (int i = 0; i < 12; ++i) *(float4*)&arr[i*4] = s4[i];
        #pragma unroll
        for (int j = 0; j < 16; ++j) {
            px[j] = arr[3*j]; py[j] = arr[3*j+1]; pz[j] = arr[3*j+2];
            const int p = tid * 16 + j;
            xs[p] = px[j]; ys[p] = py[j]; zs[p] = pz[j];
            dmin[j] = 1e10f;
        }
    }
    if (tid == 0) {
        float* o = newxyz + (size_t)b * NSAMP * 3;
        o[0] = xb[0]; o[1] = xb[1]; o[2] = xb[2];
    }
    __syncthreads();
    float lx = xs[0], ly = ys[0], lz = zs[0];
    for (int t = 1; t < NSAMP; ++t) {
        float bv = -1.0f;
        #pragma unroll
        for (int j = 0; j < 16; ++j) {
            const float dx = __fsub_rn(px[j], lx);
            const float dy = __fsub_rn(py[j], ly);
            const float dz = __fsub_rn(pz[j], lz);
            const float d = __fadd_rn(__fadd_rn(__fmul_rn(dx,dx), __fmul_rn(dy,dy)), __fmul_rn(dz,dz));
            const float nd = fminf(dmin[j], d);
            dmin[j] = nd;
            bv = fmaxf(bv, nd);
        }
        int lj = 0;
        #pragma unroll
        for (int j = 15; j >= 0; --j) if (dmin[j] == bv) lj = j;
        const int bi_lane = tid * 16 + lj;
        float mv = bv;
        #pragma unroll
        for (int m = 1; m < 64; m <<= 1) mv = fmaxf(mv, __shfl_xor(mv, m));
        const unsigned long long mask = __ballot(bv == mv);
        const int winner = __ffsll(mask) - 1;
        const int bi_w = __builtin_amdgcn_readlane(bi_lane, winner);
        const int par = t & 1;
        if ((tid & 63) == 0) { red_v[par][wv] = mv; red_i[par][wv] = bi_w; }
        __syncthreads();
        const float4 rv = *(const float4*)&red_v[par][0];
        const int4   ri = *(const int4*)&red_i[par][0];
        float fv = rv.x; int bi = ri.x;
        if (rv.y > fv) { fv = rv.y; bi = ri.y; }
        if (rv.z > fv) { fv = rv.z; bi = ri.z; }
        if (rv.w > fv) { fv = rv.w; bi = ri.w; }
        lx = xs[bi]; ly = ys[bi]; lz = zs[bi];
        if (tid == 0) {
            float* o = newxyz + ((size_t)b * NSAMP + t) * 3;
            o[0] = lx; o[1] = ly; o[2] = lz;
        }
    }
}

// ============================ kNN ============================
// (validated rounds 2-6)
__global__ __launch_bounds__(256) void knn_kernel(const float* __restrict__ xyz,
                                                  const float* __restrict__ newxyz,
                                                  int* __restrict__ idx_out)
{
    const int bs = blockIdx.x;
    const int b = bs >> 10;
    const int tid = threadIdx.x;
    __shared__ unsigned keys[NPTS];
    __shared__ int hist[256];
    __shared__ float qsh[3];
    __shared__ int ctrl[4];
    __shared__ int ties[128];
    if (tid < 3) qsh[tid] = newxyz[bs*3 + tid];
    if (tid == 0) { ctrl[0] = 0; ctrl[1] = NKNN; }
    __syncthreads();
    const float q0 = qsh[0], q1 = qsh[1], q2 = qsh[2];
    const float qq = __fadd_rn(__fadd_rn(__fmul_rn(q0,q0), __fmul_rn(q1,q1)), __fmul_rn(q2,q2));
    const float* xb = xyz + (size_t)b * NPTS * 3;
    for (int n = tid; n < NPTS; n += 256) {
        const float x0 = xb[n*3+0], x1 = xb[n*3+1], x2 = xb[n*3+2];
        const float xx = __fadd_rn(__fadd_rn(__fmul_rn(x0,x0), __fmul_rn(x1,x1)), __fmul_rn(x2,x2));
        float dt = __fmul_rn(q0, x0);
        dt = __fmaf_rn(q1, x1, dt);
        dt = __fmaf_rn(q2, x2, dt);
        const float dd = __fadd_rn(__fsub_rn(qq, __fmul_rn(2.0f, dt)), xx);
        unsigned ub = __float_as_uint(dd);
        ub = (ub & 0x80000000u) ? ~ub : (ub | 0x80000000u);
        keys[n] = ub;
    }
    for (int p = 3; p >= 0; --p) {
        __syncthreads();
        hist[tid] = 0;
        __syncthreads();
        const unsigned pre = (unsigned)ctrl[0];
        const int shift = p * 8;
        const unsigned himask = (p == 3) ? 0u : (0xFFFFFFFFu << ((p + 1) * 8));
        for (int n = tid; n < NPTS; n += 256) {
            const unsigned k = keys[n];
            if ((k & himask) == pre) atomicAdd(&hist[(k >> shift) & 255], 1);
        }
        __syncthreads();
        if (tid == 0) {
            int r = ctrl[1]; unsigned pf = (unsigned)ctrl[0];
            for (int bin = 0; bin < 256; ++bin) {
                const int cnt = hist[bin];
                if (r > cnt) r -= cnt;
                else { pf |= ((unsigned)bin) << shift; break; }
            }
            ctrl[0] = (int)pf; ctrl[1] = r;
        }
    }
    __syncthreads();
    const unsigned T = (unsigned)ctrl[0];
    if (tid == 0) { ctrl[2] = 0; ctrl[3] = 0; }
    __syncthreads();
    int* out = idx_out + (size_t)bs * NKNN;
    for (int n = tid; n < NPTS; n += 256) {
        const unsigned k = keys[n];
        if (k < T) {
            const int pos = atomicAdd(&ctrl[2], 1);
            if (pos < NKNN) out[pos] = n;
        } else if (k == T) {
            const int pos = atomicAdd(&ctrl[3], 1);
            if (pos < 128) ties[pos] = n;
        }
    }
    __syncthreads();
    if (tid == 0) {
        const int nless = ctrl[2] < NKNN ? ctrl[2] : NKNN;
        const int need = NKNN - nless;
        const int ntie = ctrl[3] < 128 ? ctrl[3] : 128;
        int last = -1;
        for (int j = 0; j < need; ++j) {
            int best = 0x7fffffff;
            for (int i = 0; i < ntie; ++i) {
                const int v = ties[i];
                if (v > last && v < best) best = v;
            }
            out[nless + j] = (best == 0x7fffffff) ? 0 : best;
            last = best;
        }
    }
}

// ============================ zero / moments ============================
__global__ void zero_all_kernel(double* st, float* g1, float* g2)
{
    const int i = blockIdx.x * 256 + threadIdx.x;
    if (i < 512) st[i] = 0.0;
    if (i < 4096) { g1[i] = 0.f; g2[i] = 0.f; }
}

__global__ __launch_bounds__(256) void gxmoments_kernel(
    const float* __restrict__ xyz, const float* __restrict__ newxyz,
    const int* __restrict__ idxws, double* __restrict__ stats)
{
    const int tid = threadIdx.x;
    double m[9];
    #pragma unroll
    for (int i = 0; i < 9; ++i) m[i] = 0.0;
    for (int row = blockIdx.x * 256 + tid; row < NROWS; row += gridDim.x * 256) {
        const int bs = row >> 5;
        const int bb = row >> 15;
        const int id = idxws[row];
        const float* xp = xyz + ((size_t)bb * NPTS + id) * 3;
        const float* qp = newxyz + bs * 3;
        const double dx = (double)(xp[0] - qp[0]);
        const double dy = (double)(xp[1] - qp[1]);
        const double dz = (double)(xp[2] - qp[2]);
        m[0] += dx; m[1] += dy; m[2] += dz;
        m[3] += dx*dx; m[4] += dx*dy; m[5] += dx*dz;
        m[6] += dy*dy; m[7] += dy*dz; m[8] += dz*dz;
    }
    #pragma unroll
    for (int i = 0; i < 9; ++i) {
        #pragma unroll
        for (int s = 1; s < 64; s <<= 1) m[i] += __shfl_xor(m[i], s);
    }
    __shared__ double part[4][9];
    if ((tid & 63) == 0) {
        #pragma unroll
        for (int i = 0; i < 9; ++i) part[tid >> 6][i] = m[i];
    }
    __syncthreads();
    if (tid < 9) atomicAdd(&stats[tid], part[0][tid] + part[1][tid] + part[2][tid] + part[3][tid]);
}

__global__ void bn0_moments_finalize_kernel(const double* __restrict__ st,
    const float* __restrict__ w0, const float* __restrict__ b0,
    const float* __restrict__ g0, const float* __restrict__ be0,
    float* __restrict__ outp)
{
    const int c = threadIdx.x;  // 64
    const double N = (double)NROWS;
    const double w0c = w0[c], w1c = w0[64 + c], w2c = w0[128 + c];
    const double b = b0[c];
    const double dotS = st[0]*w0c + st[1]*w1c + st[2]*w2c;
    const double qf = w0c*w0c*st[3] + w1c*w1c*st[6] + w2c*w2c*st[8]
                    + 2.0*(w0c*w1c*st[4] + w0c*w2c*st[5] + w1c*w2c*st[7]);
    const double mean = dotS / N + b;
    const double ex2 = (qf + 2.0*b*dotS) / N + b*b;
    const double var = ex2 - mean*mean;
    const float scale = g0[c] * rsqrtf((float)var + BN_EPS);
    outp[c] = scale;
    outp[64 + c] = be0[c] - (float)mean * scale;
}

// ============================ weight pre-pack ============================
// W (K x 64 f32, row-major) -> B-fragment bf16 pairs: [kt][ot][lane][4].
// lane l: col o = ot*16+(l&15), k = kt*32+(l>>4)*8 + j.  grid = ktiles*4.
__global__ void wfpack_kernel(const float* __restrict__ wf, unsigned* __restrict__ wfb)
{
    const int blk = blockIdx.x;
    const int kt = blk >> 2, ot = blk & 3;
    const int l = threadIdx.x;            // 64
    const int o = ot*16 + (l & 15);
    const int kb = kt*32 + (l >> 4)*8;
    unsigned out[4];
    #pragma unroll
    for (int r = 0; r < 4; ++r) {
        const float a = wf[(size_t)(kb + 2*r) * 64 + o];
        const float b = wf[(size_t)(kb + 2*r + 1) * 64 + o];
        out[r] = pack_bf16pair(a, b);
    }
    *(uint4*)&wfb[((size_t)blk * 64 + l) * 4] = *(const uint4*)out;
}

// ============================ Gram stats ============================
// BN1 stats: per row compute h1 = relu(bn0(gx@w0+b0)) (VALU), accumulate
// Sh1 (f32->f64 atomic) and G1 = H1^T H1 via MFMA (Gram frag trick:
// frag[ct] serves as both A (row-tile ct) and B (col-tile ct)).
__global__ __launch_bounds__(256) void gram1_kernel(
    const float* __restrict__ xyz, const float* __restrict__ newxyz,
    const int* __restrict__ idxws,
    const float* __restrict__ w0, const float* __restrict__ b0,
    const float* __restrict__ bnp, float* __restrict__ G1,
    double* __restrict__ Sh1)
{
    __shared__ float gxs[32][3];
    __shared__ float h1s[32][H1PAD];
    __shared__ float rsum[256];
    const int tid = threadIdx.x;
    const int c = tid & 63;
    const int rq = tid >> 6;
    const int lg = c >> 4, lm = c & 15;
    const float w0c0 = w0[c], w0c1 = w0[64+c], w0c2 = w0[128+c];
    const float b0c = b0[c], sc0 = bnp[c], sh0 = bnp[64+c];
    f32x4 Ga[4] = {{0,0,0,0},{0,0,0,0},{0,0,0,0},{0,0,0,0}};
    float sumh = 0.f;
    for (int chunk = blockIdx.x; chunk < NROWS/32; chunk += gridDim.x) {
        if (tid < 96) {
            const int slot = tid / 3, cc = tid % 3;
            const int row = chunk*32 + slot;
            const int bs = row >> 5, bb = row >> 15;
            gxs[slot][cc] = xyz[((size_t)bb * NPTS + idxws[row]) * 3 + cc] - newxyz[bs*3 + cc];
        }
        __syncthreads();
        #pragma unroll
        for (int i = 0; i < 8; ++i) {
            const int r = rq*8 + i;
            const float t0 = gxs[r][0]*w0c0 + gxs[r][1]*w0c1 + gxs[r][2]*w0c2 + b0c;
            const float h = fmaxf(sc0*t0 + sh0, 0.f);
            h1s[r][c] = h;
            sumh += h;
        }
        __syncthreads();
        frag_u fr[4];
        #pragma unroll
        for (int ct = 0; ct < 4; ++ct)
            #pragma unroll
            for (int r = 0; r < 4; ++r)
                fr[ct].u[r] = pack_bf16pair(h1s[lg*8 + 2*r][ct*16 + lm],
                                            h1s[lg*8 + 2*r + 1][ct*16 + lm]);
        #pragma unroll
        for (int ct = 0; ct < 4; ++ct)
            Ga[ct] = __builtin_amdgcn_mfma_f32_16x16x32_bf16(fr[rq].h, fr[ct].h, Ga[ct], 0, 0, 0);
        __syncthreads();
    }
    #pragma unroll
    for (int ct = 0; ct < 4; ++ct)
        #pragma unroll
        for (int r = 0; r < 4; ++r)
            atomicAdd(&G1[(rq*16 + lg*4 + r)*64 + ct*16 + lm], Ga[ct][r]);
    rsum[tid] = sumh;
    __syncthreads();
    if (tid < 64) atomicAdd(&Sh1[c], (double)(rsum[c] + rsum[64+c] + rsum[128+c] + rsum[192+c]));
}

// BN2 stats: h1 (VALU) -> t1 via MFMA (bf16, prepacked w1b) -> h2 ->
// Sh2 + G2 via Gram MFMA.
__global__ __launch_bounds__(256) void gram2_kernel(
    const float* __restrict__ xyz, const float* __restrict__ newxyz,
    const int* __restrict__ idxws,
    const float* __restrict__ w0, const float* __restrict__ b0,
    const float* __restrict__ b1, const unsigned* __restrict__ w1b,
    const float* __restrict__ bnp, float* __restrict__ G2,
    double* __restrict__ Sh2)
{
    __shared__ float gxs[32][3];
    __shared__ float h1s[32][H1PAD];
    __shared__ float h2s[32][H1PAD];
    __shared__ float rsum[256];
    const int tid = threadIdx.x;
    const int c = tid & 63;
    const int rq = tid >> 6;          // wave id = ot for t1 stage
    const int lg = c >> 4, lm = c & 15;
    const int c2 = rq*16 + lm;        // t1/h2 output channel
    const float w0c0 = w0[c], w0c1 = w0[64+c], w0c2 = w0[128+c];
    const float b0c = b0[c], sc0 = bnp[c], sh0 = bnp[64+c];
    const float b1c2 = b1[c2], sc1 = bnp[128+c2], sh1 = bnp[192+c2];
    frag_u Bw1[2];
    Bw1[0].u4 = *(const uint4*)&w1b[((0*4 + rq)*64 + c)*4];
    Bw1[1].u4 = *(const uint4*)&w1b[((1*4 + rq)*64 + c)*4];
    f32x4 Ga[4] = {{0,0,0,0},{0,0,0,0},{0,0,0,0},{0,0,0,0}};
    float sumh = 0.f;
    for (int chunk = blockIdx.x; chunk < NROWS/32; chunk += gridDim.x) {
        if (tid < 96) {
            const int slot = tid / 3, cc = tid % 3;
            const int row = chunk*32 + slot;
            const int bs = row >> 5, bb = row >> 15;
            gxs[slot][cc] = xyz[((size_t)bb * NPTS + idxws[row]) * 3 + cc] - newxyz[bs*3 + cc];
        }
        __syncthreads();
        #pragma unroll
        for (int i = 0; i < 8; ++i) {
            const int r = rq*8 + i;
            const float t0 = gxs[r][0]*w0c0 + gxs[r][1]*w0c1 + gxs[r][2]*w0c2 + b0c;
            h1s[r][c] = fmaxf(sc0*t0 + sh0, 0.f);
        }
        __syncthreads();
        // t1 tiles: wave rq = otile; mt 0..1, kt 0..1
        #pragma unroll
        for (int mt = 0; mt < 2; ++mt) {
            f32x4 acc = {0,0,0,0};
            #pragma unroll
            for (int kt = 0; kt < 2; ++kt) {
                frag_u a;
                #pragma unroll
                for (int r = 0; r < 4; ++r) {
                    const float2 f = *(const float2*)&h1s[mt*16 + lm][kt*32 + lg*8 + 2*r];
                    a.u[r] = pack_bf16pair(f.x, f.y);
                }
                acc = __builtin_amdgcn_mfma_f32_16x16x32_bf16(a.h, Bw1[kt].h, acc, 0, 0, 0);
            }
            #pragma unroll
            for (int r = 0; r < 4; ++r)
                h2s[mt*16 + lg*4 + r][c2] = fmaxf(sc1*(acc[r] + b1c2) + sh1, 0.f);
        }
        __syncthreads();
        #pragma unroll
        for (int i = 0; i < 8; ++i) sumh += h2s[rq*8 + i][c];
        frag_u fr[4];
        #pragma unroll
        for (int ct = 0; ct < 4; ++ct)
            #pragma unroll
            for (int r = 0; r < 4; ++r)
                fr[ct].u[r] = pack_bf16pair(h2s[lg*8 + 2*r][ct*16 + lm],
                                            h2s[lg*8 + 2*r + 1][ct*16 + lm]);
        #pragma unroll
        for (int ct = 0; ct < 4; ++ct)
            Ga[ct] = __builtin_amdgcn_mfma_f32_16x16x32_bf16(fr[rq].h, fr[ct].h, Ga[ct], 0, 0, 0);
        __syncthreads();
    }
    #pragma unroll
    for (int ct = 0; ct < 4; ++ct)
        #pragma unroll
        for (int r = 0; r < 4; ++r)
            atomicAdd(&G2[(rq*16 + lg*4 + r)*64 + ct*16 + lm], Ga[ct][r]);
    rsum[tid] = sumh;
    __syncthreads();
    if (tid < 64) atomicAdd(&Sh2[c], (double)(rsum[c] + rsum[64+c] + rsum[128+c] + rsum[192+c]));
}

// BN scale/shift from Sh, Gram, W, bias:
//  mean_c = (Sh.W_c)/N + b_c ;  E[t^2]_c = (W_c^T G W_c + 2 b_c Sh.W_c)/N + b_c^2
__global__ __launch_bounds__(256) void bn_gram_finalize_kernel(
    const double* __restrict__ Sh, const float* __restrict__ G,
    const float* __restrict__ w, const float* __restrict__ bias,
    const float* __restrict__ g, const float* __restrict__ be,
    float* __restrict__ outp)
{
    __shared__ float wls[64][65];
    __shared__ double shl[64];
    __shared__ double rd[256], rqd[256];
    const int tid = threadIdx.x;
    const int c = tid & 63;
    const int rqi = tid >> 6;
    for (int i = tid; i < 4096; i += 256) wls[i >> 6][i & 63] = w[i];
    if (tid < 64) shl[tid] = Sh[tid];
    __syncthreads();
    double dot = 0.0, quad = 0.0;
    for (int j = rqi*16; j < rqi*16 + 16; ++j) {
        const double wjc = (double)wls[j][c];
        dot += wjc * shl[j];
        double inner = 0.0;
        for (int k = 0; k < 64; ++k) inner += (double)G[j*64 + k] * (double)wls[k][c];
        quad += wjc * inner;
    }
    rd[tid] = dot; rqd[tid] = quad;
    __syncthreads();
    if (tid < 64) {
        const double d = rd[c] + rd[64+c] + rd[128+c] + rd[192+c];
        const double q = rqd[c] + rqd[64+c] + rqd[128+c] + rqd[192+c];
        const double N = (double)NROWS;
        const double bc = (double)bias[c];
        const double mean = d / N + bc;
        const double ex2 = (q + 2.0*bc*d) / N + bc*bc;
        const double var = ex2 - mean*mean;
        const float scale = g[c] * rsqrtf((float)var + BN_EPS);
        outp[c] = scale;
        outp[64 + c] = be[c] - (float)mean * scale;
    }
}

__global__ void bn_finalize_kernel(const double* __restrict__ st,
                                   const float* __restrict__ g,
                                   const float* __restrict__ be,
                                   float* __restrict__ outp, float n)
{
    const int c = threadIdx.x;  // 64
    const double m = st[c] / (double)n;
    const double var = st[64 + c] / (double)n - m * m;
    const float scale = g[c] * rsqrtf((float)var + BN_EPS);
    outp[c] = scale;
    outp[64 + c] = be[c] - (float)m * scale;
}

// ============================ final fused conv ============================
// 256 thr, 8 centroids/block. Phase A (MFMA): 64-row chunks, layer0 VALU ->
// t1/t2 via MFMA with prepacked w1b/w2b -> wtp k-pairs from D r-pairs.
// Phase B (validated round 5/6): nf^T MFMA -> ya (swizzled LDS) -> y MFMA.
__global__ __launch_bounds__(256) void final_conv_kernel(
    const float* __restrict__ xyz, const float* __restrict__ newxyz,
    const int* __restrict__ idxws, const float* __restrict__ feat,
    const float* __restrict__ w0, const float* __restrict__ b0,
    const float* __restrict__ b1, const float* __restrict__ b2,
    const float* __restrict__ bnp, const unsigned* __restrict__ wfb,
    const unsigned* __restrict__ w1b, const unsigned* __restrict__ w2b,
    const float* __restrict__ bf, float* __restrict__ y)
{
    __shared__ unsigned wtp[8][16][64];              // 32 KB packed k-pairs
    __shared__ __align__(16) float scratch[2*64*H1PAD];  // 33.8 KB: h1s/h2s | ya
    __shared__ float gxs[64][3];
    __shared__ int   idxs[8][32];
    __shared__ float qs[8][3];
    float* h1s = scratch;                  // [64][H1PAD]
    float* h2s = scratch + 64*H1PAD;       // [64][H1PAD]
    unsigned* yaf = (unsigned*)scratch;    // Phase B: 8192 uints
    const int tid = threadIdx.x;
    const int c = tid & 63;
    const int rq = tid >> 6;              // wave id
    const int lg = c >> 4, lm = c & 15;
    const int c2 = rq*16 + lm;
    const int bs0 = blockIdx.x * 8;
    const int b = bs0 >> 10;
    idxs[tid >> 5][tid & 31] = idxws[(size_t)bs0 * NKNN + tid];
    if (tid < 24)  qs[tid / 3][tid % 3] = newxyz[(bs0 + tid/3)*3 + (tid % 3)];
    const float w0c0 = w0[c], w0c1 = w0[64+c], w0c2 = w0[128+c];
    const float b0c = b0[c], sc0 = bnp[c], sh0 = bnp[64+c];
    const float b1c2 = b1[c2], sc1 = bnp[128+c2], sh1 = bnp[192+c2];
    const float b2c2 = b2[c2], sc2 = bnp[256+c2], sh2 = bnp[320+c2];
    frag_u Bw1[2], Bw2[2];
    #pragma unroll
    for (int kt = 0; kt < 2; ++kt) {
        Bw1[kt].u4 = *(const uint4*)&w1b[((kt*4 + rq)*64 + c)*4];
        Bw2[kt].u4 = *(const uint4*)&w2b[((kt*4 + rq)*64 + c)*4];
    }
    __syncthreads();
    // -------- Phase A: weightnet via MFMA, 4 chunks of 64 rows --------
    for (int chunk = 0; chunk < 4; ++chunk) {
        if (tid < 192) {
            const int slot = tid / 3, cc = tid % 3;
            const int grow = chunk*64 + slot;
            const int e = grow >> 5, k = grow & 31;
            gxs[slot][cc] = xyz[((size_t)b * NPTS + idxs[e][k]) * 3 + cc] - qs[e][cc];
        }
        __syncthreads();
        #pragma unroll
        for (int i = 0; i < 16; ++i) {
            const int r = rq*16 + i;
            const float t0 = gxs[r][0]*w0c0 + gxs[r][1]*w0c1 + gxs[r][2]*w0c2 + b0c;
            h1s[r*H1PAD + c] = fmaxf(sc0*t0 + sh0, 0.f);
        }
        __syncthreads();
        // t1: wave rq = otile; mt 0..3, kt 0..1
        #pragma unroll
        for (int mt = 0; mt < 4; ++mt) {
            f32x4 acc = {0,0,0,0};
            #pragma unroll
            for (int kt = 0; kt < 2; ++kt) {
                frag_u a;
                #pragma unroll
                for (int r = 0; r < 4; ++r) {
                    const float2 f = *(const float2*)&h1s[(mt*16 + lm)*H1PAD + kt*32 + lg*8 + 2*r];
                    a.u[r] = pack_bf16pair(f.x, f.y);
                }
                acc = __builtin_amdgcn_mfma_f32_16x16x32_bf16(a.h, Bw1[kt].h, acc, 0, 0, 0);
            }
            #pragma unroll
            for (int r = 0; r < 4; ++r)
                h2s[(mt*16 + lg*4 + r)*H1PAD + c2] = fmaxf(sc1*(acc[r] + b1c2) + sh1, 0.f);
        }
        __syncthreads();
        // t2 + pack into wtp
        #pragma unroll
        for (int mt = 0; mt < 4; ++mt) {
            f32x4 acc = {0,0,0,0};
            #pragma unroll
            for (int kt = 0; kt < 2; ++kt) {
                frag_u a;
                #pragma unroll
                for (int r = 0; r < 4; ++r) {
                    const float2 f = *(const float2*)&h2s[(mt*16 + lm)*H1PAD + kt*32 + lg*8 + 2*r];
                    a.u[r] = pack_bf16pair(f.x, f.y);
                }
                acc = __builtin_amdgcn_mfma_f32_16x16x32_bf16(a.h, Bw2[kt].h, acc, 0, 0, 0);
            }
            float wt[4];
            #pragma unroll
            for (int r = 0; r < 4; ++r)
                wt[r] = fmaxf(sc2*(acc[r] + b2c2) + sh2, 0.f);
            const int grow0 = chunk*64 + mt*16 + lg*4;
            const int e = grow0 >> 5, kl = grow0 & 31;
            wtp[e][kl >> 1][c2]       = pack_bf16pair(wt[0], wt[1]);
            wtp[e][(kl >> 1) + 1][c2] = pack_bf16pair(wt[2], wt[3]);
        }
        __syncthreads();
    }
    // -------- Phase B: MFMA (validated) --------
    const int lane = c;
    const int wid = rq;
    frag_u afr[2][4];
    #pragma unroll
    for (int es = 0; es < 2; ++es)
        #pragma unroll
        for (int w4 = 0; w4 < 4; ++w4)
            #pragma unroll
            for (int r = 0; r < 4; ++r)
                afr[es][w4].u[r] = wtp[wid*2 + es][lg*4 + r][w4*16 + lm];
    f32x4 yacc = {0.f, 0.f, 0.f, 0.f};
    for (int dhalf = 0; dhalf < 2; ++dhalf) {
        #pragma unroll
        for (int es = 0; es < 2; ++es) {
            const int e = wid*2 + es;
            #pragma unroll
            for (int dt = 0; dt < 2; ++dt) {
                const int d = dhalf*32 + dt*16 + lm;
                const float* fb = feat + (size_t)(b*64 + d) * NPTS;
                frag_u B;
                #pragma unroll
                for (int r = 0; r < 4; ++r) {
                    const int k0 = lg*8 + 2*r;
                    B.u[r] = pack_bf16pair(fb[idxs[e][k0]], fb[idxs[e][k0+1]]);
                }
                #pragma unroll
                for (int w4 = 0; w4 < 4; ++w4) {
                    f32x4 dnf = {0.f, 0.f, 0.f, 0.f};
                    dnf = __builtin_amdgcn_mfma_f32_16x16x32_bf16(afr[es][w4].h, B.h, dnf, 0, 0, 0);
                    const unsigned p0 = pack_bf16pair(dnf[0], dnf[1]);
                    const unsigned p1 = pack_bf16pair(dnf[2], dnf[3]);
                    const int dloc = dt*16 + lm;
                    const int kp0 = dloc*32 + w4*8 + lg*2;
                    const int sw = kp0 ^ ((lm & 3) << 3) ^ ((e & 7) << 2);
                    *(uint2*)&yaf[e*1024 + sw] = make_uint2(p0, p1);
                }
            }
        }
        __syncthreads();
        for (int kt = 0; kt < 64; ++kt) {
            frag_u A, Bf;
            const int kpb = (kt*16 + lg*4) ^ (((kt >> 1) & 3) << 3) ^ ((lm & 7) << 2);
            A.u4 = *(const uint4*)&yaf[(lm & 7)*1024 + kpb];
            Bf.u4 = *(const uint4*)&wfb[(((size_t)(dhalf*64 + kt)*4 + wid)*64 + lane)*4];
            yacc = __builtin_amdgcn_mfma_f32_16x16x32_bf16(A.h, Bf.h, yacc, 0, 0, 0);
        }
        __syncthreads();
    }
    if (lg < 2) {
        const float bfo = bf[wid*16 + lm];
        #pragma unroll
        for (int r = 0; r < 4; ++r)
            y[(size_t)(bs0 + lg*4 + r) * 64 + wid*16 + lm] = yacc[r] + bfo;
    }
}

__global__ __launch_bounds__(256) void ystats_kernel(const float* __restrict__ y,
                                                     double* __restrict__ st)
{
    const int tid = threadIdx.x;
    const int c = tid & 63;
    double s = 0.0, s2 = 0.0;
    for (int i = blockIdx.x * 256 + tid; i < NBATCH*NSAMP*64; i += gridDim.x * 256) {
        const float v = y[i];
        s += v; s2 += (double)v * (double)v;
    }
    __shared__ double rs[256], rs2[256];
    rs[tid] = s; rs2[tid] = s2;
    __syncthreads();
    if (tid < 64) {
        const double a  = rs[c]  + rs[64+c]  + rs[128+c]  + rs[192+c];
        const double a2 = rs2[c] + rs2[64+c] + rs2[128+c] + rs2[192+c];
        atomicAdd(&st[c], a);
        atomicAdd(&st[64 + c], a2);
    }
}

__global__ void writeout_kernel(const float* __restrict__ y,
                                const float* __restrict__ bnp3,
                                float* __restrict__ outp)
{
    const int i = blockIdx.x * 256 + threadIdx.x;
    if (i >= NBATCH * 64 * NSAMP) return;
    const int s = i & 1023;
    const int o = (i >> 10) & 63;
    const int bb = i >> 16;
    const float v = y[((size_t)(bb << 10) + s) * 64 + o];
    outp[i] = fmaxf(bnp3[o] * v + bnp3[64 + o], 0.f);
}

// ============================ launch ============================
extern "C" void kernel_launch(void* const* d_in, const int* in_sizes, int n_in,
                              void* d_out, int out_size, void* d_ws, size_t ws_size,
                              hipStream_t stream)
{
    (void)in_sizes; (void)n_in; (void)out_size; (void)ws_size;
    const float* xyz  = (const float*)d_in[0];
    const float* feat = (const float*)d_in[1];
    const float* w0   = (const float*)d_in[2];
    const float* b0   = (const float*)d_in[3];
    const float* g0   = (const float*)d_in[4];
    const float* be0  = (const float*)d_in[5];
    const float* w1   = (const float*)d_in[6];
    const float* b1   = (const float*)d_in[7];
    const float* g1   = (const float*)d_in[8];
    const float* be1  = (const float*)d_in[9];
    const float* w2   = (const float*)d_in[10];
    const float* b2   = (const float*)d_in[11];
    const float* g2   = (const float*)d_in[12];
    const float* be2  = (const float*)d_in[13];
    const float* wf   = (const float*)d_in[14];
    const float* bf   = (const float*)d_in[15];
    const float* gf   = (const float*)d_in[16];
    const float* bef  = (const float*)d_in[17];

    float* out = (float*)d_out;
    float* newxyz = out;                       // (B, S, 3)
    float* outmain = out + NBATCH * NSAMP * 3; // (B, 64, S)

    char* ws = (char*)d_ws;
    int*      idxws = (int*)ws;                            // 2 MB
    float*    ybuf  = (float*)(ws + 2097152);              // 4 MB
    double*   stats = (double*)(ws + 6291456);             // 4 KB (512 f64)
    float*    bnp   = (float*)(ws + 6295552);              // 2 KB
    unsigned* wfb   = (unsigned*)(ws + 6297600);           // 512 KB
    unsigned* w1b   = (unsigned*)(ws + 6821888);           // 8 KB
    unsigned* w2b   = (unsigned*)(ws + 6830080);           // 8 KB
    float*    G1    = (float*)(ws + 6838272);              // 16 KB
    float*    G2    = (float*)(ws + 6854656);              // 16 KB

    zero_all_kernel<<<16, 256, 0, stream>>>(stats, G1, G2);
    wfpack_kernel<<<512, 64, 0, stream>>>(wf, wfb);
    wfpack_kernel<<<8, 64, 0, stream>>>(w1, w1b);
    wfpack_kernel<<<8, 64, 0, stream>>>(w2, w2b);
    fps_kernel<<<NBATCH, 256, 0, stream>>>(xyz, newxyz);
    knn_kernel<<<NBATCH * NSAMP, 256, 0, stream>>>(xyz, newxyz, idxws);

    gxmoments_kernel<<<512, 256, 0, stream>>>(xyz, newxyz, idxws, stats);
    bn0_moments_finalize_kernel<<<1, 64, 0, stream>>>(stats, w0, b0, g0, be0, bnp);
    gram1_kernel<<<256, 256, 0, stream>>>(xyz, newxyz, idxws, w0, b0, bnp, G1, stats + 128);
    bn_gram_finalize_kernel<<<1, 256, 0, stream>>>(stats + 128, G1, w1, b1, g1, be1, bnp + 128);
    gram2_kernel<<<256, 256, 0, stream>>>(xyz, newxyz, idxws, w0, b0, b1, w1b, bnp, G2, stats + 192);
    bn_gram_finalize_kernel<<<1, 256, 0, stream>>>(stats + 192, G2, w2, b2, g2, be2, bnp + 256);

    final_conv_kernel<<<NBATCH * NSAMP / 8, 256, 0, stream>>>(
        xyz, newxyz, idxws, feat, w0, b0, b1, b2, bnp, wfb, w1b, w2b, bf, ybuf);

    ystats_kernel<<<256, 256, 0, stream>>>(ybuf, stats + 384);
    bn_finalize_kernel<<<1, 64, 0, stream>>>(stats + 384, gf, bef, bnp + 384, (float)(NBATCH * NSAMP));
    writeout_kernel<<<4096, 256, 0, stream>>>(ybuf, bnp + 384, outmain);
}

// Round 8
// 1594.385 us; speedup vs baseline: 3.0385x; 1.0493x over previous
//
#include <hip/hip_runtime.h>

#define NBATCH 16
#define NPTS   4096
#define NSAMP  1024
#define NKNN   32
#define NROWS  (NBATCH*NSAMP*NKNN)   // 524288
#define BN_EPS 1e-5f
#define H1PAD  66

typedef __attribute__((ext_vector_type(4))) float f32x4;
typedef __attribute__((ext_vector_type(8))) short bf16x8;
union frag_u { unsigned u[4]; bf16x8 h; uint4 u4; };

__device__ __forceinline__ unsigned pack_bf16pair(float a, float b) {
    unsigned ua = __float_as_uint(a); ua += 0x7FFFu + ((ua >> 16) & 1u);
    unsigned ub = __float_as_uint(b); ub += 0x7FFFu + ((ub >> 16) & 1u);
    return (ua >> 16) | (ub & 0xFFFF0000u);
}

// ============================ FPS v4 ============================
// 512 thr/block, 1 block/batch, 8 pts/thread contiguous. Wave max via 6-step
// DPP reduce (row_shr 1/2/4/8 + row_bcast 15/31; all values >=0 so
// bound_ctrl-0 fill is safe); index via ballot+ffs+readlane (tie -> lowest
// lane = lowest index). One barrier/iter, parity-buffered 8-slot cross-wave
// reduce. Distance arithmetic bit-identical to rounds 1-7.
__global__ __launch_bounds__(512) void fps_kernel(const float* __restrict__ xyz,
                                                  float* __restrict__ newxyz)
{
    const int b = blockIdx.x;
    const int tid = threadIdx.x;
    const int wv = tid >> 6;          // 0..7
    const float* xb = xyz + (size_t)b * NPTS * 3;
    __shared__ float xs[NPTS];
    __shared__ float ys[NPTS];
    __shared__ float zs[NPTS];
    __shared__ __align__(16) float red_v[2][8];
    __shared__ __align__(16) int   red_i[2][8];
    float px[8], py[8], pz[8], dmin[8];
    {
        float arr[24];
        const float4* s4 = (const float4*)(xb + (size_t)tid * 24);
        #pragma unroll
        for (int i = 0; i < 6; ++i) *(float4*)&arr[i*4] = s4[i];
        #pragma unroll
        for (int j = 0; j < 8; ++j) {
            px[j] = arr[3*j]; py[j] = arr[3*j+1]; pz[j] = arr[3*j+2];
            const int p = tid * 8 + j;
            xs[p] = px[j]; ys[p] = py[j]; zs[p] = pz[j];
            dmin[j] = 1e10f;
        }
    }
    if (tid == 0) {
        float* o = newxyz + (size_t)b * NSAMP * 3;
        o[0] = xb[0]; o[1] = xb[1]; o[2] = xb[2];
    }
    __syncthreads();
    float lx = xs[0], ly = ys[0], lz = zs[0];
    for (int t = 1; t < NSAMP; ++t) {
        float bv = -1.0f;
        #pragma unroll
        for (int j = 0; j < 8; ++j) {
            const float dx = __fsub_rn(px[j], lx);
            const float dy = __fsub_rn(py[j], ly);
            const float dz = __fsub_rn(pz[j], lz);
            const float d = __fadd_rn(__fadd_rn(__fmul_rn(dx,dx), __fmul_rn(dy,dy)), __fmul_rn(dz,dz));
            const float nd = fminf(dmin[j], d);
            dmin[j] = nd;
            bv = fmaxf(bv, nd);
        }
        int lj = 0;
        #pragma unroll
        for (int j = 7; j >= 0; --j) if (dmin[j] == bv) lj = j;
        const int bi_lane = tid * 8 + lj;
        // ---- wave max via DPP (dest lane 63), then broadcast ----
        float mv = bv;
        {
            int s_;
            s_ = __builtin_amdgcn_mov_dpp(__float_as_int(mv), 0x111, 0xf, 0xf, true); // row_shr:1
            mv = fmaxf(mv, __int_as_float(s_));
            s_ = __builtin_amdgcn_mov_dpp(__float_as_int(mv), 0x112, 0xf, 0xf, true); // row_shr:2
            mv = fmaxf(mv, __int_as_float(s_));
            s_ = __builtin_amdgcn_mov_dpp(__float_as_int(mv), 0x114, 0xf, 0xf, true); // row_shr:4
            mv = fmaxf(mv, __int_as_float(s_));
            s_ = __builtin_amdgcn_mov_dpp(__float_as_int(mv), 0x118, 0xf, 0xf, true); // row_shr:8
            mv = fmaxf(mv, __int_as_float(s_));
            s_ = __builtin_amdgcn_mov_dpp(__float_as_int(mv), 0x142, 0xf, 0xf, true); // row_bcast:15
            mv = fmaxf(mv, __int_as_float(s_));
            s_ = __builtin_amdgcn_mov_dpp(__float_as_int(mv), 0x143, 0xf, 0xf, true); // row_bcast:31
            mv = fmaxf(mv, __int_as_float(s_));
        }
        mv = __int_as_float(__builtin_amdgcn_readlane(__float_as_int(mv), 63));
        const unsigned long long mask = __ballot(bv == mv);
        const int winner = __ffsll(mask) - 1;
        const int bi_w = __builtin_amdgcn_readlane(bi_lane, winner);
        const int par = t & 1;
        if ((tid & 63) == 0) { red_v[par][wv] = mv; red_i[par][wv] = bi_w; }
        __syncthreads();
        // ---- cross-wave: 8 slots, ascending strict '>' (lowest wave wins) ----
        const float4 rv0 = *(const float4*)&red_v[par][0];
        const float4 rv1 = *(const float4*)&red_v[par][4];
        const int4   ri0 = *(const int4*)&red_i[par][0];
        const int4   ri1 = *(const int4*)&red_i[par][4];
        float fv = rv0.x; int bi = ri0.x;
        if (rv0.y > fv) { fv = rv0.y; bi = ri0.y; }
        if (rv0.z > fv) { fv = rv0.z; bi = ri0.z; }
        if (rv0.w > fv) { fv = rv0.w; bi = ri0.w; }
        if (rv1.x > fv) { fv = rv1.x; bi = ri1.x; }
        if (rv1.y > fv) { fv = rv1.y; bi = ri1.y; }
        if (rv1.z > fv) { fv = rv1.z; bi = ri1.z; }
        if (rv1.w > fv) { fv = rv1.w; bi = ri1.w; }
        lx = xs[bi]; ly = ys[bi]; lz = zs[bi];
        if (tid == 0) {
            float* o = newxyz + ((size_t)b * NSAMP + t) * 3;
            o[0] = lx; o[1] = ly; o[2] = lz;
        }
    }
}

// ============================ kNN ============================
// (validated rounds 2-7)
__global__ __launch_bounds__(256) void knn_kernel(const float* __restrict__ xyz,
                                                  const float* __restrict__ newxyz,
                                                  int* __restrict__ idx_out)
{
    const int bs = blockIdx.x;
    const int b = bs >> 10;
    const int tid = threadIdx.x;
    __shared__ unsigned keys[NPTS];
    __shared__ int hist[256];
    __shared__ float qsh[3];
    __shared__ int ctrl[4];
    __shared__ int ties[128];
    if (tid < 3) qsh[tid] = newxyz[bs*3 + tid];
    if (tid == 0) { ctrl[0] = 0; ctrl[1] = NKNN; }
    __syncthreads();
    const float q0 = qsh[0], q1 = qsh[1], q2 = qsh[2];
    const float qq = __fadd_rn(__fadd_rn(__fmul_rn(q0,q0), __fmul_rn(q1,q1)), __fmul_rn(q2,q2));
    const float* xb = xyz + (size_t)b * NPTS * 3;
    for (int n = tid; n < NPTS; n += 256) {
        const float x0 = xb[n*3+0], x1 = xb[n*3+1], x2 = xb[n*3+2];
        const float xx = __fadd_rn(__fadd_rn(__fmul_rn(x0,x0), __fmul_rn(x1,x1)), __fmul_rn(x2,x2));
        float dt = __fmul_rn(q0, x0);
        dt = __fmaf_rn(q1, x1, dt);
        dt = __fmaf_rn(q2, x2, dt);
        const float dd = __fadd_rn(__fsub_rn(qq, __fmul_rn(2.0f, dt)), xx);
        unsigned ub = __float_as_uint(dd);
        ub = (ub & 0x80000000u) ? ~ub : (ub | 0x80000000u);
        keys[n] = ub;
    }
    for (int p = 3; p >= 0; --p) {
        __syncthreads();
        hist[tid] = 0;
        __syncthreads();
        const unsigned pre = (unsigned)ctrl[0];
        const int shift = p * 8;
        const unsigned himask = (p == 3) ? 0u : (0xFFFFFFFFu << ((p + 1) * 8));
        for (int n = tid; n < NPTS; n += 256) {
            const unsigned k = keys[n];
            if ((k & himask) == pre) atomicAdd(&hist[(k >> shift) & 255], 1);
        }
        __syncthreads();
        if (tid == 0) {
            int r = ctrl[1]; unsigned pf = (unsigned)ctrl[0];
            for (int bin = 0; bin < 256; ++bin) {
                const int cnt = hist[bin];
                if (r > cnt) r -= cnt;
                else { pf |= ((unsigned)bin) << shift; break; }
            }
            ctrl[0] = (int)pf; ctrl[1] = r;
        }
    }
    __syncthreads();
    const unsigned T = (unsigned)ctrl[0];
    if (tid == 0) { ctrl[2] = 0; ctrl[3] = 0; }
    __syncthreads();
    int* out = idx_out + (size_t)bs * NKNN;
    for (int n = tid; n < NPTS; n += 256) {
        const unsigned k = keys[n];
        if (k < T) {
            const int pos = atomicAdd(&ctrl[2], 1);
            if (pos < NKNN) out[pos] = n;
        } else if (k == T) {
            const int pos = atomicAdd(&ctrl[3], 1);
            if (pos < 128) ties[pos] = n;
        }
    }
    __syncthreads();
    if (tid == 0) {
        const int nless = ctrl[2] < NKNN ? ctrl[2] : NKNN;
        const int need = NKNN - nless;
        const int ntie = ctrl[3] < 128 ? ctrl[3] : 128;
        int last = -1;
        for (int j = 0; j < need; ++j) {
            int best = 0x7fffffff;
            for (int i = 0; i < ntie; ++i) {
                const int v = ties[i];
                if (v > last && v < best) best = v;
            }
            out[nless + j] = (best == 0x7fffffff) ? 0 : best;
            last = best;
        }
    }
}

// ============================ zero / moments ============================
__global__ void zero_all_kernel(double* st, float* g1, float* g2)
{
    const int i = blockIdx.x * 256 + threadIdx.x;
    if (i < 512) st[i] = 0.0;
    if (i < 4096) { g1[i] = 0.f; g2[i] = 0.f; }
}

__global__ __launch_bounds__(256) void gxmoments_kernel(
    const float* __restrict__ xyz, const float* __restrict__ newxyz,
    const int* __restrict__ idxws, double* __restrict__ stats)
{
    const int tid = threadIdx.x;
    double m[9];
    #pragma unroll
    for (int i = 0; i < 9; ++i) m[i] = 0.0;
    for (int row = blockIdx.x * 256 + tid; row < NROWS; row += gridDim.x * 256) {
        const int bs = row >> 5;
        const int bb = row >> 15;
        const int id = idxws[row];
        const float* xp = xyz + ((size_t)bb * NPTS + id) * 3;
        const float* qp = newxyz + bs * 3;
        const double dx = (double)(xp[0] - qp[0]);
        const double dy = (double)(xp[1] - qp[1]);
        const double dz = (double)(xp[2] - qp[2]);
        m[0] += dx; m[1] += dy; m[2] += dz;
        m[3] += dx*dx; m[4] += dx*dy; m[5] += dx*dz;
        m[6] += dy*dy; m[7] += dy*dz; m[8] += dz*dz;
    }
    #pragma unroll
    for (int i = 0; i < 9; ++i) {
        #pragma unroll
        for (int s = 1; s < 64; s <<= 1) m[i] += __shfl_xor(m[i], s);
    }
    __shared__ double part[4][9];
    if ((tid & 63) == 0) {
        #pragma unroll
        for (int i = 0; i < 9; ++i) part[tid >> 6][i] = m[i];
    }
    __syncthreads();
    if (tid < 9) atomicAdd(&stats[tid], part[0][tid] + part[1][tid] + part[2][tid] + part[3][tid]);
}

__global__ void bn0_moments_finalize_kernel(const double* __restrict__ st,
    const float* __restrict__ w0, const float* __restrict__ b0,
    const float* __restrict__ g0, const float* __restrict__ be0,
    float* __restrict__ outp)
{
    const int c = threadIdx.x;  // 64
    const double N = (double)NROWS;
    const double w0c = w0[c], w1c = w0[64 + c], w2c = w0[128 + c];
    const double b = b0[c];
    const double dotS = st[0]*w0c + st[1]*w1c + st[2]*w2c;
    const double qf = w0c*w0c*st[3] + w1c*w1c*st[6] + w2c*w2c*st[8]
                    + 2.0*(w0c*w1c*st[4] + w0c*w2c*st[5] + w1c*w2c*st[7]);
    const double mean = dotS / N + b;
    const double ex2 = (qf + 2.0*b*dotS) / N + b*b;
    const double var = ex2 - mean*mean;
    const float scale = g0[c] * rsqrtf((float)var + BN_EPS);
    outp[c] = scale;
    outp[64 + c] = be0[c] - (float)mean * scale;
}

// ============================ weight pre-pack ============================
__global__ void wfpack_kernel(const float* __restrict__ wf, unsigned* __restrict__ wfb)
{
    const int blk = blockIdx.x;
    const int kt = blk >> 2, ot = blk & 3;
    const int l = threadIdx.x;            // 64
    const int o = ot*16 + (l & 15);
    const int kb = kt*32 + (l >> 4)*8;
    unsigned out[4];
    #pragma unroll
    for (int r = 0; r < 4; ++r) {
        const float a = wf[(size_t)(kb + 2*r) * 64 + o];
        const float b = wf[(size_t)(kb + 2*r + 1) * 64 + o];
        out[r] = pack_bf16pair(a, b);
    }
    *(uint4*)&wfb[((size_t)blk * 64 + l) * 4] = *(const uint4*)out;
}

// ============================ Gram stats ============================
__global__ __launch_bounds__(256) void gram1_kernel(
    const float* __restrict__ xyz, const float* __restrict__ newxyz,
    const int* __restrict__ idxws,
    const float* __restrict__ w0, const float* __restrict__ b0,
    const float* __restrict__ bnp, float* __restrict__ G1,
    double* __restrict__ Sh1)
{
    __shared__ float gxs[32][3];
    __shared__ float h1s[32][H1PAD];
    __shared__ float rsum[256];
    const int tid = threadIdx.x;
    const int c = tid & 63;
    const int rq = tid >> 6;
    const int lg = c >> 4, lm = c & 15;
    const float w0c0 = w0[c], w0c1 = w0[64+c], w0c2 = w0[128+c];
    const float b0c = b0[c], sc0 = bnp[c], sh0 = bnp[64+c];
    f32x4 Ga[4] = {{0,0,0,0},{0,0,0,0},{0,0,0,0},{0,0,0,0}};
    float sumh = 0.f;
    for (int chunk = blockIdx.x; chunk < NROWS/32; chunk += gridDim.x) {
        if (tid < 96) {
            const int slot = tid / 3, cc = tid % 3;
            const int row = chunk*32 + slot;
            const int bs = row >> 5, bb = row >> 15;
            gxs[slot][cc] = xyz[((size_t)bb * NPTS + idxws[row]) * 3 + cc] - newxyz[bs*3 + cc];
        }
        __syncthreads();
        #pragma unroll
        for (int i = 0; i < 8; ++i) {
            const int r = rq*8 + i;
            const float t0 = gxs[r][0]*w0c0 + gxs[r][1]*w0c1 + gxs[r][2]*w0c2 + b0c;
            const float h = fmaxf(sc0*t0 + sh0, 0.f);
            h1s[r][c] = h;
            sumh += h;
        }
        __syncthreads();
        frag_u fr[4];
        #pragma unroll
        for (int ct = 0; ct < 4; ++ct)
            #pragma unroll
            for (int r = 0; r < 4; ++r)
                fr[ct].u[r] = pack_bf16pair(h1s[lg*8 + 2*r][ct*16 + lm],
                                            h1s[lg*8 + 2*r + 1][ct*16 + lm]);
        #pragma unroll
        for (int ct = 0; ct < 4; ++ct)
            Ga[ct] = __builtin_amdgcn_mfma_f32_16x16x32_bf16(fr[rq].h, fr[ct].h, Ga[ct], 0, 0, 0);
        __syncthreads();
    }
    #pragma unroll
    for (int ct = 0; ct < 4; ++ct)
        #pragma unroll
        for (int r = 0; r < 4; ++r)
            atomicAdd(&G1[(rq*16 + lg*4 + r)*64 + ct*16 + lm], Ga[ct][r]);
    rsum[tid] = sumh;
    __syncthreads();
    if (tid < 64) atomicAdd(&Sh1[c], (double)(rsum[c] + rsum[64+c] + rsum[128+c] + rsum[192+c]));
}

__global__ __launch_bounds__(256) void gram2_kernel(
    const float* __restrict__ xyz, const float* __restrict__ newxyz,
    const int* __restrict__ idxws,
    const float* __restrict__ w0, const float* __restrict__ b0,
    const float* __restrict__ b1, const unsigned* __restrict__ w1b,
    const float* __restrict__ bnp, float* __restrict__ G2,
    double* __restrict__ Sh2)
{
    __shared__ float gxs[32][3];
    __shared__ float h1s[32][H1PAD];
    __shared__ float h2s[32][H1PAD];
    __shared__ float rsum[256];
    const int tid = threadIdx.x;
    const int c = tid & 63;
    const int rq = tid >> 6;
    const int lg = c >> 4, lm = c & 15;
    const int c2 = rq*16 + lm;
    const float w0c0 = w0[c], w0c1 = w0[64+c], w0c2 = w0[128+c];
    const float b0c = b0[c], sc0 = bnp[c], sh0 = bnp[64+c];
    const float b1c2 = b1[c2], sc1 = bnp[128+c2], sh1 = bnp[192+c2];
    frag_u Bw1[2];
    Bw1[0].u4 = *(const uint4*)&w1b[((0*4 + rq)*64 + c)*4];
    Bw1[1].u4 = *(const uint4*)&w1b[((1*4 + rq)*64 + c)*4];
    f32x4 Ga[4] = {{0,0,0,0},{0,0,0,0},{0,0,0,0},{0,0,0,0}};
    float sumh = 0.f;
    for (int chunk = blockIdx.x; chunk < NROWS/32; chunk += gridDim.x) {
        if (tid < 96) {
            const int slot = tid / 3, cc = tid % 3;
            const int row = chunk*32 + slot;
            const int bs = row >> 5, bb = row >> 15;
            gxs[slot][cc] = xyz[((size_t)bb * NPTS + idxws[row]) * 3 + cc] - newxyz[bs*3 + cc];
        }
        __syncthreads();
        #pragma unroll
        for (int i = 0; i < 8; ++i) {
            const int r = rq*8 + i;
            const float t0 = gxs[r][0]*w0c0 + gxs[r][1]*w0c1 + gxs[r][2]*w0c2 + b0c;
            h1s[r][c] = fmaxf(sc0*t0 + sh0, 0.f);
        }
        __syncthreads();
        #pragma unroll
        for (int mt = 0; mt < 2; ++mt) {
            f32x4 acc = {0,0,0,0};
            #pragma unroll
            for (int kt = 0; kt < 2; ++kt) {
                frag_u a;
                #pragma unroll
                for (int r = 0; r < 4; ++r) {
                    const float2 f = *(const float2*)&h1s[mt*16 + lm][kt*32 + lg*8 + 2*r];
                    a.u[r] = pack_bf16pair(f.x, f.y);
                }
                acc = __builtin_amdgcn_mfma_f32_16x16x32_bf16(a.h, Bw1[kt].h, acc, 0, 0, 0);
            }
            #pragma unroll
            for (int r = 0; r < 4; ++r)
                h2s[mt*16 + lg*4 + r][c2] = fmaxf(sc1*(acc[r] + b1c2) + sh1, 0.f);
        }
        __syncthreads();
        #pragma unroll
        for (int i = 0; i < 8; ++i) sumh += h2s[rq*8 + i][c];
        frag_u fr[4];
        #pragma unroll
        for (int ct = 0; ct < 4; ++ct)
            #pragma unroll
            for (int r = 0; r < 4; ++r)
                fr[ct].u[r] = pack_bf16pair(h2s[lg*8 + 2*r][ct*16 + lm],
                                            h2s[lg*8 + 2*r + 1][ct*16 + lm]);
        #pragma unroll
        for (int ct = 0; ct < 4; ++ct)
            Ga[ct] = __builtin_amdgcn_mfma_f32_16x16x32_bf16(fr[rq].h, fr[ct].h, Ga[ct], 0, 0, 0);
        __syncthreads();
    }
    #pragma unroll
    for (int ct = 0; ct < 4; ++ct)
        #pragma unroll
        for (int r = 0; r < 4; ++r)
            atomicAdd(&G2[(rq*16 + lg*4 + r)*64 + ct*16 + lm], Ga[ct][r]);
    rsum[tid] = sumh;
    __syncthreads();
    if (tid < 64) atomicAdd(&Sh2[c], (double)(rsum[c] + rsum[64+c] + rsum[128+c] + rsum[192+c]));
}

__global__ __launch_bounds__(256) void bn_gram_finalize_kernel(
    const double* __restrict__ Sh, const float* __restrict__ G,
    const float* __restrict__ w, const float* __restrict__ bias,
    const float* __restrict__ g, const float* __restrict__ be,
    float* __restrict__ outp)
{
    __shared__ float wls[64][65];
    __shared__ double shl[64];
    __shared__ double rd[256], rqd[256];
    const int tid = threadIdx.x;
    const int c = tid & 63;
    const int rqi = tid >> 6;
    for (int i = tid; i < 4096; i += 256) wls[i >> 6][i & 63] = w[i];
    if (tid < 64) shl[tid] = Sh[tid];
    __syncthreads();
    double dot = 0.0, quad = 0.0;
    for (int j = rqi*16; j < rqi*16 + 16; ++j) {
        const double wjc = (double)wls[j][c];
        dot += wjc * shl[j];
        double inner = 0.0;
        for (int k = 0; k < 64; ++k) inner += (double)G[j*64 + k] * (double)wls[k][c];
        quad += wjc * inner;
    }
    rd[tid] = dot; rqd[tid] = quad;
    __syncthreads();
    if (tid < 64) {
        const double d = rd[c] + rd[64+c] + rd[128+c] + rd[192+c];
        const double q = rqd[c] + rqd[64+c] + rqd[128+c] + rqd[192+c];
        const double N = (double)NROWS;
        const double bc = (double)bias[c];
        const double mean = d / N + bc;
        const double ex2 = (q + 2.0*bc*d) / N + bc*bc;
        const double var = ex2 - mean*mean;
        const float scale = g[c] * rsqrtf((float)var + BN_EPS);
        outp[c] = scale;
        outp[64 + c] = be[c] - (float)mean * scale;
    }
}

__global__ void bn_finalize_kernel(const double* __restrict__ st,
                                   const float* __restrict__ g,
                                   const float* __restrict__ be,
                                   float* __restrict__ outp, float n)
{
    const int c = threadIdx.x;  // 64
    const double m = st[c] / (double)n;
    const double var = st[64 + c] / (double)n - m * m;
    const float scale = g[c] * rsqrtf((float)var + BN_EPS);
    outp[c] = scale;
    outp[64 + c] = be[c] - (float)m * scale;
}

// ============================ final fused conv ============================
__global__ __launch_bounds__(256) void final_conv_kernel(
    const float* __restrict__ xyz, const float* __restrict__ newxyz,
    const int* __restrict__ idxws, const float* __restrict__ feat,
    const float* __restrict__ w0, const float* __restrict__ b0,
    const float* __restrict__ b1, const float* __restrict__ b2,
    const float* __restrict__ bnp, const unsigned* __restrict__ wfb,
    const unsigned* __restrict__ w1b, const unsigned* __restrict__ w2b,
    const float* __restrict__ bf, float* __restrict__ y)
{
    __shared__ unsigned wtp[8][16][64];
    __shared__ __align__(16) float scratch[2*64*H1PAD];
    __shared__ float gxs[64][3];
    __shared__ int   idxs[8][32];
    __shared__ float qs[8][3];
    float* h1s = scratch;
    float* h2s = scratch + 64*H1PAD;
    unsigned* yaf = (unsigned*)scratch;
    const int tid = threadIdx.x;
    const int c = tid & 63;
    const int rq = tid >> 6;
    const int lg = c >> 4, lm = c & 15;
    const int c2 = rq*16 + lm;
    const int bs0 = blockIdx.x * 8;
    const int b = bs0 >> 10;
    idxs[tid >> 5][tid & 31] = idxws[(size_t)bs0 * NKNN + tid];
    if (tid < 24)  qs[tid / 3][tid % 3] = newxyz[(bs0 + tid/3)*3 + (tid % 3)];
    const float w0c0 = w0[c], w0c1 = w0[64+c], w0c2 = w0[128+c];
    const float b0c = b0[c], sc0 = bnp[c], sh0 = bnp[64+c];
    const float b1c2 = b1[c2], sc1 = bnp[128+c2], sh1 = bnp[192+c2];
    const float b2c2 = b2[c2], sc2 = bnp[256+c2], sh2 = bnp[320+c2];
    frag_u Bw1[2], Bw2[2];
    #pragma unroll
    for (int kt = 0; kt < 2; ++kt) {
        Bw1[kt].u4 = *(const uint4*)&w1b[((kt*4 + rq)*64 + c)*4];
        Bw2[kt].u4 = *(const uint4*)&w2b[((kt*4 + rq)*64 + c)*4];
    }
    __syncthreads();
    for (int chunk = 0; chunk < 4; ++chunk) {
        if (tid < 192) {
            const int slot = tid / 3, cc = tid % 3;
            const int grow = chunk*64 + slot;
            const int e = grow >> 5, k = grow & 31;
            gxs[slot][cc] = xyz[((size_t)b * NPTS + idxs[e][k]) * 3 + cc] - qs[e][cc];
        }
        __syncthreads();
        #pragma unroll
        for (int i = 0; i < 16; ++i) {
            const int r = rq*16 + i;
            const float t0 = gxs[r][0]*w0c0 + gxs[r][1]*w0c1 + gxs[r][2]*w0c2 + b0c;
            h1s[r*H1PAD + c] = fmaxf(sc0*t0 + sh0, 0.f);
        }
        __syncthreads();
        #pragma unroll
        for (int mt = 0; mt < 4; ++mt) {
            f32x4 acc = {0,0,0,0};
            #pragma unroll
            for (int kt = 0; kt < 2; ++kt) {
                frag_u a;
                #pragma unroll
                for (int r = 0; r < 4; ++r) {
                    const float2 f = *(const float2*)&h1s[(mt*16 + lm)*H1PAD + kt*32 + lg*8 + 2*r];
                    a.u[r] = pack_bf16pair(f.x, f.y);
                }
                acc = __builtin_amdgcn_mfma_f32_16x16x32_bf16(a.h, Bw1[kt].h, acc, 0, 0, 0);
            }
            #pragma unroll
            for (int r = 0; r < 4; ++r)
                h2s[(mt*16 + lg*4 + r)*H1PAD + c2] = fmaxf(sc1*(acc[r] + b1c2) + sh1, 0.f);
        }
        __syncthreads();
        #pragma unroll
        for (int mt = 0; mt < 4; ++mt) {
            f32x4 acc = {0,0,0,0};
            #pragma unroll
            for (int kt = 0; kt < 2; ++kt) {
                frag_u a;
                #pragma unroll
                for (int r = 0; r < 4; ++r) {
                    const float2 f = *(const float2*)&h2s[(mt*16 + lm)*H1PAD + kt*32 + lg*8 + 2*r];
                    a.u[r] = pack_bf16pair(f.x, f.y);
                }
                acc = __builtin_amdgcn_mfma_f32_16x16x32_bf16(a.h, Bw2[kt].h, acc, 0, 0, 0);
            }
            float wt[4];
            #pragma unroll
            for (int r = 0; r < 4; ++r)
                wt[r] = fmaxf(sc2*(acc[r] + b2c2) + sh2, 0.f);
            const int grow0 = chunk*64 + mt*16 + lg*4;
            const int e = grow0 >> 5, kl = grow0 & 31;
            wtp[e][kl >> 1][c2]       = pack_bf16pair(wt[0], wt[1]);
            wtp[e][(kl >> 1) + 1][c2] = pack_bf16pair(wt[2], wt[3]);
        }
        __syncthreads();
    }
    const int lane = c;
    const int wid = rq;
    frag_u afr[2][4];
    #pragma unroll
    for (int es = 0; es < 2; ++es)
        #pragma unroll
        for (int w4 = 0; w4 < 4; ++w4)
            #pragma unroll
            for (int r = 0; r < 4; ++r)
                afr[es][w4].u[r] = wtp[wid*2 + es][lg*4 + r][w4*16 + lm];
    f32x4 yacc = {0.f, 0.f, 0.f, 0.f};
    for (int dhalf = 0; dhalf < 2; ++dhalf) {
        #pragma unroll
        for (int es = 0; es < 2; ++es) {
            const int e = wid*2 + es;
            #pragma unroll
            for (int dt = 0; dt < 2; ++dt) {
                const int d = dhalf*32 + dt*16 + lm;
                const float* fb = feat + (size_t)(b*64 + d) * NPTS;
                frag_u B;
                #pragma unroll
                for (int r = 0; r < 4; ++r) {
                    const int k0 = lg*8 + 2*r;
                    B.u[r] = pack_bf16pair(fb[idxs[e][k0]], fb[idxs[e][k0+1]]);
                }
                #pragma unroll
                for (int w4 = 0; w4 < 4; ++w4) {
                    f32x4 dnf = {0.f, 0.f, 0.f, 0.f};
                    dnf = __builtin_amdgcn_mfma_f32_16x16x32_bf16(afr[es][w4].h, B.h, dnf, 0, 0, 0);
                    const unsigned p0 = pack_bf16pair(dnf[0], dnf[1]);
                    const unsigned p1 = pack_bf16pair(dnf[2], dnf[3]);
                    const int dloc = dt*16 + lm;
                    const int kp0 = dloc*32 + w4*8 + lg*2;
                    const int sw = kp0 ^ ((lm & 3) << 3) ^ ((e & 7) << 2);
                    *(uint2*)&yaf[e*1024 + sw] = make_uint2(p0, p1);
                }
            }
        }
        __syncthreads();
        for (int kt = 0; kt < 64; ++kt) {
            frag_u A, Bf;
            const int kpb = (kt*16 + lg*4) ^ (((kt >> 1) & 3) << 3) ^ ((lm & 7) << 2);
            A.u4 = *(const uint4*)&yaf[(lm & 7)*1024 + kpb];
            Bf.u4 = *(const uint4*)&wfb[(((size_t)(dhalf*64 + kt)*4 + wid)*64 + lane)*4];
            yacc = __builtin_amdgcn_mfma_f32_16x16x32_bf16(A.h, Bf.h, yacc, 0, 0, 0);
        }
        __syncthreads();
    }
    if (lg < 2) {
        const float bfo = bf[wid*16 + lm];
        #pragma unroll
        for (int r = 0; r < 4; ++r)
            y[(size_t)(bs0 + lg*4 + r) * 64 + wid*16 + lm] = yacc[r] + bfo;
    }
}

__global__ __launch_bounds__(256) void ystats_kernel(const float* __restrict__ y,
                                                     double* __restrict__ st)
{
    const int tid = threadIdx.x;
    const int c = tid & 63;
    double s = 0.0, s2 = 0.0;
    for (int i = blockIdx.x * 256 + tid; i < NBATCH*NSAMP*64; i += gridDim.x * 256) {
        const float v = y[i];
        s += v; s2 += (double)v * (double)v;
    }
    __shared__ double rs[256], rs2[256];
    rs[tid] = s; rs2[tid] = s2;
    __syncthreads();
    if (tid < 64) {
        const double a  = rs[c]  + rs[64+c]  + rs[128+c]  + rs[192+c];
        const double a2 = rs2[c] + rs2[64+c] + rs2[128+c] + rs2[192+c];
        atomicAdd(&st[c], a);
        atomicAdd(&st[64 + c], a2);
    }
}

__global__ void writeout_kernel(const float* __restrict__ y,
                                const float* __restrict__ bnp3,
                                float* __restrict__ outp)
{
    const int i = blockIdx.x * 256 + threadIdx.x;
    if (i >= NBATCH * 64 * NSAMP) return;
    const int s = i & 1023;
    const int o = (i >> 10) & 63;
    const int bb = i >> 16;
    const float v = y[((size_t)(bb << 10) + s) * 64 + o];
    outp[i] = fmaxf(bnp3[o] * v + bnp3[64 + o], 0.f);
}

// ============================ launch ============================
extern "C" void kernel_launch(void* const* d_in, const int* in_sizes, int n_in,
                              void* d_out, int out_size, void* d_ws, size_t ws_size,
                              hipStream_t stream)
{
    (void)in_sizes; (void)n_in; (void)out_size; (void)ws_size;
    const float* xyz  = (const float*)d_in[0];
    const float* feat = (const float*)d_in[1];
    const float* w0   = (const float*)d_in[2];
    const float* b0   = (const float*)d_in[3];
    const float* g0   = (const float*)d_in[4];
    const float* be0  = (const float*)d_in[5];
    const float* w1   = (const float*)d_in[6];
    const float* b1   = (const float*)d_in[7];
    const float* g1   = (const float*)d_in[8];
    const float* be1  = (const float*)d_in[9];
    const float* w2   = (const float*)d_in[10];
    const float* b2   = (const float*)d_in[11];
    const float* g2   = (const float*)d_in[12];
    const float* be2  = (const float*)d_in[13];
    const float* wf   = (const float*)d_in[14];
    const float* bf   = (const float*)d_in[15];
    const float* gf   = (const float*)d_in[16];
    const float* bef  = (const float*)d_in[17];

    float* out = (float*)d_out;
    float* newxyz = out;                       // (B, S, 3)
    float* outmain = out + NBATCH * NSAMP * 3; // (B, 64, S)

    char* ws = (char*)d_ws;
    int*      idxws = (int*)ws;                            // 2 MB
    float*    ybuf  = (float*)(ws + 2097152);              // 4 MB
    double*   stats = (double*)(ws + 6291456);             // 4 KB
    float*    bnp   = (float*)(ws + 6295552);              // 2 KB
    unsigned* wfb   = (unsigned*)(ws + 6297600);           // 512 KB
    unsigned* w1b   = (unsigned*)(ws + 6821888);           // 8 KB
    unsigned* w2b   = (unsigned*)(ws + 6830080);           // 8 KB
    float*    G1    = (float*)(ws + 6838272);              // 16 KB
    float*    G2    = (float*)(ws + 6854656);              // 16 KB

    zero_all_kernel<<<16, 256, 0, stream>>>(stats, G1, G2);
    wfpack_kernel<<<512, 64, 0, stream>>>(wf, wfb);
    wfpack_kernel<<<8, 64, 0, stream>>>(w1, w1b);
    wfpack_kernel<<<8, 64, 0, stream>>>(w2, w2b);
    fps_kernel<<<NBATCH, 512, 0, stream>>>(xyz, newxyz);
    knn_kernel<<<NBATCH * NSAMP, 256, 0, stream>>>(xyz, newxyz, idxws);

    gxmoments_kernel<<<512, 256, 0, stream>>>(xyz, newxyz, idxws, stats);
    bn0_moments_finalize_kernel<<<1, 64, 0, stream>>>(stats, w0, b0, g0, be0, bnp);
    gram1_kernel<<<256, 256, 0, stream>>>(xyz, newxyz, idxws, w0, b0, bnp, G1, stats + 128);
    bn_gram_finalize_kernel<<<1, 256, 0, stream>>>(stats + 128, G1, w1, b1, g1, be1, bnp + 128);
    gram2_kernel<<<256, 256, 0, stream>>>(xyz, newxyz, idxws, w0, b0, b1, w1b, bnp, G2, stats + 192);
    bn_gram_finalize_kernel<<<1, 256, 0, stream>>>(stats + 192, G2, w2, b2, g2, be2, bnp + 256);

    final_conv_kernel<<<NBATCH * NSAMP / 8, 256, 0, stream>>>(
        xyz, newxyz, idxws, feat, w0, b0, b1, b2, bnp, wfb, w1b, w2b, bf, ybuf);

    ystats_kernel<<<256, 256, 0, stream>>>(ybuf, stats + 384);
    bn_finalize_kernel<<<1, 64, 0, stream>>>(stats + 384, gf, bef, bnp + 384, (float)(NBATCH * NSAMP));
    writeout_kernel<<<4096, 256, 0, stream>>>(ybuf, bnp + 384, outmain);
}

// Round 9
// 1594.097 us; speedup vs baseline: 3.0391x; 1.0002x over previous
//
#include <hip/hip_runtime.h>

#define NBATCH 16
#define NPTS   4096
#define NSAMP  1024
#define NKNN   32
#define NROWS  (NBATCH*NSAMP*NKNN)   // 524288
#define BN_EPS 1e-5f
#define H1PAD  66

typedef __attribute__((ext_vector_type(4))) float f32x4;
typedef __attribute__((ext_vector_type(8))) short bf16x8;
union frag_u { unsigned u[4]; bf16x8 h; uint4 u4; };

__device__ __forceinline__ unsigned pack_bf16pair(float a, float b) {
    unsigned ua = __float_as_uint(a); ua += 0x7FFFu + ((ua >> 16) & 1u);
    unsigned ub = __float_as_uint(b); ub += 0x7FFFu + ((ub >> 16) & 1u);
    return (ua >> 16) | (ub & 0xFFFF0000u);
}

// ============================ FPS v5 ============================
// 256 thr/block, 16 pts/thread contiguous. DPP wave-max (validated r8),
// ballot+ffs index recovery. NEW: (1) newxyz staged in LDS, single global
// flush at end -> no vmcnt(0) drain at the per-iter barrier; (2) per-wave
// reduce slot carries winner COORDS (float4 v,x,y,z) so the post-barrier
// select has no dependent LDS read. Distance arithmetic bit-identical r1-8.
__global__ __launch_bounds__(256) void fps_kernel(const float* __restrict__ xyz,
                                                  float* __restrict__ newxyz)
{
    const int b = blockIdx.x;
    const int tid = threadIdx.x;
    const int wv = tid >> 6;          // 0..3
    const float* xb = xyz + (size_t)b * NPTS * 3;
    __shared__ float xs[NPTS];
    __shared__ float ys[NPTS];
    __shared__ float zs[NPTS];
    __shared__ __align__(16) float4 red[2][4];   // (maxval, x, y, z)
    __shared__ __align__(16) float nxs[NSAMP*3]; // 12 KB output staging
    float px[16], py[16], pz[16], dmin[16];
    {
        float arr[48];
        const float4* s4 = (const float4*)(xb + (size_t)tid * 48);
        #pragma unroll
        for (int i = 0; i < 12; ++i) *(float4*)&arr[i*4] = s4[i];
        #pragma unroll
        for (int j = 0; j < 16; ++j) {
            px[j] = arr[3*j]; py[j] = arr[3*j+1]; pz[j] = arr[3*j+2];
            const int p = tid * 16 + j;
            xs[p] = px[j]; ys[p] = py[j]; zs[p] = pz[j];
            dmin[j] = 1e10f;
        }
    }
    if (tid == 0) { nxs[0] = xb[0]; nxs[1] = xb[1]; nxs[2] = xb[2]; }
    __syncthreads();
    float lx = xs[0], ly = ys[0], lz = zs[0];
    for (int t = 1; t < NSAMP; ++t) {
        float bv = -1.0f;
        #pragma unroll
        for (int j = 0; j < 16; ++j) {
            const float dx = __fsub_rn(px[j], lx);
            const float dy = __fsub_rn(py[j], ly);
            const float dz = __fsub_rn(pz[j], lz);
            const float d = __fadd_rn(__fadd_rn(__fmul_rn(dx,dx), __fmul_rn(dy,dy)), __fmul_rn(dz,dz));
            const float nd = fminf(dmin[j], d);
            dmin[j] = nd;
            bv = fmaxf(bv, nd);
        }
        int lj = 0;
        #pragma unroll
        for (int j = 15; j >= 0; --j) if (dmin[j] == bv) lj = j;
        const int bi_lane = tid * 16 + lj;
        // ---- wave max via DPP (validated round 8) ----
        float mv = bv;
        {
            int s_;
            s_ = __builtin_amdgcn_mov_dpp(__float_as_int(mv), 0x111, 0xf, 0xf, true); // row_shr:1
            mv = fmaxf(mv, __int_as_float(s_));
            s_ = __builtin_amdgcn_mov_dpp(__float_as_int(mv), 0x112, 0xf, 0xf, true); // row_shr:2
            mv = fmaxf(mv, __int_as_float(s_));
            s_ = __builtin_amdgcn_mov_dpp(__float_as_int(mv), 0x114, 0xf, 0xf, true); // row_shr:4
            mv = fmaxf(mv, __int_as_float(s_));
            s_ = __builtin_amdgcn_mov_dpp(__float_as_int(mv), 0x118, 0xf, 0xf, true); // row_shr:8
            mv = fmaxf(mv, __int_as_float(s_));
            s_ = __builtin_amdgcn_mov_dpp(__float_as_int(mv), 0x142, 0xf, 0xf, true); // row_bcast:15
            mv = fmaxf(mv, __int_as_float(s_));
            s_ = __builtin_amdgcn_mov_dpp(__float_as_int(mv), 0x143, 0xf, 0xf, true); // row_bcast:31
            mv = fmaxf(mv, __int_as_float(s_));
        }
        mv = __int_as_float(__builtin_amdgcn_readlane(__float_as_int(mv), 63));
        const unsigned long long mask = __ballot(bv == mv);
        const int winner = __ffsll(mask) - 1;
        const int bi_w = __builtin_amdgcn_readlane(bi_lane, winner);
        // fetch this wave's candidate coords pre-barrier (uniform -> broadcast)
        const float wx = xs[bi_w], wy = ys[bi_w], wz = zs[bi_w];
        const int par = t & 1;
        if ((tid & 63) == 0) red[par][wv] = make_float4(mv, wx, wy, wz);
        __syncthreads();
        // ---- cross-wave: 4 coord-carrying slots, ascending strict '>' ----
        float4 w0 = red[par][0];
        const float4 w1 = red[par][1];
        const float4 w2 = red[par][2];
        const float4 w3 = red[par][3];
        if (w1.x > w0.x) w0 = w1;
        if (w2.x > w0.x) w0 = w2;
        if (w3.x > w0.x) w0 = w3;
        lx = w0.y; ly = w0.z; lz = w0.w;
        if (tid == 0) { nxs[t*3] = lx; nxs[t*3+1] = ly; nxs[t*3+2] = lz; }
    }
    __syncthreads();
    {   // single flush LDS -> global
        float4* d4 = (float4*)(newxyz + (size_t)b * NSAMP * 3);
        const float4* s4 = (const float4*)nxs;
        #pragma unroll
        for (int i = tid; i < NSAMP*3/4; i += 256) d4[i] = s4[i];
    }
}

// ============================ kNN ============================
// (validated rounds 2-8)
__global__ __launch_bounds__(256) void knn_kernel(const float* __restrict__ xyz,
                                                  const float* __restrict__ newxyz,
                                                  int* __restrict__ idx_out)
{
    const int bs = blockIdx.x;
    const int b = bs >> 10;
    const int tid = threadIdx.x;
    __shared__ unsigned keys[NPTS];
    __shared__ int hist[256];
    __shared__ float qsh[3];
    __shared__ int ctrl[4];
    __shared__ int ties[128];
    if (tid < 3) qsh[tid] = newxyz[bs*3 + tid];
    if (tid == 0) { ctrl[0] = 0; ctrl[1] = NKNN; }
    __syncthreads();
    const float q0 = qsh[0], q1 = qsh[1], q2 = qsh[2];
    const float qq = __fadd_rn(__fadd_rn(__fmul_rn(q0,q0), __fmul_rn(q1,q1)), __fmul_rn(q2,q2));
    const float* xb = xyz + (size_t)b * NPTS * 3;
    for (int n = tid; n < NPTS; n += 256) {
        const float x0 = xb[n*3+0], x1 = xb[n*3+1], x2 = xb[n*3+2];
        const float xx = __fadd_rn(__fadd_rn(__fmul_rn(x0,x0), __fmul_rn(x1,x1)), __fmul_rn(x2,x2));
        float dt = __fmul_rn(q0, x0);
        dt = __fmaf_rn(q1, x1, dt);
        dt = __fmaf_rn(q2, x2, dt);
        const float dd = __fadd_rn(__fsub_rn(qq, __fmul_rn(2.0f, dt)), xx);
        unsigned ub = __float_as_uint(dd);
        ub = (ub & 0x80000000u) ? ~ub : (ub | 0x80000000u);
        keys[n] = ub;
    }
    for (int p = 3; p >= 0; --p) {
        __syncthreads();
        hist[tid] = 0;
        __syncthreads();
        const unsigned pre = (unsigned)ctrl[0];
        const int shift = p * 8;
        const unsigned himask = (p == 3) ? 0u : (0xFFFFFFFFu << ((p + 1) * 8));
        for (int n = tid; n < NPTS; n += 256) {
            const unsigned k = keys[n];
            if ((k & himask) == pre) atomicAdd(&hist[(k >> shift) & 255], 1);
        }
        __syncthreads();
        if (tid == 0) {
            int r = ctrl[1]; unsigned pf = (unsigned)ctrl[0];
            for (int bin = 0; bin < 256; ++bin) {
                const int cnt = hist[bin];
                if (r > cnt) r -= cnt;
                else { pf |= ((unsigned)bin) << shift; break; }
            }
            ctrl[0] = (int)pf; ctrl[1] = r;
        }
    }
    __syncthreads();
    const unsigned T = (unsigned)ctrl[0];
    if (tid == 0) { ctrl[2] = 0; ctrl[3] = 0; }
    __syncthreads();
    int* out = idx_out + (size_t)bs * NKNN;
    for (int n = tid; n < NPTS; n += 256) {
        const unsigned k = keys[n];
        if (k < T) {
            const int pos = atomicAdd(&ctrl[2], 1);
            if (pos < NKNN) out[pos] = n;
        } else if (k == T) {
            const int pos = atomicAdd(&ctrl[3], 1);
            if (pos < 128) ties[pos] = n;
        }
    }
    __syncthreads();
    if (tid == 0) {
        const int nless = ctrl[2] < NKNN ? ctrl[2] : NKNN;
        const int need = NKNN - nless;
        const int ntie = ctrl[3] < 128 ? ctrl[3] : 128;
        int last = -1;
        for (int j = 0; j < need; ++j) {
            int best = 0x7fffffff;
            for (int i = 0; i < ntie; ++i) {
                const int v = ties[i];
                if (v > last && v < best) best = v;
            }
            out[nless + j] = (best == 0x7fffffff) ? 0 : best;
            last = best;
        }
    }
}

// ============================ zero / moments ============================
__global__ void zero_all_kernel(double* st, float* g1, float* g2)
{
    const int i = blockIdx.x * 256 + threadIdx.x;
    if (i < 512) st[i] = 0.0;
    if (i < 4096) { g1[i] = 0.f; g2[i] = 0.f; }
}

__global__ __launch_bounds__(256) void gxmoments_kernel(
    const float* __restrict__ xyz, const float* __restrict__ newxyz,
    const int* __restrict__ idxws, double* __restrict__ stats)
{
    const int tid = threadIdx.x;
    double m[9];
    #pragma unroll
    for (int i = 0; i < 9; ++i) m[i] = 0.0;
    for (int row = blockIdx.x * 256 + tid; row < NROWS; row += gridDim.x * 256) {
        const int bs = row >> 5;
        const int bb = row >> 15;
        const int id = idxws[row];
        const float* xp = xyz + ((size_t)bb * NPTS + id) * 3;
        const float* qp = newxyz + bs * 3;
        const double dx = (double)(xp[0] - qp[0]);
        const double dy = (double)(xp[1] - qp[1]);
        const double dz = (double)(xp[2] - qp[2]);
        m[0] += dx; m[1] += dy; m[2] += dz;
        m[3] += dx*dx; m[4] += dx*dy; m[5] += dx*dz;
        m[6] += dy*dy; m[7] += dy*dz; m[8] += dz*dz;
    }
    #pragma unroll
    for (int i = 0; i < 9; ++i) {
        #pragma unroll
        for (int s = 1; s < 64; s <<= 1) m[i] += __shfl_xor(m[i], s);
    }
    __shared__ double part[4][9];
    if ((tid & 63) == 0) {
        #pragma unroll
        for (int i = 0; i < 9; ++i) part[tid >> 6][i] = m[i];
    }
    __syncthreads();
    if (tid < 9) atomicAdd(&stats[tid], part[0][tid] + part[1][tid] + part[2][tid] + part[3][tid]);
}

__global__ void bn0_moments_finalize_kernel(const double* __restrict__ st,
    const float* __restrict__ w0, const float* __restrict__ b0,
    const float* __restrict__ g0, const float* __restrict__ be0,
    float* __restrict__ outp)
{
    const int c = threadIdx.x;  // 64
    const double N = (double)NROWS;
    const double w0c = w0[c], w1c = w0[64 + c], w2c = w0[128 + c];
    const double b = b0[c];
    const double dotS = st[0]*w0c + st[1]*w1c + st[2]*w2c;
    const double qf = w0c*w0c*st[3] + w1c*w1c*st[6] + w2c*w2c*st[8]
                    + 2.0*(w0c*w1c*st[4] + w0c*w2c*st[5] + w1c*w2c*st[7]);
    const double mean = dotS / N + b;
    const double ex2 = (qf + 2.0*b*dotS) / N + b*b;
    const double var = ex2 - mean*mean;
    const float scale = g0[c] * rsqrtf((float)var + BN_EPS);
    outp[c] = scale;
    outp[64 + c] = be0[c] - (float)mean * scale;
}

// ============================ weight pre-pack ============================
__global__ void wfpack_kernel(const float* __restrict__ wf, unsigned* __restrict__ wfb)
{
    const int blk = blockIdx.x;
    const int kt = blk >> 2, ot = blk & 3;
    const int l = threadIdx.x;            // 64
    const int o = ot*16 + (l & 15);
    const int kb = kt*32 + (l >> 4)*8;
    unsigned out[4];
    #pragma unroll
    for (int r = 0; r < 4; ++r) {
        const float a = wf[(size_t)(kb + 2*r) * 64 + o];
        const float b = wf[(size_t)(kb + 2*r + 1) * 64 + o];
        out[r] = pack_bf16pair(a, b);
    }
    *(uint4*)&wfb[((size_t)blk * 64 + l) * 4] = *(const uint4*)out;
}

// ============================ Gram stats ============================
__global__ __launch_bounds__(256) void gram1_kernel(
    const float* __restrict__ xyz, const float* __restrict__ newxyz,
    const int* __restrict__ idxws,
    const float* __restrict__ w0, const float* __restrict__ b0,
    const float* __restrict__ bnp, float* __restrict__ G1,
    double* __restrict__ Sh1)
{
    __shared__ float gxs[32][3];
    __shared__ float h1s[32][H1PAD];
    __shared__ float rsum[256];
    const int tid = threadIdx.x;
    const int c = tid & 63;
    const int rq = tid >> 6;
    const int lg = c >> 4, lm = c & 15;
    const float w0c0 = w0[c], w0c1 = w0[64+c], w0c2 = w0[128+c];
    const float b0c = b0[c], sc0 = bnp[c], sh0 = bnp[64+c];
    f32x4 Ga[4] = {{0,0,0,0},{0,0,0,0},{0,0,0,0},{0,0,0,0}};
    float sumh = 0.f;
    for (int chunk = blockIdx.x; chunk < NROWS/32; chunk += gridDim.x) {
        if (tid < 96) {
            const int slot = tid / 3, cc = tid % 3;
            const int row = chunk*32 + slot;
            const int bs = row >> 5, bb = row >> 15;
            gxs[slot][cc] = xyz[((size_t)bb * NPTS + idxws[row]) * 3 + cc] - newxyz[bs*3 + cc];
        }
        __syncthreads();
        #pragma unroll
        for (int i = 0; i < 8; ++i) {
            const int r = rq*8 + i;
            const float t0 = gxs[r][0]*w0c0 + gxs[r][1]*w0c1 + gxs[r][2]*w0c2 + b0c;
            const float h = fmaxf(sc0*t0 + sh0, 0.f);
            h1s[r][c] = h;
            sumh += h;
        }
        __syncthreads();
        frag_u fr[4];
        #pragma unroll
        for (int ct = 0; ct < 4; ++ct)
            #pragma unroll
            for (int r = 0; r < 4; ++r)
                fr[ct].u[r] = pack_bf16pair(h1s[lg*8 + 2*r][ct*16 + lm],
                                            h1s[lg*8 + 2*r + 1][ct*16 + lm]);
        #pragma unroll
        for (int ct = 0; ct < 4; ++ct)
            Ga[ct] = __builtin_amdgcn_mfma_f32_16x16x32_bf16(fr[rq].h, fr[ct].h, Ga[ct], 0, 0, 0);
        __syncthreads();
    }
    #pragma unroll
    for (int ct = 0; ct < 4; ++ct)
        #pragma unroll
        for (int r = 0; r < 4; ++r)
            atomicAdd(&G1[(rq*16 + lg*4 + r)*64 + ct*16 + lm], Ga[ct][r]);
    rsum[tid] = sumh;
    __syncthreads();
    if (tid < 64) atomicAdd(&Sh1[c], (double)(rsum[c] + rsum[64+c] + rsum[128+c] + rsum[192+c]));
}

__global__ __launch_bounds__(256) void gram2_kernel(
    const float* __restrict__ xyz, const float* __restrict__ newxyz,
    const int* __restrict__ idxws,
    const float* __restrict__ w0, const float* __restrict__ b0,
    const float* __restrict__ b1, const unsigned* __restrict__ w1b,
    const float* __restrict__ bnp, float* __restrict__ G2,
    double* __restrict__ Sh2)
{
    __shared__ float gxs[32][3];
    __shared__ float h1s[32][H1PAD];
    __shared__ float h2s[32][H1PAD];
    __shared__ float rsum[256];
    const int tid = threadIdx.x;
    const int c = tid & 63;
    const int rq = tid >> 6;
    const int lg = c >> 4, lm = c & 15;
    const int c2 = rq*16 + lm;
    const float w0c0 = w0[c], w0c1 = w0[64+c], w0c2 = w0[128+c];
    const float b0c = b0[c], sc0 = bnp[c], sh0 = bnp[64+c];
    const float b1c2 = b1[c2], sc1 = bnp[128+c2], sh1 = bnp[192+c2];
    frag_u Bw1[2];
    Bw1[0].u4 = *(const uint4*)&w1b[((0*4 + rq)*64 + c)*4];
    Bw1[1].u4 = *(const uint4*)&w1b[((1*4 + rq)*64 + c)*4];
    f32x4 Ga[4] = {{0,0,0,0},{0,0,0,0},{0,0,0,0},{0,0,0,0}};
    float sumh = 0.f;
    for (int chunk = blockIdx.x; chunk < NROWS/32; chunk += gridDim.x) {
        if (tid < 96) {
            const int slot = tid / 3, cc = tid % 3;
            const int row = chunk*32 + slot;
            const int bs = row >> 5, bb = row >> 15;
            gxs[slot][cc] = xyz[((size_t)bb * NPTS + idxws[row]) * 3 + cc] - newxyz[bs*3 + cc];
        }
        __syncthreads();
        #pragma unroll
        for (int i = 0; i < 8; ++i) {
            const int r = rq*8 + i;
            const float t0 = gxs[r][0]*w0c0 + gxs[r][1]*w0c1 + gxs[r][2]*w0c2 + b0c;
            h1s[r][c] = fmaxf(sc0*t0 + sh0, 0.f);
        }
        __syncthreads();
        #pragma unroll
        for (int mt = 0; mt < 2; ++mt) {
            f32x4 acc = {0,0,0,0};
            #pragma unroll
            for (int kt = 0; kt < 2; ++kt) {
                frag_u a;
                #pragma unroll
                for (int r = 0; r < 4; ++r) {
                    const float2 f = *(const float2*)&h1s[mt*16 + lm][kt*32 + lg*8 + 2*r];
                    a.u[r] = pack_bf16pair(f.x, f.y);
                }
                acc = __builtin_amdgcn_mfma_f32_16x16x32_bf16(a.h, Bw1[kt].h, acc, 0, 0, 0);
            }
            #pragma unroll
            for (int r = 0; r < 4; ++r)
                h2s[mt*16 + lg*4 + r][c2] = fmaxf(sc1*(acc[r] + b1c2) + sh1, 0.f);
        }
        __syncthreads();
        #pragma unroll
        for (int i = 0; i < 8; ++i) sumh += h2s[rq*8 + i][c];
        frag_u fr[4];
        #pragma unroll
        for (int ct = 0; ct < 4; ++ct)
            #pragma unroll
            for (int r = 0; r < 4; ++r)
                fr[ct].u[r] = pack_bf16pair(h2s[lg*8 + 2*r][ct*16 + lm],
                                            h2s[lg*8 + 2*r + 1][ct*16 + lm]);
        #pragma unroll
        for (int ct = 0; ct < 4; ++ct)
            Ga[ct] = __builtin_amdgcn_mfma_f32_16x16x32_bf16(fr[rq].h, fr[ct].h, Ga[ct], 0, 0, 0);
        __syncthreads();
    }
    #pragma unroll
    for (int ct = 0; ct < 4; ++ct)
        #pragma unroll
        for (int r = 0; r < 4; ++r)
            atomicAdd(&G2[(rq*16 + lg*4 + r)*64 + ct*16 + lm], Ga[ct][r]);
    rsum[tid] = sumh;
    __syncthreads();
    if (tid < 64) atomicAdd(&Sh2[c], (double)(rsum[c] + rsum[64+c] + rsum[128+c] + rsum[192+c]));
}

__global__ __launch_bounds__(256) void bn_gram_finalize_kernel(
    const double* __restrict__ Sh, const float* __restrict__ G,
    const float* __restrict__ w, const float* __restrict__ bias,
    const float* __restrict__ g, const float* __restrict__ be,
    float* __restrict__ outp)
{
    __shared__ float wls[64][65];
    __shared__ double shl[64];
    __shared__ double rd[256], rqd[256];
    const int tid = threadIdx.x;
    const int c = tid & 63;
    const int rqi = tid >> 6;
    for (int i = tid; i < 4096; i += 256) wls[i >> 6][i & 63] = w[i];
    if (tid < 64) shl[tid] = Sh[tid];
    __syncthreads();
    double dot = 0.0, quad = 0.0;
    for (int j = rqi*16; j < rqi*16 + 16; ++j) {
        const double wjc = (double)wls[j][c];
        dot += wjc * shl[j];
        double inner = 0.0;
        for (int k = 0; k < 64; ++k) inner += (double)G[j*64 + k] * (double)wls[k][c];
        quad += wjc * inner;
    }
    rd[tid] = dot; rqd[tid] = quad;
    __syncthreads();
    if (tid < 64) {
        const double d = rd[c] + rd[64+c] + rd[128+c] + rd[192+c];
        const double q = rqd[c] + rqd[64+c] + rqd[128+c] + rqd[192+c];
        const double N = (double)NROWS;
        const double bc = (double)bias[c];
        const double mean = d / N + bc;
        const double ex2 = (q + 2.0*bc*d) / N + bc*bc;
        const double var = ex2 - mean*mean;
        const float scale = g[c] * rsqrtf((float)var + BN_EPS);
        outp[c] = scale;
        outp[64 + c] = be[c] - (float)mean * scale;
    }
}

__global__ void bn_finalize_kernel(const double* __restrict__ st,
                                   const float* __restrict__ g,
                                   const float* __restrict__ be,
                                   float* __restrict__ outp, float n)
{
    const int c = threadIdx.x;  // 64
    const double m = st[c] / (double)n;
    const double var = st[64 + c] / (double)n - m * m;
    const float scale = g[c] * rsqrtf((float)var + BN_EPS);
    outp[c] = scale;
    outp[64 + c] = be[c] - (float)m * scale;
}

// ============================ final fused conv ============================
__global__ __launch_bounds__(256) void final_conv_kernel(
    const float* __restrict__ xyz, const float* __restrict__ newxyz,
    const int* __restrict__ idxws, const float* __restrict__ feat,
    const float* __restrict__ w0, const float* __restrict__ b0,
    const float* __restrict__ b1, const float* __restrict__ b2,
    const float* __restrict__ bnp, const unsigned* __restrict__ wfb,
    const unsigned* __restrict__ w1b, const unsigned* __restrict__ w2b,
    const float* __restrict__ bf, float* __restrict__ y)
{
    __shared__ unsigned wtp[8][16][64];
    __shared__ __align__(16) float scratch[2*64*H1PAD];
    __shared__ float gxs[64][3];
    __shared__ int   idxs[8][32];
    __shared__ float qs[8][3];
    float* h1s = scratch;
    float* h2s = scratch + 64*H1PAD;
    unsigned* yaf = (unsigned*)scratch;
    const int tid = threadIdx.x;
    const int c = tid & 63;
    const int rq = tid >> 6;
    const int lg = c >> 4, lm = c & 15;
    const int c2 = rq*16 + lm;
    const int bs0 = blockIdx.x * 8;
    const int b = bs0 >> 10;
    idxs[tid >> 5][tid & 31] = idxws[(size_t)bs0 * NKNN + tid];
    if (tid < 24)  qs[tid / 3][tid % 3] = newxyz[(bs0 + tid/3)*3 + (tid % 3)];
    const float w0c0 = w0[c], w0c1 = w0[64+c], w0c2 = w0[128+c];
    const float b0c = b0[c], sc0 = bnp[c], sh0 = bnp[64+c];
    const float b1c2 = b1[c2], sc1 = bnp[128+c2], sh1 = bnp[192+c2];
    const float b2c2 = b2[c2], sc2 = bnp[256+c2], sh2 = bnp[320+c2];
    frag_u Bw1[2], Bw2[2];
    #pragma unroll
    for (int kt = 0; kt < 2; ++kt) {
        Bw1[kt].u4 = *(const uint4*)&w1b[((kt*4 + rq)*64 + c)*4];
        Bw2[kt].u4 = *(const uint4*)&w2b[((kt*4 + rq)*64 + c)*4];
    }
    __syncthreads();
    for (int chunk = 0; chunk < 4; ++chunk) {
        if (tid < 192) {
            const int slot = tid / 3, cc = tid % 3;
            const int grow = chunk*64 + slot;
            const int e = grow >> 5, k = grow & 31;
            gxs[slot][cc] = xyz[((size_t)b * NPTS + idxs[e][k]) * 3 + cc] - qs[e][cc];
        }
        __syncthreads();
        #pragma unroll
        for (int i = 0; i < 16; ++i) {
            const int r = rq*16 + i;
            const float t0 = gxs[r][0]*w0c0 + gxs[r][1]*w0c1 + gxs[r][2]*w0c2 + b0c;
            h1s[r*H1PAD + c] = fmaxf(sc0*t0 + sh0, 0.f);
        }
        __syncthreads();
        #pragma unroll
        for (int mt = 0; mt < 4; ++mt) {
            f32x4 acc = {0,0,0,0};
            #pragma unroll
            for (int kt = 0; kt < 2; ++kt) {
                frag_u a;
                #pragma unroll
                for (int r = 0; r < 4; ++r) {
                    const float2 f = *(const float2*)&h1s[(mt*16 + lm)*H1PAD + kt*32 + lg*8 + 2*r];
                    a.u[r] = pack_bf16pair(f.x, f.y);
                }
                acc = __builtin_amdgcn_mfma_f32_16x16x32_bf16(a.h, Bw1[kt].h, acc, 0, 0, 0);
            }
            #pragma unroll
            for (int r = 0; r < 4; ++r)
                h2s[(mt*16 + lg*4 + r)*H1PAD + c2] = fmaxf(sc1*(acc[r] + b1c2) + sh1, 0.f);
        }
        __syncthreads();
        #pragma unroll
        for (int mt = 0; mt < 4; ++mt) {
            f32x4 acc = {0,0,0,0};
            #pragma unroll
            for (int kt = 0; kt < 2; ++kt) {
                frag_u a;
                #pragma unroll
                for (int r = 0; r < 4; ++r) {
                    const float2 f = *(const float2*)&h2s[(mt*16 + lm)*H1PAD + kt*32 + lg*8 + 2*r];
                    a.u[r] = pack_bf16pair(f.x, f.y);
                }
                acc = __builtin_amdgcn_mfma_f32_16x16x32_bf16(a.h, Bw2[kt].h, acc, 0, 0, 0);
            }
            float wt[4];
            #pragma unroll
            for (int r = 0; r < 4; ++r)
                wt[r] = fmaxf(sc2*(acc[r] + b2c2) + sh2, 0.f);
            const int grow0 = chunk*64 + mt*16 + lg*4;
            const int e = grow0 >> 5, kl = grow0 & 31;
            wtp[e][kl >> 1][c2]       = pack_bf16pair(wt[0], wt[1]);
            wtp[e][(kl >> 1) + 1][c2] = pack_bf16pair(wt[2], wt[3]);
        }
        __syncthreads();
    }
    const int lane = c;
    const int wid = rq;
    frag_u afr[2][4];
    #pragma unroll
    for (int es = 0; es < 2; ++es)
        #pragma unroll
        for (int w4 = 0; w4 < 4; ++w4)
            #pragma unroll
            for (int r = 0; r < 4; ++r)
                afr[es][w4].u[r] = wtp[wid*2 + es][lg*4 + r][w4*16 + lm];
    f32x4 yacc = {0.f, 0.f, 0.f, 0.f};
    for (int dhalf = 0; dhalf < 2; ++dhalf) {
        #pragma unroll
        for (int es = 0; es < 2; ++es) {
            const int e = wid*2 + es;
            #pragma unroll
            for (int dt = 0; dt < 2; ++dt) {
                const int d = dhalf*32 + dt*16 + lm;
                const float* fb = feat + (size_t)(b*64 + d) * NPTS;
                frag_u B;
                #pragma unroll
                for (int r = 0; r < 4; ++r) {
                    const int k0 = lg*8 + 2*r;
                    B.u[r] = pack_bf16pair(fb[idxs[e][k0]], fb[idxs[e][k0+1]]);
                }
                #pragma unroll
                for (int w4 = 0; w4 < 4; ++w4) {
                    f32x4 dnf = {0.f, 0.f, 0.f, 0.f};
                    dnf = __builtin_amdgcn_mfma_f32_16x16x32_bf16(afr[es][w4].h, B.h, dnf, 0, 0, 0);
                    const unsigned p0 = pack_bf16pair(dnf[0], dnf[1]);
                    const unsigned p1 = pack_bf16pair(dnf[2], dnf[3]);
                    const int dloc = dt*16 + lm;
                    const int kp0 = dloc*32 + w4*8 + lg*2;
                    const int sw = kp0 ^ ((lm & 3) << 3) ^ ((e & 7) << 2);
                    *(uint2*)&yaf[e*1024 + sw] = make_uint2(p0, p1);
                }
            }
        }
        __syncthreads();
        for (int kt = 0; kt < 64; ++kt) {
            frag_u A, Bf;
            const int kpb = (kt*16 + lg*4) ^ (((kt >> 1) & 3) << 3) ^ ((lm & 7) << 2);
            A.u4 = *(const uint4*)&yaf[(lm & 7)*1024 + kpb];
            Bf.u4 = *(const uint4*)&wfb[(((size_t)(dhalf*64 + kt)*4 + wid)*64 + lane)*4];
            yacc = __builtin_amdgcn_mfma_f32_16x16x32_bf16(A.h, Bf.h, yacc, 0, 0, 0);
        }
        __syncthreads();
    }
    if (lg < 2) {
        const float bfo = bf[wid*16 + lm];
        #pragma unroll
        for (int r = 0; r < 4; ++r)
            y[(size_t)(bs0 + lg*4 + r) * 64 + wid*16 + lm] = yacc[r] + bfo;
    }
}

__global__ __launch_bounds__(256) void ystats_kernel(const float* __restrict__ y,
                                                     double* __restrict__ st)
{
    const int tid = threadIdx.x;
    const int c = tid & 63;
    double s = 0.0, s2 = 0.0;
    for (int i = blockIdx.x * 256 + tid; i < NBATCH*NSAMP*64; i += gridDim.x * 256) {
        const float v = y[i];
        s += v; s2 += (double)v * (double)v;
    }
    __shared__ double rs[256], rs2[256];
    rs[tid] = s; rs2[tid] = s2;
    __syncthreads();
    if (tid < 64) {
        const double a  = rs[c]  + rs[64+c]  + rs[128+c]  + rs[192+c];
        const double a2 = rs2[c] + rs2[64+c] + rs2[128+c] + rs2[192+c];
        atomicAdd(&st[c], a);
        atomicAdd(&st[64 + c], a2);
    }
}

__global__ void writeout_kernel(const float* __restrict__ y,
                                const float* __restrict__ bnp3,
                                float* __restrict__ outp)
{
    const int i = blockIdx.x * 256 + threadIdx.x;
    if (i >= NBATCH * 64 * NSAMP) return;
    const int s = i & 1023;
    const int o = (i >> 10) & 63;
    const int bb = i >> 16;
    const float v = y[((size_t)(bb << 10) + s) * 64 + o];
    outp[i] = fmaxf(bnp3[o] * v + bnp3[64 + o], 0.f);
}

// ============================ launch ============================
extern "C" void kernel_launch(void* const* d_in, const int* in_sizes, int n_in,
                              void* d_out, int out_size, void* d_ws, size_t ws_size,
                              hipStream_t stream)
{
    (void)in_sizes; (void)n_in; (void)out_size; (void)ws_size;
    const float* xyz  = (const float*)d_in[0];
    const float* feat = (const float*)d_in[1];
    const float* w0   = (const float*)d_in[2];
    const float* b0   = (const float*)d_in[3];
    const float* g0   = (const float*)d_in[4];
    const float* be0  = (const float*)d_in[5];
    const float* w1   = (const float*)d_in[6];
    const float* b1   = (const float*)d_in[7];
    const float* g1   = (const float*)d_in[8];
    const float* be1  = (const float*)d_in[9];
    const float* w2   = (const float*)d_in[10];
    const float* b2   = (const float*)d_in[11];
    const float* g2   = (const float*)d_in[12];
    const float* be2  = (const float*)d_in[13];
    const float* wf   = (const float*)d_in[14];
    const float* bf   = (const float*)d_in[15];
    const float* gf   = (const float*)d_in[16];
    const float* bef  = (const float*)d_in[17];

    float* out = (float*)d_out;
    float* newxyz = out;                       // (B, S, 3)
    float* outmain = out + NBATCH * NSAMP * 3; // (B, 64, S)

    char* ws = (char*)d_ws;
    int*      idxws = (int*)ws;                            // 2 MB
    float*    ybuf  = (float*)(ws + 2097152);              // 4 MB
    double*   stats = (double*)(ws + 6291456);             // 4 KB
    float*    bnp   = (float*)(ws + 6295552);              // 2 KB
    unsigned* wfb   = (unsigned*)(ws + 6297600);           // 512 KB
    unsigned* w1b   = (unsigned*)(ws + 6821888);           // 8 KB
    unsigned* w2b   = (unsigned*)(ws + 6830080);           // 8 KB
    float*    G1    = (float*)(ws + 6838272);              // 16 KB
    float*    G2    = (float*)(ws + 6854656);              // 16 KB

    zero_all_kernel<<<16, 256, 0, stream>>>(stats, G1, G2);
    wfpack_kernel<<<512, 64, 0, stream>>>(wf, wfb);
    wfpack_kernel<<<8, 64, 0, stream>>>(w1, w1b);
    wfpack_kernel<<<8, 64, 0, stream>>>(w2, w2b);
    fps_kernel<<<NBATCH, 256, 0, stream>>>(xyz, newxyz);
    knn_kernel<<<NBATCH * NSAMP, 256, 0, stream>>>(xyz, newxyz, idxws);

    gxmoments_kernel<<<512, 256, 0, stream>>>(xyz, newxyz, idxws, stats);
    bn0_moments_finalize_kernel<<<1, 64, 0, stream>>>(stats, w0, b0, g0, be0, bnp);
    gram1_kernel<<<256, 256, 0, stream>>>(xyz, newxyz, idxws, w0, b0, bnp, G1, stats + 128);
    bn_gram_finalize_kernel<<<1, 256, 0, stream>>>(stats + 128, G1, w1, b1, g1, be1, bnp + 128);
    gram2_kernel<<<256, 256, 0, stream>>>(xyz, newxyz, idxws, w0, b0, b1, w1b, bnp, G2, stats + 192);
    bn_gram_finalize_kernel<<<1, 256, 0, stream>>>(stats + 192, G2, w2, b2, g2, be2, bnp + 256);

    final_conv_kernel<<<NBATCH * NSAMP / 8, 256, 0, stream>>>(
        xyz, newxyz, idxws, feat, w0, b0, b1, b2, bnp, wfb, w1b, w2b, bf, ybuf);

    ystats_kernel<<<256, 256, 0, stream>>>(ybuf, stats + 384);
    bn_finalize_kernel<<<1, 64, 0, stream>>>(stats + 384, gf, bef, bnp + 384, (float)(NBATCH * NSAMP));
    writeout_kernel<<<4096, 256, 0, stream>>>(ybuf, bnp + 384, outmain);
}

// Round 10
// 1371.402 us; speedup vs baseline: 3.5326x; 1.1624x over previous
//
#include <hip/hip_runtime.h>

#define NBATCH 16
#define NPTS   4096
#define NSAMP  1024
#define NKNN   32
#define NROWS  (NBATCH*NSAMP*NKNN)   // 524288
#define BN_EPS 1e-5f
#define H1PAD  66
#define KNN_CAP 512

typedef __attribute__((ext_vector_type(4))) float f32x4;
typedef __attribute__((ext_vector_type(8))) short bf16x8;
union frag_u { unsigned u[4]; bf16x8 h; uint4 u4; };

__device__ __forceinline__ unsigned pack_bf16pair(float a, float b) {
    unsigned ua = __float_as_uint(a); ua += 0x7FFFu + ((ua >> 16) & 1u);
    unsigned ub = __float_as_uint(b); ub += 0x7FFFu + ((ub >> 16) & 1u);
    return (ua >> 16) | (ub & 0xFFFF0000u);
}

// ============================ FPS v5 ============================
// (validated rounds 1-9; at structural floor ~650us — untouched)
__global__ __launch_bounds__(256) void fps_kernel(const float* __restrict__ xyz,
                                                  float* __restrict__ newxyz)
{
    const int b = blockIdx.x;
    const int tid = threadIdx.x;
    const int wv = tid >> 6;          // 0..3
    const float* xb = xyz + (size_t)b * NPTS * 3;
    __shared__ float xs[NPTS];
    __shared__ float ys[NPTS];
    __shared__ float zs[NPTS];
    __shared__ __align__(16) float4 red[2][4];   // (maxval, x, y, z)
    __shared__ __align__(16) float nxs[NSAMP*3]; // 12 KB output staging
    float px[16], py[16], pz[16], dmin[16];
    {
        float arr[48];
        const float4* s4 = (const float4*)(xb + (size_t)tid * 48);
        #pragma unroll
        for (int i = 0; i < 12; ++i) *(float4*)&arr[i*4] = s4[i];
        #pragma unroll
        for (int j = 0; j < 16; ++j) {
            px[j] = arr[3*j]; py[j] = arr[3*j+1]; pz[j] = arr[3*j+2];
            const int p = tid * 16 + j;
            xs[p] = px[j]; ys[p] = py[j]; zs[p] = pz[j];
            dmin[j] = 1e10f;
        }
    }
    if (tid == 0) { nxs[0] = xb[0]; nxs[1] = xb[1]; nxs[2] = xb[2]; }
    __syncthreads();
    float lx = xs[0], ly = ys[0], lz = zs[0];
    for (int t = 1; t < NSAMP; ++t) {
        float bv = -1.0f;
        #pragma unroll
        for (int j = 0; j < 16; ++j) {
            const float dx = __fsub_rn(px[j], lx);
            const float dy = __fsub_rn(py[j], ly);
            const float dz = __fsub_rn(pz[j], lz);
            const float d = __fadd_rn(__fadd_rn(__fmul_rn(dx,dx), __fmul_rn(dy,dy)), __fmul_rn(dz,dz));
            const float nd = fminf(dmin[j], d);
            dmin[j] = nd;
            bv = fmaxf(bv, nd);
        }
        int lj = 0;
        #pragma unroll
        for (int j = 15; j >= 0; --j) if (dmin[j] == bv) lj = j;
        const int bi_lane = tid * 16 + lj;
        float mv = bv;
        {
            int s_;
            s_ = __builtin_amdgcn_mov_dpp(__float_as_int(mv), 0x111, 0xf, 0xf, true);
            mv = fmaxf(mv, __int_as_float(s_));
            s_ = __builtin_amdgcn_mov_dpp(__float_as_int(mv), 0x112, 0xf, 0xf, true);
            mv = fmaxf(mv, __int_as_float(s_));
            s_ = __builtin_amdgcn_mov_dpp(__float_as_int(mv), 0x114, 0xf, 0xf, true);
            mv = fmaxf(mv, __int_as_float(s_));
            s_ = __builtin_amdgcn_mov_dpp(__float_as_int(mv), 0x118, 0xf, 0xf, true);
            mv = fmaxf(mv, __int_as_float(s_));
            s_ = __builtin_amdgcn_mov_dpp(__float_as_int(mv), 0x142, 0xf, 0xf, true);
            mv = fmaxf(mv, __int_as_float(s_));
            s_ = __builtin_amdgcn_mov_dpp(__float_as_int(mv), 0x143, 0xf, 0xf, true);
            mv = fmaxf(mv, __int_as_float(s_));
        }
        mv = __int_as_float(__builtin_amdgcn_readlane(__float_as_int(mv), 63));
        const unsigned long long mask = __ballot(bv == mv);
        const int winner = __ffsll(mask) - 1;
        const int bi_w = __builtin_amdgcn_readlane(bi_lane, winner);
        const float wx = xs[bi_w], wy = ys[bi_w], wz = zs[bi_w];
        const int par = t & 1;
        if ((tid & 63) == 0) red[par][wv] = make_float4(mv, wx, wy, wz);
        __syncthreads();
        float4 w0 = red[par][0];
        const float4 w1 = red[par][1];
        const float4 w2 = red[par][2];
        const float4 w3 = red[par][3];
        if (w1.x > w0.x) w0 = w1;
        if (w2.x > w0.x) w0 = w2;
        if (w3.x > w0.x) w0 = w3;
        lx = w0.y; ly = w0.z; lz = w0.w;
        if (tid == 0) { nxs[t*3] = lx; nxs[t*3+1] = ly; nxs[t*3+2] = lz; }
    }
    __syncthreads();
    {
        float4* d4 = (float4*)(newxyz + (size_t)b * NSAMP * 3);
        const float4* s4 = (const float4*)nxs;
        #pragma unroll
        for (int i = tid; i < NSAMP*3/4; i += 256) d4[i] = s4[i];
    }
}

// ============================ kNN v2 ============================
// Same keys (FMA-chain dot, validated r2-9), same selection math. NEW:
// (1) parallel bin-select (shfl_up prefix scan; bin = unique excl<r<=incl),
// (2) after the top-byte round, compact candidate indices (cap 512, full-scan
// fallback) so rounds 2-0 + output touch <=512 entries. Output permutation
// within the <T set changes (downstream is K-permutation-invariant);
// tie tail remains ascending-index.
__device__ __forceinline__ void bin_select(int* hist, int* ctrl, int* wsum,
                                           int tid, int shift)
{
    const int lane = tid & 63, wv = tid >> 6;
    const int cnt = hist[tid];
    const int r = ctrl[1];            // read old r BEFORE the barrier
    int incl = cnt;
    #pragma unroll
    for (int d = 1; d < 64; d <<= 1) {
        const int v = __shfl_up(incl, d);
        if (lane >= d) incl += v;
    }
    if (lane == 63) wsum[wv] = incl;
    __syncthreads();
    int base = 0;
    if (wv > 0) base += wsum[0];
    if (wv > 1) base += wsum[1];
    if (wv > 2) base += wsum[2];
    incl += base;
    const int excl = incl - cnt;
    if (excl < r && r <= incl) {      // exactly one thread
        ctrl[0] |= tid << shift;
        ctrl[1] = r - excl;
        ctrl[2] = cnt;
    }
}

__global__ __launch_bounds__(256) void knn_kernel(const float* __restrict__ xyz,
                                                  const float* __restrict__ newxyz,
                                                  int* __restrict__ idx_out)
{
    const int bs = blockIdx.x;
    const int b = bs >> 10;
    const int tid = threadIdx.x;
    __shared__ unsigned keys[NPTS];   // 16 KB
    __shared__ int hist[256];
    __shared__ float qsh[3];
    __shared__ int ctrl[8];           // 0:pf 1:r 2:selCnt 3:eqn 4:ltn 5:outn 6:tien
    __shared__ int wsum[4];
    __shared__ int cl[KNN_CAP];
    __shared__ int lt[32];
    __shared__ int ties[128];
    if (tid < 3) qsh[tid] = newxyz[bs*3 + tid];
    if (tid == 0) { ctrl[0] = 0; ctrl[1] = NKNN; }
    hist[tid] = 0;
    __syncthreads();
    const float q0 = qsh[0], q1 = qsh[1], q2 = qsh[2];
    const float qq = __fadd_rn(__fadd_rn(__fmul_rn(q0,q0), __fmul_rn(q1,q1)), __fmul_rn(q2,q2));
    const float* xb = xyz + (size_t)b * NPTS * 3;
    // keys + fused top-byte histogram
    for (int n = tid; n < NPTS; n += 256) {
        const float x0 = xb[n*3+0], x1 = xb[n*3+1], x2 = xb[n*3+2];
        const float xx = __fadd_rn(__fadd_rn(__fmul_rn(x0,x0), __fmul_rn(x1,x1)), __fmul_rn(x2,x2));
        float dt = __fmul_rn(q0, x0);
        dt = __fmaf_rn(q1, x1, dt);
        dt = __fmaf_rn(q2, x2, dt);
        const float dd = __fadd_rn(__fsub_rn(qq, __fmul_rn(2.0f, dt)), xx);
        unsigned ub = __float_as_uint(dd);
        ub = (ub & 0x80000000u) ? ~ub : (ub | 0x80000000u);
        keys[n] = ub;
        atomicAdd(&hist[ub >> 24], 1);
    }
    __syncthreads();
    bin_select(hist, ctrl, wsum, tid, 24);
    __syncthreads();
    const unsigned pf3 = (unsigned)ctrl[0];
    const int bin3 = (int)(pf3 >> 24);
    const int m = ctrl[2];
    const bool compact = (m <= KNN_CAP);
    if (tid == 0) { ctrl[3] = 0; ctrl[4] = 0; ctrl[5] = 0; ctrl[6] = 0; }
    __syncthreads();
    if (compact) {
        for (int n = tid; n < NPTS; n += 256) {
            const int tb = (int)(keys[n] >> 24);
            if (tb == bin3)      { const int pos = atomicAdd(&ctrl[3], 1); cl[pos] = n; }
            else if (tb < bin3)  { const int pos = atomicAdd(&ctrl[4], 1); lt[pos] = n; }  // <=31
        }
    }
    __syncthreads();
    // rounds on byte 2,1,0
    for (int p = 2; p >= 0; --p) {
        hist[tid] = 0;
        __syncthreads();
        const unsigned pre = (unsigned)ctrl[0];
        const int shift = p * 8;
        const unsigned himask = 0xFFFFFFFFu << ((p + 1) * 8);
        if (compact) {
            const int eqn = ctrl[3];
            for (int i = tid; i < eqn; i += 256) {
                const unsigned k = keys[cl[i]];
                if ((k & himask) == pre) atomicAdd(&hist[(k >> shift) & 255], 1);
            }
        } else {
            for (int n = tid; n < NPTS; n += 256) {
                const unsigned k = keys[n];
                if ((k & himask) == pre) atomicAdd(&hist[(k >> shift) & 255], 1);
            }
        }
        __syncthreads();
        bin_select(hist, ctrl, wsum, tid, shift);
        __syncthreads();
    }
    // output
    const unsigned T = (unsigned)ctrl[0];
    int* out = idx_out + (size_t)bs * NKNN;
    if (compact) {
        const int ltn = ctrl[4];
        if (tid == 0) ctrl[5] = ltn;
        __syncthreads();
        if (tid < ltn) out[tid] = lt[tid];   // all strictly < T by construction
        const int eqn = ctrl[3];
        for (int i = tid; i < eqn; i += 256) {
            const int n = cl[i];
            const unsigned k = keys[n];
            if (k < T) {
                const int pos = atomicAdd(&ctrl[5], 1);
                if (pos < NKNN) out[pos] = n;
            } else if (k == T) {
                const int pos = atomicAdd(&ctrl[6], 1);
                if (pos < 128) ties[pos] = n;
            }
        }
    } else {
        for (int n = tid; n < NPTS; n += 256) {
            const unsigned k = keys[n];
            if (k < T) {
                const int pos = atomicAdd(&ctrl[5], 1);
                if (pos < NKNN) out[pos] = n;
            } else if (k == T) {
                const int pos = atomicAdd(&ctrl[6], 1);
                if (pos < 128) ties[pos] = n;
            }
        }
    }
    __syncthreads();
    if (tid == 0) {
        const int nless = ctrl[5] < NKNN ? ctrl[5] : NKNN;
        const int need = NKNN - nless;
        const int ntie = ctrl[6] < 128 ? ctrl[6] : 128;
        int last = -1;
        for (int j = 0; j < need; ++j) {
            int best = 0x7fffffff;
            for (int i = 0; i < ntie; ++i) {
                const int v = ties[i];
                if (v > last && v < best) best = v;
            }
            out[nless + j] = (best == 0x7fffffff) ? 0 : best;
            last = best;
        }
    }
}

// ============================ zero / moments ============================
__global__ void zero_all_kernel(double* st, float* g1, float* g2)
{
    const int i = blockIdx.x * 256 + threadIdx.x;
    if (i < 512) st[i] = 0.0;
    if (i < 4096) { g1[i] = 0.f; g2[i] = 0.f; }
}

__global__ __launch_bounds__(256) void gxmoments_kernel(
    const float* __restrict__ xyz, const float* __restrict__ newxyz,
    const int* __restrict__ idxws, double* __restrict__ stats)
{
    const int tid = threadIdx.x;
    double m[9];
    #pragma unroll
    for (int i = 0; i < 9; ++i) m[i] = 0.0;
    for (int row = blockIdx.x * 256 + tid; row < NROWS; row += gridDim.x * 256) {
        const int bs = row >> 5;
        const int bb = row >> 15;
        const int id = idxws[row];
        const float* xp = xyz + ((size_t)bb * NPTS + id) * 3;
        const float* qp = newxyz + bs * 3;
        const double dx = (double)(xp[0] - qp[0]);
        const double dy = (double)(xp[1] - qp[1]);
        const double dz = (double)(xp[2] - qp[2]);
        m[0] += dx; m[1] += dy; m[2] += dz;
        m[3] += dx*dx; m[4] += dx*dy; m[5] += dx*dz;
        m[6] += dy*dy; m[7] += dy*dz; m[8] += dz*dz;
    }
    #pragma unroll
    for (int i = 0; i < 9; ++i) {
        #pragma unroll
        for (int s = 1; s < 64; s <<= 1) m[i] += __shfl_xor(m[i], s);
    }
    __shared__ double part[4][9];
    if ((tid & 63) == 0) {
        #pragma unroll
        for (int i = 0; i < 9; ++i) part[tid >> 6][i] = m[i];
    }
    __syncthreads();
    if (tid < 9) atomicAdd(&stats[tid], part[0][tid] + part[1][tid] + part[2][tid] + part[3][tid]);
}

__global__ void bn0_moments_finalize_kernel(const double* __restrict__ st,
    const float* __restrict__ w0, const float* __restrict__ b0,
    const float* __restrict__ g0, const float* __restrict__ be0,
    float* __restrict__ outp)
{
    const int c = threadIdx.x;  // 64
    const double N = (double)NROWS;
    const double w0c = w0[c], w1c = w0[64 + c], w2c = w0[128 + c];
    const double b = b0[c];
    const double dotS = st[0]*w0c + st[1]*w1c + st[2]*w2c;
    const double qf = w0c*w0c*st[3] + w1c*w1c*st[6] + w2c*w2c*st[8]
                    + 2.0*(w0c*w1c*st[4] + w0c*w2c*st[5] + w1c*w2c*st[7]);
    const double mean = dotS / N + b;
    const double ex2 = (qf + 2.0*b*dotS) / N + b*b;
    const double var = ex2 - mean*mean;
    const float scale = g0[c] * rsqrtf((float)var + BN_EPS);
    outp[c] = scale;
    outp[64 + c] = be0[c] - (float)mean * scale;
}

// ============================ weight pre-pack ============================
__global__ void wfpack_kernel(const float* __restrict__ wf, unsigned* __restrict__ wfb)
{
    const int blk = blockIdx.x;
    const int kt = blk >> 2, ot = blk & 3;
    const int l = threadIdx.x;            // 64
    const int o = ot*16 + (l & 15);
    const int kb = kt*32 + (l >> 4)*8;
    unsigned out[4];
    #pragma unroll
    for (int r = 0; r < 4; ++r) {
        const float a = wf[(size_t)(kb + 2*r) * 64 + o];
        const float b = wf[(size_t)(kb + 2*r + 1) * 64 + o];
        out[r] = pack_bf16pair(a, b);
    }
    *(uint4*)&wfb[((size_t)blk * 64 + l) * 4] = *(const uint4*)out;
}

// ============================ Gram stats ============================
__global__ __launch_bounds__(256) void gram1_kernel(
    const float* __restrict__ xyz, const float* __restrict__ newxyz,
    const int* __restrict__ idxws,
    const float* __restrict__ w0, const float* __restrict__ b0,
    const float* __restrict__ bnp, float* __restrict__ G1,
    double* __restrict__ Sh1)
{
    __shared__ float gxs[32][3];
    __shared__ float h1s[32][H1PAD];
    __shared__ float rsum[256];
    const int tid = threadIdx.x;
    const int c = tid & 63;
    const int rq = tid >> 6;
    const int lg = c >> 4, lm = c & 15;
    const float w0c0 = w0[c], w0c1 = w0[64+c], w0c2 = w0[128+c];
    const float b0c = b0[c], sc0 = bnp[c], sh0 = bnp[64+c];
    f32x4 Ga[4] = {{0,0,0,0},{0,0,0,0},{0,0,0,0},{0,0,0,0}};
    float sumh = 0.f;
    for (int chunk = blockIdx.x; chunk < NROWS/32; chunk += gridDim.x) {
        if (tid < 96) {
            const int slot = tid / 3, cc = tid % 3;
            const int row = chunk*32 + slot;
            const int bs = row >> 5, bb = row >> 15;
            gxs[slot][cc] = xyz[((size_t)bb * NPTS + idxws[row]) * 3 + cc] - newxyz[bs*3 + cc];
        }
        __syncthreads();
        #pragma unroll
        for (int i = 0; i < 8; ++i) {
            const int r = rq*8 + i;
            const float t0 = gxs[r][0]*w0c0 + gxs[r][1]*w0c1 + gxs[r][2]*w0c2 + b0c;
            const float h = fmaxf(sc0*t0 + sh0, 0.f);
            h1s[r][c] = h;
            sumh += h;
        }
        __syncthreads();
        frag_u fr[4];
        #pragma unroll
        for (int ct = 0; ct < 4; ++ct)
            #pragma unroll
            for (int r = 0; r < 4; ++r)
                fr[ct].u[r] = pack_bf16pair(h1s[lg*8 + 2*r][ct*16 + lm],
                                            h1s[lg*8 + 2*r + 1][ct*16 + lm]);
        #pragma unroll
        for (int ct = 0; ct < 4; ++ct)
            Ga[ct] = __builtin_amdgcn_mfma_f32_16x16x32_bf16(fr[rq].h, fr[ct].h, Ga[ct], 0, 0, 0);
        __syncthreads();
    }
    #pragma unroll
    for (int ct = 0; ct < 4; ++ct)
        #pragma unroll
        for (int r = 0; r < 4; ++r)
            atomicAdd(&G1[(rq*16 + lg*4 + r)*64 + ct*16 + lm], Ga[ct][r]);
    rsum[tid] = sumh;
    __syncthreads();
    if (tid < 64) atomicAdd(&Sh1[c], (double)(rsum[c] + rsum[64+c] + rsum[128+c] + rsum[192+c]));
}

__global__ __launch_bounds__(256) void gram2_kernel(
    const float* __restrict__ xyz, const float* __restrict__ newxyz,
    const int* __restrict__ idxws,
    const float* __restrict__ w0, const float* __restrict__ b0,
    const float* __restrict__ b1, const unsigned* __restrict__ w1b,
    const float* __restrict__ bnp, float* __restrict__ G2,
    double* __restrict__ Sh2)
{
    __shared__ float gxs[32][3];
    __shared__ float h1s[32][H1PAD];
    __shared__ float h2s[32][H1PAD];
    __shared__ float rsum[256];
    const int tid = threadIdx.x;
    const int c = tid & 63;
    const int rq = tid >> 6;
    const int lg = c >> 4, lm = c & 15;
    const int c2 = rq*16 + lm;
    const float w0c0 = w0[c], w0c1 = w0[64+c], w0c2 = w0[128+c];
    const float b0c = b0[c], sc0 = bnp[c], sh0 = bnp[64+c];
    const float b1c2 = b1[c2], sc1 = bnp[128+c2], sh1 = bnp[192+c2];
    frag_u Bw1[2];
    Bw1[0].u4 = *(const uint4*)&w1b[((0*4 + rq)*64 + c)*4];
    Bw1[1].u4 = *(const uint4*)&w1b[((1*4 + rq)*64 + c)*4];
    f32x4 Ga[4] = {{0,0,0,0},{0,0,0,0},{0,0,0,0},{0,0,0,0}};
    float sumh = 0.f;
    for (int chunk = blockIdx.x; chunk < NROWS/32; chunk += gridDim.x) {
        if (tid < 96) {
            const int slot = tid / 3, cc = tid % 3;
            const int row = chunk*32 + slot;
            const int bs = row >> 5, bb = row >> 15;
            gxs[slot][cc] = xyz[((size_t)bb * NPTS + idxws[row]) * 3 + cc] - newxyz[bs*3 + cc];
        }
        __syncthreads();
        #pragma unroll
        for (int i = 0; i < 8; ++i) {
            const int r = rq*8 + i;
            const float t0 = gxs[r][0]*w0c0 + gxs[r][1]*w0c1 + gxs[r][2]*w0c2 + b0c;
            h1s[r][c] = fmaxf(sc0*t0 + sh0, 0.f);
        }
        __syncthreads();
        #pragma unroll
        for (int mt = 0; mt < 2; ++mt) {
            f32x4 acc = {0,0,0,0};
            #pragma unroll
            for (int kt = 0; kt < 2; ++kt) {
                frag_u a;
                #pragma unroll
                for (int r = 0; r < 4; ++r) {
                    const float2 f = *(const float2*)&h1s[mt*16 + lm][kt*32 + lg*8 + 2*r];
                    a.u[r] = pack_bf16pair(f.x, f.y);
                }
                acc = __builtin_amdgcn_mfma_f32_16x16x32_bf16(a.h, Bw1[kt].h, acc, 0, 0, 0);
            }
            #pragma unroll
            for (int r = 0; r < 4; ++r)
                h2s[mt*16 + lg*4 + r][c2] = fmaxf(sc1*(acc[r] + b1c2) + sh1, 0.f);
        }
        __syncthreads();
        #pragma unroll
        for (int i = 0; i < 8; ++i) sumh += h2s[rq*8 + i][c];
        frag_u fr[4];
        #pragma unroll
        for (int ct = 0; ct < 4; ++ct)
            #pragma unroll
            for (int r = 0; r < 4; ++r)
                fr[ct].u[r] = pack_bf16pair(h2s[lg*8 + 2*r][ct*16 + lm],
                                            h2s[lg*8 + 2*r + 1][ct*16 + lm]);
        #pragma unroll
        for (int ct = 0; ct < 4; ++ct)
            Ga[ct] = __builtin_amdgcn_mfma_f32_16x16x32_bf16(fr[rq].h, fr[ct].h, Ga[ct], 0, 0, 0);
        __syncthreads();
    }
    #pragma unroll
    for (int ct = 0; ct < 4; ++ct)
        #pragma unroll
        for (int r = 0; r < 4; ++r)
            atomicAdd(&G2[(rq*16 + lg*4 + r)*64 + ct*16 + lm], Ga[ct][r]);
    rsum[tid] = sumh;
    __syncthreads();
    if (tid < 64) atomicAdd(&Sh2[c], (double)(rsum[c] + rsum[64+c] + rsum[128+c] + rsum[192+c]));
}

__global__ __launch_bounds__(256) void bn_gram_finalize_kernel(
    const double* __restrict__ Sh, const float* __restrict__ G,
    const float* __restrict__ w, const float* __restrict__ bias,
    const float* __restrict__ g, const float* __restrict__ be,
    float* __restrict__ outp)
{
    __shared__ float wls[64][65];
    __shared__ double shl[64];
    __shared__ double rd[256], rqd[256];
    const int tid = threadIdx.x;
    const int c = tid & 63;
    const int rqi = tid >> 6;
    for (int i = tid; i < 4096; i += 256) wls[i >> 6][i & 63] = w[i];
    if (tid < 64) shl[tid] = Sh[tid];
    __syncthreads();
    double dot = 0.0, quad = 0.0;
    for (int j = rqi*16; j < rqi*16 + 16; ++j) {
        const double wjc = (double)wls[j][c];
        dot += wjc * shl[j];
        double inner = 0.0;
        for (int k = 0; k < 64; ++k) inner += (double)G[j*64 + k] * (double)wls[k][c];
        quad += wjc * inner;
    }
    rd[tid] = dot; rqd[tid] = quad;
    __syncthreads();
    if (tid < 64) {
        const double d = rd[c] + rd[64+c] + rd[128+c] + rd[192+c];
        const double q = rqd[c] + rqd[64+c] + rqd[128+c] + rqd[192+c];
        const double N = (double)NROWS;
        const double bc = (double)bias[c];
        const double mean = d / N + bc;
        const double ex2 = (q + 2.0*bc*d) / N + bc*bc;
        const double var = ex2 - mean*mean;
        const float scale = g[c] * rsqrtf((float)var + BN_EPS);
        outp[c] = scale;
        outp[64 + c] = be[c] - (float)mean * scale;
    }
}

__global__ void bn_finalize_kernel(const double* __restrict__ st,
                                   const float* __restrict__ g,
                                   const float* __restrict__ be,
                                   float* __restrict__ outp, float n)
{
    const int c = threadIdx.x;  // 64
    const double m = st[c] / (double)n;
    const double var = st[64 + c] / (double)n - m * m;
    const float scale = g[c] * rsqrtf((float)var + BN_EPS);
    outp[c] = scale;
    outp[64 + c] = be[c] - (float)m * scale;
}

// ============================ final fused conv ============================
__global__ __launch_bounds__(256) void final_conv_kernel(
    const float* __restrict__ xyz, const float* __restrict__ newxyz,
    const int* __restrict__ idxws, const float* __restrict__ feat,
    const float* __restrict__ w0, const float* __restrict__ b0,
    const float* __restrict__ b1, const float* __restrict__ b2,
    const float* __restrict__ bnp, const unsigned* __restrict__ wfb,
    const unsigned* __restrict__ w1b, const unsigned* __restrict__ w2b,
    const float* __restrict__ bf, float* __restrict__ y)
{
    __shared__ unsigned wtp[8][16][64];
    __shared__ __align__(16) float scratch[2*64*H1PAD];
    __shared__ float gxs[64][3];
    __shared__ int   idxs[8][32];
    __shared__ float qs[8][3];
    float* h1s = scratch;
    float* h2s = scratch + 64*H1PAD;
    unsigned* yaf = (unsigned*)scratch;
    const int tid = threadIdx.x;
    const int c = tid & 63;
    const int rq = tid >> 6;
    const int lg = c >> 4, lm = c & 15;
    const int c2 = rq*16 + lm;
    const int bs0 = blockIdx.x * 8;
    const int b = bs0 >> 10;
    idxs[tid >> 5][tid & 31] = idxws[(size_t)bs0 * NKNN + tid];
    if (tid < 24)  qs[tid / 3][tid % 3] = newxyz[(bs0 + tid/3)*3 + (tid % 3)];
    const float w0c0 = w0[c], w0c1 = w0[64+c], w0c2 = w0[128+c];
    const float b0c = b0[c], sc0 = bnp[c], sh0 = bnp[64+c];
    const float b1c2 = b1[c2], sc1 = bnp[128+c2], sh1 = bnp[192+c2];
    const float b2c2 = b2[c2], sc2 = bnp[256+c2], sh2 = bnp[320+c2];
    frag_u Bw1[2], Bw2[2];
    #pragma unroll
    for (int kt = 0; kt < 2; ++kt) {
        Bw1[kt].u4 = *(const uint4*)&w1b[((kt*4 + rq)*64 + c)*4];
        Bw2[kt].u4 = *(const uint4*)&w2b[((kt*4 + rq)*64 + c)*4];
    }
    __syncthreads();
    for (int chunk = 0; chunk < 4; ++chunk) {
        if (tid < 192) {
            const int slot = tid / 3, cc = tid % 3;
            const int grow = chunk*64 + slot;
            const int e = grow >> 5, k = grow & 31;
            gxs[slot][cc] = xyz[((size_t)b * NPTS + idxs[e][k]) * 3 + cc] - qs[e][cc];
        }
        __syncthreads();
        #pragma unroll
        for (int i = 0; i < 16; ++i) {
            const int r = rq*16 + i;
            const float t0 = gxs[r][0]*w0c0 + gxs[r][1]*w0c1 + gxs[r][2]*w0c2 + b0c;
            h1s[r*H1PAD + c] = fmaxf(sc0*t0 + sh0, 0.f);
        }
        __syncthreads();
        #pragma unroll
        for (int mt = 0; mt < 4; ++mt) {
            f32x4 acc = {0,0,0,0};
            #pragma unroll
            for (int kt = 0; kt < 2; ++kt) {
                frag_u a;
                #pragma unroll
                for (int r = 0; r < 4; ++r) {
                    const float2 f = *(const float2*)&h1s[(mt*16 + lm)*H1PAD + kt*32 + lg*8 + 2*r];
                    a.u[r] = pack_bf16pair(f.x, f.y);
                }
                acc = __builtin_amdgcn_mfma_f32_16x16x32_bf16(a.h, Bw1[kt].h, acc, 0, 0, 0);
            }
            #pragma unroll
            for (int r = 0; r < 4; ++r)
                h2s[(mt*16 + lg*4 + r)*H1PAD + c2] = fmaxf(sc1*(acc[r] + b1c2) + sh1, 0.f);
        }
        __syncthreads();
        #pragma unroll
        for (int mt = 0; mt < 4; ++mt) {
            f32x4 acc = {0,0,0,0};
            #pragma unroll
            for (int kt = 0; kt < 2; ++kt) {
                frag_u a;
                #pragma unroll
                for (int r = 0; r < 4; ++r) {
                    const float2 f = *(const float2*)&h2s[(mt*16 + lm)*H1PAD + kt*32 + lg*8 + 2*r];
                    a.u[r] = pack_bf16pair(f.x, f.y);
                }
                acc = __builtin_amdgcn_mfma_f32_16x16x32_bf16(a.h, Bw2[kt].h, acc, 0, 0, 0);
            }
            float wt[4];
            #pragma unroll
            for (int r = 0; r < 4; ++r)
                wt[r] = fmaxf(sc2*(acc[r] + b2c2) + sh2, 0.f);
            const int grow0 = chunk*64 + mt*16 + lg*4;
            const int e = grow0 >> 5, kl = grow0 & 31;
            wtp[e][kl >> 1][c2]       = pack_bf16pair(wt[0], wt[1]);
            wtp[e][(kl >> 1) + 1][c2] = pack_bf16pair(wt[2], wt[3]);
        }
        __syncthreads();
    }
    const int lane = c;
    const int wid = rq;
    frag_u afr[2][4];
    #pragma unroll
    for (int es = 0; es < 2; ++es)
        #pragma unroll
        for (int w4 = 0; w4 < 4; ++w4)
            #pragma unroll
            for (int r = 0; r < 4; ++r)
                afr[es][w4].u[r] = wtp[wid*2 + es][lg*4 + r][w4*16 + lm];
    f32x4 yacc = {0.f, 0.f, 0.f, 0.f};
    for (int dhalf = 0; dhalf < 2; ++dhalf) {
        #pragma unroll
        for (int es = 0; es < 2; ++es) {
            const int e = wid*2 + es;
            #pragma unroll
            for (int dt = 0; dt < 2; ++dt) {
                const int d = dhalf*32 + dt*16 + lm;
                const float* fb = feat + (size_t)(b*64 + d) * NPTS;
                frag_u B;
                #pragma unroll
                for (int r = 0; r < 4; ++r) {
                    const int k0 = lg*8 + 2*r;
                    B.u[r] = pack_bf16pair(fb[idxs[e][k0]], fb[idxs[e][k0+1]]);
                }
                #pragma unroll
                for (int w4 = 0; w4 < 4; ++w4) {
                    f32x4 dnf = {0.f, 0.f, 0.f, 0.f};
                    dnf = __builtin_amdgcn_mfma_f32_16x16x32_bf16(afr[es][w4].h, B.h, dnf, 0, 0, 0);
                    const unsigned p0 = pack_bf16pair(dnf[0], dnf[1]);
                    const unsigned p1 = pack_bf16pair(dnf[2], dnf[3]);
                    const int dloc = dt*16 + lm;
                    const int kp0 = dloc*32 + w4*8 + lg*2;
                    const int sw = kp0 ^ ((lm & 3) << 3) ^ ((e & 7) << 2);
                    *(uint2*)&yaf[e*1024 + sw] = make_uint2(p0, p1);
                }
            }
        }
        __syncthreads();
        for (int kt = 0; kt < 64; ++kt) {
            frag_u A, Bf;
            const int kpb = (kt*16 + lg*4) ^ (((kt >> 1) & 3) << 3) ^ ((lm & 7) << 2);
            A.u4 = *(const uint4*)&yaf[(lm & 7)*1024 + kpb];
            Bf.u4 = *(const uint4*)&wfb[(((size_t)(dhalf*64 + kt)*4 + wid)*64 + lane)*4];
            yacc = __builtin_amdgcn_mfma_f32_16x16x32_bf16(A.h, Bf.h, yacc, 0, 0, 0);
        }
        __syncthreads();
    }
    if (lg < 2) {
        const float bfo = bf[wid*16 + lm];
        #pragma unroll
        for (int r = 0; r < 4; ++r)
            y[(size_t)(bs0 + lg*4 + r) * 64 + wid*16 + lm] = yacc[r] + bfo;
    }
}

__global__ __launch_bounds__(256) void ystats_kernel(const float* __restrict__ y,
                                                     double* __restrict__ st)
{
    const int tid = threadIdx.x;
    const int c = tid & 63;
    double s = 0.0, s2 = 0.0;
    for (int i = blockIdx.x * 256 + tid; i < NBATCH*NSAMP*64; i += gridDim.x * 256) {
        const float v = y[i];
        s += v; s2 += (double)v * (double)v;
    }
    __shared__ double rs[256], rs2[256];
    rs[tid] = s; rs2[tid] = s2;
    __syncthreads();
    if (tid < 64) {
        const double a  = rs[c]  + rs[64+c]  + rs[128+c]  + rs[192+c];
        const double a2 = rs2[c] + rs2[64+c] + rs2[128+c] + rs2[192+c];
        atomicAdd(&st[c], a);
        atomicAdd(&st[64 + c], a2);
    }
}

__global__ void writeout_kernel(const float* __restrict__ y,
                                const float* __restrict__ bnp3,
                                float* __restrict__ outp)
{
    const int i = blockIdx.x * 256 + threadIdx.x;
    if (i >= NBATCH * 64 * NSAMP) return;
    const int s = i & 1023;
    const int o = (i >> 10) & 63;
    const int bb = i >> 16;
    const float v = y[((size_t)(bb << 10) + s) * 64 + o];
    outp[i] = fmaxf(bnp3[o] * v + bnp3[64 + o], 0.f);
}

// ============================ launch ============================
extern "C" void kernel_launch(void* const* d_in, const int* in_sizes, int n_in,
                              void* d_out, int out_size, void* d_ws, size_t ws_size,
                              hipStream_t stream)
{
    (void)in_sizes; (void)n_in; (void)out_size; (void)ws_size;
    const float* xyz  = (const float*)d_in[0];
    const float* feat = (const float*)d_in[1];
    const float* w0   = (const float*)d_in[2];
    const float* b0   = (const float*)d_in[3];
    const float* g0   = (const float*)d_in[4];
    const float* be0  = (const float*)d_in[5];
    const float* w1   = (const float*)d_in[6];
    const float* b1   = (const float*)d_in[7];
    const float* g1   = (const float*)d_in[8];
    const float* be1  = (const float*)d_in[9];
    const float* w2   = (const float*)d_in[10];
    const float* b2   = (const float*)d_in[11];
    const float* g2   = (const float*)d_in[12];
    const float* be2  = (const float*)d_in[13];
    const float* wf   = (const float*)d_in[14];
    const float* bf   = (const float*)d_in[15];
    const float* gf   = (const float*)d_in[16];
    const float* bef  = (const float*)d_in[17];

    float* out = (float*)d_out;
    float* newxyz = out;                       // (B, S, 3)
    float* outmain = out + NBATCH * NSAMP * 3; // (B, 64, S)

    char* ws = (char*)d_ws;
    int*      idxws = (int*)ws;                            // 2 MB
    float*    ybuf  = (float*)(ws + 2097152);              // 4 MB
    double*   stats = (double*)(ws + 6291456);             // 4 KB
    float*    bnp   = (float*)(ws + 6295552);              // 2 KB
    unsigned* wfb   = (unsigned*)(ws + 6297600);           // 512 KB
    unsigned* w1b   = (unsigned*)(ws + 6821888);           // 8 KB
    unsigned* w2b   = (unsigned*)(ws + 6830080);           // 8 KB
    float*    G1    = (float*)(ws + 6838272);              // 16 KB
    float*    G2    = (float*)(ws + 6854656);              // 16 KB

    zero_all_kernel<<<16, 256, 0, stream>>>(stats, G1, G2);
    wfpack_kernel<<<512, 64, 0, stream>>>(wf, wfb);
    wfpack_kernel<<<8, 64, 0, stream>>>(w1, w1b);
    wfpack_kernel<<<8, 64, 0, stream>>>(w2, w2b);
    fps_kernel<<<NBATCH, 256, 0, stream>>>(xyz, newxyz);
    knn_kernel<<<NBATCH * NSAMP, 256, 0, stream>>>(xyz, newxyz, idxws);

    gxmoments_kernel<<<512, 256, 0, stream>>>(xyz, newxyz, idxws, stats);
    bn0_moments_finalize_kernel<<<1, 64, 0, stream>>>(stats, w0, b0, g0, be0, bnp);
    gram1_kernel<<<256, 256, 0, stream>>>(xyz, newxyz, idxws, w0, b0, bnp, G1, stats + 128);
    bn_gram_finalize_kernel<<<1, 256, 0, stream>>>(stats + 128, G1, w1, b1, g1, be1, bnp + 128);
    gram2_kernel<<<256, 256, 0, stream>>>(xyz, newxyz, idxws, w0, b0, b1, w1b, bnp, G2, stats + 192);
    bn_gram_finalize_kernel<<<1, 256, 0, stream>>>(stats + 192, G2, w2, b2, g2, be2, bnp + 256);

    final_conv_kernel<<<NBATCH * NSAMP / 8, 256, 0, stream>>>(
        xyz, newxyz, idxws, feat, w0, b0, b1, b2, bnp, wfb, w1b, w2b, bf, ybuf);

    ystats_kernel<<<256, 256, 0, stream>>>(ybuf, stats + 384);
    bn_finalize_kernel<<<1, 64, 0, stream>>>(stats + 384, gf, bef, bnp + 384, (float)(NBATCH * NSAMP));
    writeout_kernel<<<4096, 256, 0, stream>>>(ybuf, bnp + 384, outmain);
}